// Round 5
// baseline (8942.381 us; speedup 1.0000x reference)
//
#include <hip/hip_runtime.h>
#include <cfloat>
#include <math.h>

#define B_ 64
#define P_ 196
#define ENC_ 2048
#define D_ 512
#define V_ 32000
#define L_ 32
#define T_ 31
#define NBLK_ 256

// flat f32 output layout (reference return order)
#define OUT_PREDS 0L
#define OUT_CAPS  63488000L              // 64*31*32000
#define OUT_DECL  63490048L              // +64*32
#define OUT_ALPH  63490112L              // +64
#define OUT_ORDER 63878976L              // +64*31*196

typedef __bf16 bf16;
typedef __bf16 bf16x8 __attribute__((ext_vector_type(8)));
typedef __bf16 bf16x4 __attribute__((ext_vector_type(4)));
typedef __bf16 bf16x2 __attribute__((ext_vector_type(2)));
typedef float  f32x4  __attribute__((ext_vector_type(4)));

static __device__ __forceinline__ float sigmoidf_(float x) { return 1.f / (1.f + __expf(-x)); }

// ---------------- sort by length, caps gather, scalar outputs, barrier reset ----------------
__global__ void k_order(const int* __restrict__ cap_len, const int* __restrict__ caps,
                        int* __restrict__ order_i, int* __restrict__ declen_i,
                        int* __restrict__ caps_i, float* __restrict__ out,
                        unsigned* __restrict__ bar)
{
    __shared__ int len_s[B_];
    int tid = threadIdx.x;
    if (tid == 0) { bar[0] = 0u; bar[1] = 0u; }
    len_s[tid] = cap_len[tid];
    __syncthreads();
    int li = len_s[tid];
    int pos = 0;
    for (int j = 0; j < B_; ++j) {
        int lj = len_s[j];
        pos += (lj > li) || (lj == li && j < tid);   // stable descending rank
    }
    order_i[pos]  = tid;
    declen_i[pos] = li - 1;
    out[OUT_ORDER + pos] = (float)tid;
    out[OUT_DECL  + pos] = (float)(li - 1);
    for (int l = 0; l < L_; ++l) {
        int tok = caps[tid * L_ + l];
        caps_i[pos * L_ + l] = tok;
        out[OUT_CAPS + pos * L_ + l] = (float)tok;
    }
}

// ---------------- f32 -> bf16 convert (8/thread) ----------------
__global__ __launch_bounds__(256) void k_cvt(const float* __restrict__ in, bf16* __restrict__ ob, long n)
{
    long i = ((long)blockIdx.x * 256 + threadIdx.x) * 8;
    if (i >= n) return;
    float4 a = *(const float4*)(in + i);
    float4 b = *(const float4*)(in + i + 4);
    bf16x8 v;
    v[0]=(bf16)a.x; v[1]=(bf16)a.y; v[2]=(bf16)a.z; v[3]=(bf16)a.w;
    v[4]=(bf16)b.x; v[5]=(bf16)b.y; v[6]=(bf16)b.z; v[7]=(bf16)b.w;
    *(bf16x8*)(ob + i) = v;
}

// ---------------- enc gather-by-order + convert to bf16 ----------------
__global__ __launch_bounds__(256) void k_cvt_enc(const float* __restrict__ enc,
                                                 const int* __restrict__ order_i,
                                                 bf16* __restrict__ enc_s)
{
    long i = ((long)blockIdx.x * 256 + threadIdx.x) * 8;
    int b = (int)(i / ((long)P_ * ENC_));
    long rem = i - (long)b * P_ * ENC_;
    const float* src = enc + (long)order_i[b] * P_ * ENC_ + rem;
    float4 a = *(const float4*)(src);
    float4 c = *(const float4*)(src + 4);
    bf16x8 v;
    v[0]=(bf16)a.x; v[1]=(bf16)a.y; v[2]=(bf16)a.z; v[3]=(bf16)a.w;
    v[4]=(bf16)c.x; v[5]=(bf16)c.y; v[6]=(bf16)c.z; v[7]=(bf16)c.w;
    *(bf16x8*)(enc_s + i) = v;
}

// ---------------- mean over pixels (bf16 in/out) ----------------
__global__ __launch_bounds__(256) void k_meanb(const bf16* __restrict__ enc_s, bf16* __restrict__ mean_b)
{
    int b = blockIdx.x, col = blockIdx.y * 256 + threadIdx.x;
    float s = 0.f;
    const bf16* eb = enc_s + (long)b * P_ * ENC_ + col;
    for (int p = 0; p < P_; ++p) s += (float)eb[(long)p * ENC_];
    mean_b[(long)b * ENC_ + col] = (bf16)(s * (1.f / (float)P_));
}

// ---------------- MFMA GEMM (pre/post kernels): C[M][N] = A[M][K] * B[N][K]^T ------
// Swapped-operand mfma: acc regs hold 4 consecutive n per lane -> dwordx4 stores.
// FUSE: 0=single B, 1=N-split.  EPI: 0=RAW f32, 1=bf16 +bias (att1), 2=masked preds +bias
// SWZ:  0=3D grid; 1=att1 784 blocks XCD-chunked; 2=preds 7750 blocks XCD-chunked
template<int FUSE, int EPI, int SWZ>
__global__ void __launch_bounds__(256)
k_mgemm(const bf16* __restrict__ A, long lda,
        const bf16* __restrict__ B1, const bf16* __restrict__ B2,
        const float* __restrict__ bias,
        float* __restrict__ Cf, bf16* __restrict__ Cb,
        int N, int K, int kspl, int Nsp,
        const int* __restrict__ declen_i)
{
    const int tid = threadIdx.x;
    const int lane = tid & 63, w = tid >> 6;
    int mt, nt, z;
    if (SWZ == 0)      { mt = blockIdx.x; nt = blockIdx.y; z = blockIdx.z; }
    else if (SWZ == 1) { int o = blockIdx.x; int wg = (o & 7) * 98 + (o >> 3);
                         mt = wg >> 2; nt = wg & 3; z = 0; }
    else               { int o = blockIdx.x; int xcd = o & 7;
                         int base = xcd < 6 ? xcd * 969 : 5814 + (xcd - 6) * 968;
                         int wg = base + (o >> 3);
                         nt = wg / 31; mt = wg - 31 * nt; z = 0; }
    const int krange = K / kspl;
    const int k0 = z * krange, k1 = k0 + krange;
    const int r16 = lane & 15, kq = lane >> 4;
    const int koff = kq * 8;

    const bf16* Ap = A + (long)(mt * 64 + r16) * lda + koff;
    const int ncol0 = nt * 128 + w * 32;

    const bf16* Bp[2];
#pragma unroll
    for (int ni = 0; ni < 2; ++ni) {
        int n = ncol0 + ni * 16 + r16;
        if (FUSE == 1)
            Bp[ni] = (n < Nsp) ? B1 + (long)n * K + koff
                               : B2 + (long)(n - Nsp) * K + koff;
        else
            Bp[ni] = B1 + (long)n * K + koff;
    }

    f32x4 acc[4][2] = {};
    bf16x8 af[4], bfr[2];
#pragma unroll
    for (int mi = 0; mi < 4; ++mi) af[mi] = *(const bf16x8*)(Ap + (long)mi * 16 * lda + k0);
#pragma unroll
    for (int ni = 0; ni < 2; ++ni) bfr[ni] = *(const bf16x8*)(Bp[ni] + k0);
    for (int kk = k0 + 32; kk < k1; kk += 32) {
        bf16x8 af2[4], bf2[2];
#pragma unroll
        for (int mi = 0; mi < 4; ++mi) af2[mi] = *(const bf16x8*)(Ap + (long)mi * 16 * lda + kk);
#pragma unroll
        for (int ni = 0; ni < 2; ++ni) bf2[ni] = *(const bf16x8*)(Bp[ni] + kk);
#pragma unroll
        for (int mi = 0; mi < 4; ++mi)
#pragma unroll
            for (int ni = 0; ni < 2; ++ni)
                acc[mi][ni] = __builtin_amdgcn_mfma_f32_16x16x32_bf16(bfr[ni], af[mi], acc[mi][ni], 0, 0, 0);
#pragma unroll
        for (int mi = 0; mi < 4; ++mi) af[mi] = af2[mi];
#pragma unroll
        for (int ni = 0; ni < 2; ++ni) bfr[ni] = bf2[ni];
    }
#pragma unroll
    for (int mi = 0; mi < 4; ++mi)
#pragma unroll
        for (int ni = 0; ni < 2; ++ni)
            acc[mi][ni] = __builtin_amdgcn_mfma_f32_16x16x32_bf16(bfr[ni], af[mi], acc[mi][ni], 0, 0, 0);

    // Swapped C/D layout: lane -> row = mt*64+mi*16+r16, cols = ncol0+ni*16+kq*4 .. +3
#pragma unroll
    for (int mi = 0; mi < 4; ++mi) {
        const int row = mt * 64 + mi * 16 + r16;
#pragma unroll
        for (int ni = 0; ni < 2; ++ni) {
            const int col = ncol0 + ni * 16 + kq * 4;
            f32x4 v = acc[mi][ni];
            if (EPI == 0) {
                *(f32x4*)(Cf + (long)z * 64 * N + (long)row * N + col) = v;
            } else if (EPI == 1) {
                f32x4 bv = *(const f32x4*)(bias + col);
                bf16x4 o;
                o[0]=(bf16)(v[0]+bv[0]); o[1]=(bf16)(v[1]+bv[1]);
                o[2]=(bf16)(v[2]+bv[2]); o[3]=(bf16)(v[3]+bv[3]);
                *(bf16x4*)(Cb + (long)row * N + col) = o;
            } else { // row encodes t*64+b over hseq
                int tt = row >> 6, b = row & 63;
                bool msk = tt < declen_i[b];
                f32x4 bv = *(const f32x4*)(bias + col);
                f32x4 o;
                o[0] = msk ? v[0]+bv[0] : 0.f; o[1] = msk ? v[1]+bv[1] : 0.f;
                o[2] = msk ? v[2]+bv[2] : 0.f; o[3] = msk ? v[3]+bv[3] : 0.f;
                *(f32x4*)(Cf + OUT_PREDS + ((long)b * T_ + tt) * V_ + col) = o;
            }
        }
    }
}

// ---------------- LN stats helper (blockDim=512, init kernel) ----------------
static __device__ __forceinline__ void ln_stats(float x, float* r1, float* r2,
                                                float& m, float& var)
{
    int tid = threadIdx.x;
    r1[tid] = x; r2[tid] = x * x;
    __syncthreads();
    for (int s = 256; s > 0; s >>= 1) {
        if (tid < s) { r1[tid] += r1[tid + s]; r2[tid] += r2[tid + s]; }
        __syncthreads();
    }
    m = r1[0] * (1.f / 512.f);
    var = r2[0] * (1.f / 512.f) - m * m;
    __syncthreads();
}

// ---------------- init h,c = LN(mean_enc @ W^T + b) ----------------
__global__ __launch_bounds__(512)
void k_initln(const float* __restrict__ pi,
              const float* __restrict__ b_h, const float* __restrict__ b_c,
              const float* __restrict__ g_h, const float* __restrict__ be_h,
              const float* __restrict__ g_c, const float* __restrict__ be_c,
              bf16* __restrict__ xh, float* __restrict__ c)
{
    int b = blockIdx.x, d = threadIdx.x;
    float yh = pi[(long)b * 1024 + d]       + b_h[d];
    float yc = pi[(long)b * 1024 + 512 + d] + b_c[d];
    __shared__ float r1[512], r2[512];
    float m, v;
    ln_stats(yh, r1, r2, m, v);
    xh[(long)b * 3072 + 2560 + d] = (bf16)((yh - m) * rsqrtf(v + 1e-5f) * g_h[d] + be_h[d]);
    ln_stats(yc, r1, r2, m, v);
    c[(long)b * 512 + d] = (yc - m) * rsqrtf(v + 1e-5f) * g_c[d] + be_c[d];
}

// ---------------- device-scope grid barrier ----------------
static __device__ __forceinline__ void gbar(unsigned* bar)
{
    __threadfence();                 // release: every thread flushes its CU's writes
    __syncthreads();
    if (threadIdx.x == 0) {
        unsigned g = __hip_atomic_load(&bar[1], __ATOMIC_RELAXED, __HIP_MEMORY_SCOPE_AGENT);
        unsigned a = __hip_atomic_fetch_add(&bar[0], 1u, __ATOMIC_ACQ_REL, __HIP_MEMORY_SCOPE_AGENT);
        if (a == (unsigned)(NBLK_ - 1)) {
            __hip_atomic_store(&bar[0], 0u, __ATOMIC_RELAXED, __HIP_MEMORY_SCOPE_AGENT);
            __hip_atomic_store(&bar[1], g + 1u, __ATOMIC_RELEASE, __HIP_MEMORY_SCOPE_AGENT);
        } else {
            while (__hip_atomic_load(&bar[1], __ATOMIC_RELAXED, __HIP_MEMORY_SCOPE_AGENT) == g)
                __builtin_amdgcn_s_sleep(1);
        }
    }
    __syncthreads();
    __threadfence();                 // acquire: every reading CU invalidates stale lines
}

// ---------------- persistent step loop: 31 steps, 4 phases, grid barriers ----------------
__global__ __launch_bounds__(256)
void k_steps(const bf16* __restrict__ att1_b, const bf16* __restrict__ enc_s,
             const bf16* __restrict__ Wd,  const bf16* __restrict__ Wbt,
             const bf16* __restrict__ Wih, const bf16* __restrict__ Whh,
             const float* __restrict__ b_dec, const float* __restrict__ b_beta,
             const float* __restrict__ Wfull,
             const float* __restrict__ b_ih, const float* __restrict__ b_hh,
             const float* __restrict__ g_h, const float* __restrict__ be_h,
             const float* __restrict__ g_c, const float* __restrict__ be_c,
             const int* __restrict__ caps_i, const int* __restrict__ declen_i,
             const float* __restrict__ emb,
             bf16* __restrict__ xh, float* __restrict__ cst,
             float* __restrict__ att2gate, float* __restrict__ gp,
             bf16* __restrict__ hseq, float* __restrict__ out,
             unsigned* __restrict__ bar)
{
    const int bid = blockIdx.x, tid = threadIdx.x;
    const int lane = tid & 63, w = tid >> 6;
    const int r16 = lane & 15, kq = lane >> 4, koff = kq * 8;
    __shared__ float att2s[512], wf[512], red[256], alp[P_];
    __shared__ float r1[256], r2[256];

    for (int t = 0; t < T_; ++t) {
        // ---- Phase A: [att2|gate_pre] = h @ [W_dec|W_beta]^T, S=4, 80 blocks ----
        if (bid < 80) {
            const int nt = bid % 20, z = bid / 20;
            const int k0 = z * 128;
            const int ncol0 = nt * 128 + w * 32;
            const bf16* Ap = xh + 2560 + (long)r16 * 3072 + koff;
            const bf16* Bp[2];
#pragma unroll
            for (int ni = 0; ni < 2; ++ni) {
                int n = ncol0 + ni * 16 + r16;
                Bp[ni] = ((n < 512) ? Wd + (long)n * 512 : Wbt + (long)(n - 512) * 512) + koff;
            }
            f32x4 acc[4][2] = {};
#pragma unroll
            for (int kk = k0; kk < k0 + 128; kk += 32) {
                bf16x8 af[4], bfr[2];
#pragma unroll
                for (int mi = 0; mi < 4; ++mi) af[mi] = *(const bf16x8*)(Ap + (long)mi * 16 * 3072 + kk);
#pragma unroll
                for (int ni = 0; ni < 2; ++ni) bfr[ni] = *(const bf16x8*)(Bp[ni] + kk);
#pragma unroll
                for (int mi = 0; mi < 4; ++mi)
#pragma unroll
                    for (int ni = 0; ni < 2; ++ni)
                        acc[mi][ni] = __builtin_amdgcn_mfma_f32_16x16x32_bf16(bfr[ni], af[mi], acc[mi][ni], 0, 0, 0);
            }
            float* C = att2gate + (long)z * 64 * 2560;
#pragma unroll
            for (int mi = 0; mi < 4; ++mi) {
                const int row = mi * 16 + r16;
#pragma unroll
                for (int ni = 0; ni < 2; ++ni)
                    *(f32x4*)(C + (long)row * 2560 + ncol0 + ni * 16 + kq * 4) = acc[mi][ni];
            }
        }
        gbar(bar);

        // ---- Phase BC: alpha + awe + emb, 256 blocks = (b, seg) ----
        {
            const int b = bid >> 2, seg = bid & 3;
            if (t < declen_i[b]) {
                for (int i = tid; i < 512; i += 256) {
                    float s = b_dec[i];
#pragma unroll
                    for (int z = 0; z < 4; ++z) s += att2gate[((long)z * 64 + b) * 2560 + i];
                    att2s[i] = s;
                    wf[i] = Wfull[i];
                }
                __syncthreads();
                float ev = -FLT_MAX;
                if (tid < P_) {
                    const bf16* ar = att1_b + ((long)b * P_ + tid) * 512;
                    float acc = 0.f;
                    for (int a0 = 0; a0 < 512; a0 += 8) {
                        bf16x8 v = *(const bf16x8*)(ar + a0);
#pragma unroll
                        for (int j = 0; j < 8; ++j)
                            acc += fmaxf((float)v[j] + att2s[a0 + j], 0.f) * wf[a0 + j];
                    }
                    ev = acc;   // + b_full: softmax-invariant
                }
                red[tid] = ev;
                __syncthreads();
                for (int s = 128; s > 0; s >>= 1) { if (tid < s) red[tid] = fmaxf(red[tid], red[tid + s]); __syncthreads(); }
                float mx = red[0];
                __syncthreads();
                float ex = (tid < P_) ? __expf(ev - mx) : 0.f;
                red[tid] = ex;
                __syncthreads();
                for (int s = 128; s > 0; s >>= 1) { if (tid < s) red[tid] += red[tid + s]; __syncthreads(); }
                float inv = 1.f / red[0];
                if (tid < P_) alp[tid] = ex * inv;
                __syncthreads();
                if (seg == 1 && tid < P_)
                    out[OUT_ALPH + ((long)b * T_ + t) * P_ + tid] = alp[tid];
                // awe for this 512-col segment
                const int c0 = seg * 512 + tid * 2;
                const bf16* eb = enc_s + (long)b * P_ * ENC_ + c0;
                float a0 = 0.f, a1 = 0.f;
#pragma unroll 4
                for (int p = 0; p < P_; ++p) {
                    bf16x2 v = *(const bf16x2*)(eb + (long)p * ENC_);
                    float al = alp[p];
                    a0 += al * (float)v[0]; a1 += al * (float)v[1];
                }
                float g0 = b_beta[c0], g1 = b_beta[c0 + 1];
#pragma unroll
                for (int z = 0; z < 4; ++z) {
                    const float* gs = att2gate + ((long)z * 64 + b) * 2560 + 512 + c0;
                    g0 += gs[0]; g1 += gs[1];
                }
                bf16x2 o;
                o[0] = (bf16)(a0 * sigmoidf_(g0));
                o[1] = (bf16)(a1 * sigmoidf_(g1));
                *(bf16x2*)(xh + (long)b * 3072 + 512 + c0) = o;
                if (seg == 0) {
                    int tok = caps_i[b * L_ + t];
                    for (int i = tid; i < 512; i += 256)
                        xh[(long)b * 3072 + i] = (bf16)emb[(long)tok * 512 + i];
                }
            } else {
                if (seg == 1 && tid < P_)
                    out[OUT_ALPH + ((long)b * T_ + t) * P_ + tid] = 0.f;
            }
        }
        gbar(bar);

        // ---- Phase D: gates = xh @ [W_ih;W_hh]^T (K-split 2560, S=8), 128 blocks ----
        if (bid < 128) {
            const int nt = bid & 15, z = bid >> 4;
            const int k0 = z * 384;
            const int ncol0 = nt * 128 + w * 32;
            const bf16* Ap = xh + (long)r16 * 3072 + koff;
            const bf16* Bih[2]; const bf16* Bhh[2];
#pragma unroll
            for (int ni = 0; ni < 2; ++ni) {
                int n = ncol0 + ni * 16 + r16;
                Bih[ni] = Wih + (long)n * 2560 + koff;
                Bhh[ni] = Whh + (long)n * 512 + koff - 2560;
            }
            f32x4 acc[4][2] = {};
            for (int kk = k0; kk < k0 + 384; kk += 32) {
                bf16x8 af[4], bfr[2];
#pragma unroll
                for (int mi = 0; mi < 4; ++mi) af[mi] = *(const bf16x8*)(Ap + (long)mi * 16 * 3072 + kk);
#pragma unroll
                for (int ni = 0; ni < 2; ++ni)
                    bfr[ni] = *(const bf16x8*)(((kk < 2560) ? Bih[ni] : Bhh[ni]) + kk);
#pragma unroll
                for (int mi = 0; mi < 4; ++mi)
#pragma unroll
                    for (int ni = 0; ni < 2; ++ni)
                        acc[mi][ni] = __builtin_amdgcn_mfma_f32_16x16x32_bf16(bfr[ni], af[mi], acc[mi][ni], 0, 0, 0);
            }
            float* C = gp + (long)z * 64 * 2048;
#pragma unroll
            for (int mi = 0; mi < 4; ++mi) {
                const int row = mi * 16 + r16;
#pragma unroll
                for (int ni = 0; ni < 2; ++ni)
                    *(f32x4*)(C + (long)row * 2048 + ncol0 + ni * 16 + kq * 4) = acc[mi][ni];
            }
        }
        gbar(bar);

        // ---- Phase E: LSTM + 2x LN + state update + hseq, 64 blocks, 2 d/thread ----
        if (bid < 64) {
            const int b = bid;
            if (t < declen_i[b]) {
                const int d0 = tid, d1 = tid + 256;
                float iv0 = b_ih[d0] + b_hh[d0],             iv1 = b_ih[d1] + b_hh[d1];
                float fv0 = b_ih[512+d0] + b_hh[512+d0],     fv1 = b_ih[512+d1] + b_hh[512+d1];
                float gv0 = b_ih[1024+d0] + b_hh[1024+d0],   gv1 = b_ih[1024+d1] + b_hh[1024+d1];
                float ov0 = b_ih[1536+d0] + b_hh[1536+d0],   ov1 = b_ih[1536+d1] + b_hh[1536+d1];
#pragma unroll
                for (int z = 0; z < 8; ++z) {
                    const float* gs = gp + ((long)z * 64 + b) * 2048;
                    iv0 += gs[d0]; fv0 += gs[512+d0]; gv0 += gs[1024+d0]; ov0 += gs[1536+d0];
                    iv1 += gs[d1]; fv1 += gs[512+d1]; gv1 += gs[1024+d1]; ov1 += gs[1536+d1];
                }
                float c0 = cst[(long)b * 512 + d0], c1 = cst[(long)b * 512 + d1];
                float cn0 = sigmoidf_(fv0) * c0 + sigmoidf_(iv0) * tanhf(gv0);
                float cn1 = sigmoidf_(fv1) * c1 + sigmoidf_(iv1) * tanhf(gv1);
                float hn0 = sigmoidf_(ov0) * tanhf(cn0);
                float hn1 = sigmoidf_(ov1) * tanhf(cn1);
                // LN(h)
                r1[tid] = hn0 + hn1; r2[tid] = hn0*hn0 + hn1*hn1;
                __syncthreads();
                for (int s = 128; s > 0; s >>= 1) { if (tid < s) { r1[tid]+=r1[tid+s]; r2[tid]+=r2[tid+s]; } __syncthreads(); }
                float m = r1[0] * (1.f/512.f), vv = r2[0] * (1.f/512.f) - m*m;
                float rs = rsqrtf(vv + 1e-5f);
                float hl0 = (hn0 - m) * rs * g_h[d0] + be_h[d0];
                float hl1 = (hn1 - m) * rs * g_h[d1] + be_h[d1];
                __syncthreads();
                // LN(c)
                r1[tid] = cn0 + cn1; r2[tid] = cn0*cn0 + cn1*cn1;
                __syncthreads();
                for (int s = 128; s > 0; s >>= 1) { if (tid < s) { r1[tid]+=r1[tid+s]; r2[tid]+=r2[tid+s]; } __syncthreads(); }
                float m2 = r1[0] * (1.f/512.f), vv2 = r2[0] * (1.f/512.f) - m2*m2;
                float rs2 = rsqrtf(vv2 + 1e-5f);
                float cl0 = (cn0 - m2) * rs2 * g_c[d0] + be_c[d0];
                float cl1 = (cn1 - m2) * rs2 * g_c[d1] + be_c[d1];
                bf16 hv0 = (bf16)hl0, hv1 = (bf16)hl1;
                xh[(long)b * 3072 + 2560 + d0] = hv0;
                xh[(long)b * 3072 + 2560 + d1] = hv1;
                hseq[((long)t * B_ + b) * 512 + d0] = hv0;
                hseq[((long)t * B_ + b) * 512 + d1] = hv1;
                cst[(long)b * 512 + d0] = cl0;
                cst[(long)b * 512 + d1] = cl1;
            }
        }
        gbar(bar);
    }
}

extern "C" void kernel_launch(void* const* d_in, const int* in_sizes, int n_in,
                              void* d_out, int out_size, void* d_ws, size_t ws_size,
                              hipStream_t stream)
{
    const float* enc       = (const float*)d_in[0];
    const int*   caps      = (const int*)  d_in[1];
    const int*   caplen    = (const int*)  d_in[2];
    const float* emb       = (const float*)d_in[3];
    const float* W_enc_att = (const float*)d_in[4];
    const float* b_enc_att = (const float*)d_in[5];
    const float* W_dec_att = (const float*)d_in[6];
    const float* b_dec_att = (const float*)d_in[7];
    const float* W_full    = (const float*)d_in[8];
    // d_in[9] = b_full (softmax-invariant, unused)
    const float* W_ih      = (const float*)d_in[10];
    const float* b_ih      = (const float*)d_in[11];
    const float* W_hh      = (const float*)d_in[12];
    const float* b_hh      = (const float*)d_in[13];
    const float* g_h       = (const float*)d_in[14];
    const float* be_h      = (const float*)d_in[15];
    const float* g_c       = (const float*)d_in[16];
    const float* be_c      = (const float*)d_in[17];
    const float* W_init_h  = (const float*)d_in[18];
    const float* b_init_h  = (const float*)d_in[19];
    const float* W_init_c  = (const float*)d_in[20];
    const float* b_init_c  = (const float*)d_in[21];
    const float* W_beta    = (const float*)d_in[22];
    const float* b_beta    = (const float*)d_in[23];
    const float* W_fc      = (const float*)d_in[24];
    const float* b_fc      = (const float*)d_in[25];
    float* out = (float*)d_out;

    char* w = (char*)d_ws;
    auto alloc = [&](size_t bytes) { char* p = w; w += (bytes + 255) & ~(size_t)255; return p; };
    int*   order_i  = (int*)  alloc(B_ * 4);
    int*   declen_i = (int*)  alloc(B_ * 4);
    int*   caps_i   = (int*)  alloc(B_ * L_ * 4);
    unsigned* bar   = (unsigned*)alloc(256);
    bf16*  enc_s    = (bf16*) alloc((size_t)B_ * P_ * ENC_ * 2);
    bf16*  mean_b   = (bf16*) alloc((size_t)B_ * ENC_ * 2);
    bf16*  att1_b   = (bf16*) alloc((size_t)B_ * P_ * 512 * 2);
    float* pi       = (float*)alloc((size_t)B_ * 1024 * 4);
    float* att2gate = (float*)alloc((size_t)4 * B_ * 2560 * 4);
    bf16*  xh       = (bf16*) alloc((size_t)B_ * 3072 * 2);
    float* gp       = (float*)alloc((size_t)8 * B_ * 2048 * 4);
    float* cbuf     = (float*)alloc((size_t)B_ * 512 * 4);
    bf16*  hseq     = (bf16*) alloc((size_t)T_ * B_ * 512 * 2);
    bf16*  W_enc_b  = (bf16*) alloc((size_t)512 * 2048 * 2);
    bf16*  W_dec_b  = (bf16*) alloc((size_t)512 * 512 * 2);
    bf16*  W_beta_b = (bf16*) alloc((size_t)2048 * 512 * 2);
    bf16*  W_ih_b   = (bf16*) alloc((size_t)2048 * 2560 * 2);
    bf16*  W_hh_b   = (bf16*) alloc((size_t)2048 * 512 * 2);
    bf16*  W_fc_b   = (bf16*) alloc((size_t)32000 * 512 * 2);
    bf16*  W_inh_b  = (bf16*) alloc((size_t)512 * 2048 * 2);
    bf16*  W_inc_b  = (bf16*) alloc((size_t)512 * 2048 * 2);

    k_order<<<1, B_, 0, stream>>>(caplen, caps, order_i, declen_i, caps_i, out, bar);
    k_cvt_enc<<<12544, 256, 0, stream>>>(enc, order_i, enc_s);
    k_meanb<<<dim3(B_, 8), 256, 0, stream>>>(enc_s, mean_b);

    auto cvt = [&](const float* src, bf16* dst, long n) {
        k_cvt<<<(int)((n / 8 + 255) / 256), 256, 0, stream>>>(src, dst, n);
    };
    cvt(W_enc_att, W_enc_b, 512L * 2048);
    cvt(W_dec_att, W_dec_b, 512L * 512);
    cvt(W_beta,    W_beta_b, 2048L * 512);
    cvt(W_ih,      W_ih_b,  2048L * 2560);
    cvt(W_hh,      W_hh_b,  2048L * 512);
    cvt(W_fc,      W_fc_b,  32000L * 512);
    cvt(W_init_h,  W_inh_b, 512L * 2048);
    cvt(W_init_c,  W_inc_b, 512L * 2048);

    // init: [h|c] = mean_b @ [W_init_h|W_init_c]^T  (N-split), then LN
    k_mgemm<1, 0, 0><<<dim3(1, 8, 1), 256, 0, stream>>>(mean_b, 2048, W_inh_b, W_inc_b,
        nullptr, pi, nullptr, 1024, 2048, 1, 512, nullptr);
    k_initln<<<B_, 512, 0, stream>>>(pi, b_init_h, b_init_c, g_h, be_h, g_c, be_c, xh, cbuf);

    // att1 = enc_s @ W_enc^T + b -> bf16 [12544][512]; 784 blocks XCD-chunked
    k_mgemm<0, 1, 1><<<784, 256, 0, stream>>>(enc_s, 2048, W_enc_b, nullptr,
        b_enc_att, nullptr, att1_b, 512, 2048, 1, 0, nullptr);

    // all 31 steps in one persistent kernel (256 blocks = 1/CU, device barrier)
    k_steps<<<NBLK_, 256, 0, stream>>>(att1_b, enc_s, W_dec_b, W_beta_b, W_ih_b, W_hh_b,
        b_dec_att, b_beta, W_full, b_ih, b_hh, g_h, be_h, g_c, be_c,
        caps_i, declen_i, emb, xh, cbuf, att2gate, gp, hseq, out, bar);

    // preds = hseq @ W_fc^T + b_fc (M=1984, masked scatter); 7750 blocks XCD-chunked
    k_mgemm<0, 2, 2><<<7750, 256, 0, stream>>>(hseq, 512, W_fc_b, nullptr,
        b_fc, out, nullptr, V_, 512, 1, 0, declen_i);
}

// Round 6
// 4495.402 us; speedup vs baseline: 1.9892x; 1.9892x over previous
//
#include <hip/hip_runtime.h>
#include <cfloat>
#include <math.h>

#define B_ 64
#define P_ 196
#define ENC_ 2048
#define D_ 512
#define V_ 32000
#define L_ 32
#define T_ 31

// flat f32 output layout (reference return order)
#define OUT_PREDS 0L
#define OUT_CAPS  63488000L              // 64*31*32000
#define OUT_DECL  63490048L              // +64*32
#define OUT_ALPH  63490112L              // +64
#define OUT_ORDER 63878976L              // +64*31*196

typedef __bf16 bf16;
typedef __bf16 bf16x8 __attribute__((ext_vector_type(8)));
typedef __bf16 bf16x4 __attribute__((ext_vector_type(4)));
typedef __bf16 bf16x2 __attribute__((ext_vector_type(2)));
typedef float  f32x4  __attribute__((ext_vector_type(4)));

static __device__ __forceinline__ float sigmoidf_(float x) { return 1.f / (1.f + __expf(-x)); }

// ------- sort by length, caps gather, scalar outputs, active-row compaction -------
__global__ void k_order(const int* __restrict__ cap_len, const int* __restrict__ caps,
                        int* __restrict__ order_i, int* __restrict__ declen_i,
                        int* __restrict__ caps_i, float* __restrict__ out,
                        int* __restrict__ rmap, int* __restrict__ orow, int* __restrict__ mact)
{
    __shared__ int len_s[B_], dl_s[B_];
    int tid = threadIdx.x;
    len_s[tid] = cap_len[tid];
    __syncthreads();
    int li = len_s[tid];
    int pos = 0;
    for (int j = 0; j < B_; ++j) {
        int lj = len_s[j];
        pos += (lj > li) || (lj == li && j < tid);   // stable descending rank
    }
    order_i[pos]  = tid;
    declen_i[pos] = li - 1;
    dl_s[pos]     = li - 1;
    out[OUT_ORDER + pos] = (float)tid;
    out[OUT_DECL  + pos] = (float)(li - 1);
    for (int l = 0; l < L_; ++l) {
        int tok = caps[tid * L_ + l];
        caps_i[pos * L_ + l] = tok;
        out[OUT_CAPS + pos * L_ + l] = (float)tok;
    }
    __syncthreads();
    // compaction: list of active (b,t) rows; rmap -> hseq row (t*64+b), orow -> out row (b*T+t)
    int p = tid;
    int off = 0;
    for (int j = 0; j < p; ++j) off += dl_s[j];
    int dl = dl_s[p];
    for (int tt = 0; tt < dl; ++tt) {
        rmap[off + tt] = tt * B_ + p;
        orow[off + tt] = p * T_ + tt;
    }
    if (p == B_ - 1) {
        int M = off + dl;
        mact[0] = M;
        int Mr = (M + 63) & ~63;
        for (int i = M; i < Mr; ++i) { rmap[i] = 0; orow[i] = -1; }
    }
}

// ---------------- f32 -> bf16 convert (8/thread) ----------------
__global__ __launch_bounds__(256) void k_cvt(const float* __restrict__ in, bf16* __restrict__ ob, long n)
{
    long i = ((long)blockIdx.x * 256 + threadIdx.x) * 8;
    if (i >= n) return;
    float4 a = *(const float4*)(in + i);
    float4 b = *(const float4*)(in + i + 4);
    bf16x8 v;
    v[0]=(bf16)a.x; v[1]=(bf16)a.y; v[2]=(bf16)a.z; v[3]=(bf16)a.w;
    v[4]=(bf16)b.x; v[5]=(bf16)b.y; v[6]=(bf16)b.z; v[7]=(bf16)b.w;
    *(bf16x8*)(ob + i) = v;
}

// ---------------- enc gather-by-order + convert to bf16 ----------------
__global__ __launch_bounds__(256) void k_cvt_enc(const float* __restrict__ enc,
                                                 const int* __restrict__ order_i,
                                                 bf16* __restrict__ enc_s)
{
    long i = ((long)blockIdx.x * 256 + threadIdx.x) * 8;
    int b = (int)(i / ((long)P_ * ENC_));
    long rem = i - (long)b * P_ * ENC_;
    const float* src = enc + (long)order_i[b] * P_ * ENC_ + rem;
    float4 a = *(const float4*)(src);
    float4 c = *(const float4*)(src + 4);
    bf16x8 v;
    v[0]=(bf16)a.x; v[1]=(bf16)a.y; v[2]=(bf16)a.z; v[3]=(bf16)a.w;
    v[4]=(bf16)c.x; v[5]=(bf16)c.y; v[6]=(bf16)c.z; v[7]=(bf16)c.w;
    *(bf16x8*)(enc_s + i) = v;
}

// ---------------- mean over pixels (bf16 in/out) ----------------
__global__ __launch_bounds__(256) void k_meanb(const bf16* __restrict__ enc_s, bf16* __restrict__ mean_b)
{
    int b = blockIdx.x, col = blockIdx.y * 256 + threadIdx.x;
    float s = 0.f;
    const bf16* eb = enc_s + (long)b * P_ * ENC_ + col;
    for (int p = 0; p < P_; ++p) s += (float)eb[(long)p * ENC_];
    mean_b[(long)b * ENC_ + col] = (bf16)(s * (1.f / (float)P_));
}

// ---------------- MFMA GEMM: C[M][N] = A[M][K](bf16) * B[N][K]^T(bf16) ------
// 256 thr = 4 waves; tile (MI*16) x 128; swapped-operand mfma -> dwordx4 stores.
// FUSE: 0=single B, 1=N-split at Nsp, 2=K-split at Ksp (B1 rows Ksp wide, B2 rows K-Ksp wide)
// EPI:  0=RAW f32 partial slot z (M=64), 1=bf16 +bias
// SWZ:  0=3D grid; 1=att1 392 blocks XCD-chunked (mt=wg>>2, nt=wg&3)
template<int MI, int FUSE, int EPI, int SWZ>
__global__ void __launch_bounds__(256)
k_mgemm(const bf16* __restrict__ A, long lda,
        const bf16* __restrict__ B1, const bf16* __restrict__ B2,
        const float* __restrict__ bias,
        float* __restrict__ Cf, bf16* __restrict__ Cb,
        int N, int K, int kspl, int Nsp, int Ksp)
{
    const int tid = threadIdx.x;
    const int lane = tid & 63, w = tid >> 6;
    int mt, nt, z;
    if (SWZ == 0) { mt = blockIdx.x; nt = blockIdx.y; z = blockIdx.z; }
    else          { int o = blockIdx.x; int wg = (o & 7) * 49 + (o >> 3);
                    mt = wg >> 2; nt = wg & 3; z = 0; }
    const int krange = K / kspl;
    const int k0 = z * krange, k1 = k0 + krange;
    const int r16 = lane & 15, kq = lane >> 4;
    const int koff = kq * 8;

    const bf16* Ap = A + (long)(mt * (MI * 16) + r16) * lda + koff;
    const int ncol0 = nt * 128 + w * 32;

    const bf16* Bp[2];
    const bf16* B2p[2];
#pragma unroll
    for (int ni = 0; ni < 2; ++ni) {
        int n = ncol0 + ni * 16 + r16;
        if (FUSE == 1)
            Bp[ni] = (n < Nsp) ? B1 + (long)n * K + koff
                               : B2 + (long)(n - Nsp) * K + koff;
        else if (FUSE == 2) {
            Bp[ni]  = B1 + (long)n * Ksp + koff;
            B2p[ni] = B2 + (long)n * (K - Ksp) + koff - Ksp;  // +kk yields col kk-Ksp
        } else
            Bp[ni] = B1 + (long)n * K + koff;
    }

    auto loadA = [&](int kk, bf16x8* dst) {
#pragma unroll
        for (int mi = 0; mi < MI; ++mi)
            dst[mi] = *(const bf16x8*)(Ap + (long)mi * 16 * lda + kk);
    };
    auto loadB = [&](int kk, bf16x8* dst) {
#pragma unroll
        for (int ni = 0; ni < 2; ++ni) {
            if (FUSE == 2 && kk >= Ksp) dst[ni] = *(const bf16x8*)(B2p[ni] + kk);
            else                        dst[ni] = *(const bf16x8*)(Bp[ni] + kk);
        }
    };

    f32x4 acc[MI][2] = {};
    bf16x8 af[MI], bfr[2];
    loadA(k0, af); loadB(k0, bfr);
    for (int kk = k0 + 32; kk < k1; kk += 32) {
        bf16x8 af2[MI], bf2[2];
        loadA(kk, af2); loadB(kk, bf2);
#pragma unroll
        for (int mi = 0; mi < MI; ++mi)
#pragma unroll
            for (int ni = 0; ni < 2; ++ni)   // swapped operands: lane->row, regs->cols
                acc[mi][ni] = __builtin_amdgcn_mfma_f32_16x16x32_bf16(bfr[ni], af[mi], acc[mi][ni], 0, 0, 0);
#pragma unroll
        for (int mi = 0; mi < MI; ++mi) af[mi] = af2[mi];
#pragma unroll
        for (int ni = 0; ni < 2; ++ni) bfr[ni] = bf2[ni];
    }
#pragma unroll
    for (int mi = 0; mi < MI; ++mi)
#pragma unroll
        for (int ni = 0; ni < 2; ++ni)
            acc[mi][ni] = __builtin_amdgcn_mfma_f32_16x16x32_bf16(bfr[ni], af[mi], acc[mi][ni], 0, 0, 0);

#pragma unroll
    for (int mi = 0; mi < MI; ++mi) {
        const int row = mt * (MI * 16) + mi * 16 + r16;
#pragma unroll
        for (int ni = 0; ni < 2; ++ni) {
            const int col = ncol0 + ni * 16 + kq * 4;
            f32x4 v = acc[mi][ni];
            if (EPI == 0) {
                *(f32x4*)(Cf + (long)z * 64 * N + (long)row * N + col) = v;
            } else {
                f32x4 bv = *(const f32x4*)(bias + col);
                bf16x4 o;
                o[0]=(bf16)(v[0]+bv[0]); o[1]=(bf16)(v[1]+bv[1]);
                o[2]=(bf16)(v[2]+bv[2]); o[3]=(bf16)(v[3]+bv[3]);
                *(bf16x4*)(Cb + (long)row * N + col) = o;
            }
        }
    }
}

// ---------------- LN stats helper (blockDim=512) ----------------
static __device__ __forceinline__ void ln_stats(float x, float* r1, float* r2,
                                                float& m, float& var)
{
    int tid = threadIdx.x;
    r1[tid] = x; r2[tid] = x * x;
    __syncthreads();
    for (int s = 256; s > 0; s >>= 1) {
        if (tid < s) { r1[tid] += r1[tid + s]; r2[tid] += r2[tid + s]; }
        __syncthreads();
    }
    m = r1[0] * (1.f / 512.f);
    var = r2[0] * (1.f / 512.f) - m * m;
    __syncthreads();
}

// ------- att2|gate matvec from f32 h in LDS: n = d + j*512, j<5 -------
static __device__ __forceinline__ void att2gate_mv(const float* h_s, const bf16* Wd,
                                                   const bf16* Wbt, float* att2g, int b)
{
    const int d = threadIdx.x;
#pragma unroll
    for (int j = 0; j < 5; ++j) {
        const int n = d + j * 512;
        const bf16* wr = (n < 512) ? (Wd + (long)n * 512) : (Wbt + (long)(n - 512) * 512);
        float acc = 0.f;
        for (int k = 0; k < 512; k += 8) {
            bf16x8 wv = *(const bf16x8*)(wr + k);
#pragma unroll
            for (int q = 0; q < 8; ++q) acc += h_s[k + q] * (float)wv[q];
        }
        att2g[(long)b * 2560 + n] = acc;
    }
}

// ---------------- init h,c = LN(mean_enc @ W^T + b) + att2gate for t=0 ----------------
__global__ __launch_bounds__(512)
void k_initln(const float* __restrict__ pi,
              const float* __restrict__ b_h, const float* __restrict__ b_c,
              const float* __restrict__ g_h, const float* __restrict__ be_h,
              const float* __restrict__ g_c, const float* __restrict__ be_c,
              const bf16* __restrict__ Wd, const bf16* __restrict__ Wbt,
              bf16* __restrict__ xh, float* __restrict__ c, float* __restrict__ att2g)
{
    int b = blockIdx.x, d = threadIdx.x;
    float yh = pi[(long)b * 1024 + d]       + b_h[d];
    float yc = pi[(long)b * 1024 + 512 + d] + b_c[d];
    __shared__ float r1[512], r2[512], h_s[512];
    float m, v;
    ln_stats(yh, r1, r2, m, v);
    float hln = (yh - m) * rsqrtf(v + 1e-5f) * g_h[d] + be_h[d];
    xh[(long)b * 3072 + 2560 + d] = (bf16)hln;
    h_s[d] = hln;
    ln_stats(yc, r1, r2, m, v);
    c[(long)b * 512 + d] = (yc - m) * rsqrtf(v + 1e-5f) * g_c[d] + be_c[d];
    __syncthreads();
    att2gate_mv(h_s, Wd, Wbt, att2g, b);
}

// ------- fused attention: alpha + awe*gate + emb; 256 blocks = (b, seg) -------
__global__ __launch_bounds__(256)
void k_attn(const float* __restrict__ att2g, const float* __restrict__ b_dec,
            const float* __restrict__ b_beta, const float* __restrict__ Wfull,
            const bf16* __restrict__ att1_b, const bf16* __restrict__ enc_s,
            const int* __restrict__ caps_i, const int* __restrict__ declen_i,
            const float* __restrict__ emb,
            bf16* __restrict__ xh, float* __restrict__ out, int t)
{
    const int b = blockIdx.x >> 2, seg = blockIdx.x & 3, tid = threadIdx.x;
    if (t >= declen_i[b]) {
        if (seg == 1 && tid < P_) out[OUT_ALPH + ((long)b * T_ + t) * P_ + tid] = 0.f;
        return;
    }
    __shared__ float att2s[512], wf[512], red[256], alp[P_];
    for (int i = tid; i < 512; i += 256) {
        att2s[i] = att2g[(long)b * 2560 + i] + b_dec[i];
        wf[i] = Wfull[i];
    }
    __syncthreads();
    float ev = -FLT_MAX;
    if (tid < P_) {
        const bf16* ar = att1_b + ((long)b * P_ + tid) * 512;
        float acc = 0.f;
        for (int a0 = 0; a0 < 512; a0 += 8) {
            bf16x8 v = *(const bf16x8*)(ar + a0);
#pragma unroll
            for (int j = 0; j < 8; ++j)
                acc += fmaxf((float)v[j] + att2s[a0 + j], 0.f) * wf[a0 + j];
        }
        ev = acc;   // + b_full: softmax-invariant
    }
    red[tid] = ev;
    __syncthreads();
    for (int s = 128; s > 0; s >>= 1) { if (tid < s) red[tid] = fmaxf(red[tid], red[tid + s]); __syncthreads(); }
    float mx = red[0];
    __syncthreads();
    float ex = (tid < P_) ? __expf(ev - mx) : 0.f;
    red[tid] = ex;
    __syncthreads();
    for (int s = 128; s > 0; s >>= 1) { if (tid < s) red[tid] += red[tid + s]; __syncthreads(); }
    float inv = 1.f / red[0];
    if (tid < P_) alp[tid] = ex * inv;
    __syncthreads();
    if (seg == 1 && tid < P_)
        out[OUT_ALPH + ((long)b * T_ + t) * P_ + tid] = alp[tid];
    // awe for this 512-col segment
    const int c0 = seg * 512 + tid * 2;
    const bf16* eb = enc_s + (long)b * P_ * ENC_ + c0;
    float a0 = 0.f, a1 = 0.f;
#pragma unroll 4
    for (int p = 0; p < P_; ++p) {
        bf16x2 v = *(const bf16x2*)(eb + (long)p * ENC_);
        float al = alp[p];
        a0 += al * (float)v[0]; a1 += al * (float)v[1];
    }
    float g0 = b_beta[c0]     + att2g[(long)b * 2560 + 512 + c0];
    float g1 = b_beta[c0 + 1] + att2g[(long)b * 2560 + 512 + c0 + 1];
    bf16x2 o;
    o[0] = (bf16)(a0 * sigmoidf_(g0));
    o[1] = (bf16)(a1 * sigmoidf_(g1));
    *(bf16x2*)(xh + (long)b * 3072 + 512 + c0) = o;
    if (seg == 0) {
        int tok = caps_i[b * L_ + t];
        for (int i = tid; i < 512; i += 256)
            xh[(long)b * 3072 + i] = (bf16)emb[(long)tok * 512 + i];
    }
}

// -------- LSTM + 2x LN + state update + hseq + next-step att2gate --------
__global__ __launch_bounds__(512)
void k_lstm(const float* __restrict__ gp, const float* __restrict__ b_ih, const float* __restrict__ b_hh,
            const float* __restrict__ g_h, const float* __restrict__ be_h,
            const float* __restrict__ g_c, const float* __restrict__ be_c,
            const bf16* __restrict__ Wd, const bf16* __restrict__ Wbt,
            bf16* __restrict__ xh, float* __restrict__ c, bf16* __restrict__ hseq,
            float* __restrict__ att2g, const int* __restrict__ declen_i, int t)
{
    int b = blockIdx.x, d = threadIdx.x;
    if (t >= declen_i[b]) return;
    float iv = b_ih[d]        + b_hh[d];
    float fv = b_ih[512 + d]  + b_hh[512 + d];
    float gv = b_ih[1024 + d] + b_hh[1024 + d];
    float ov = b_ih[1536 + d] + b_hh[1536 + d];
#pragma unroll
    for (int s = 0; s < 8; ++s) {
        const float* gs = gp + ((long)s * B_ + b) * 2048;
        iv += gs[d]; fv += gs[512 + d]; gv += gs[1024 + d]; ov += gs[1536 + d];
    }
    float cn = sigmoidf_(fv) * c[(long)b * 512 + d] + sigmoidf_(iv) * tanhf(gv);
    float hn = sigmoidf_(ov) * tanhf(cn);
    __shared__ float r1[512], r2[512], h_s[512];
    float m, v;
    ln_stats(hn, r1, r2, m, v);
    float hln = (hn - m) * rsqrtf(v + 1e-5f) * g_h[d] + be_h[d];
    ln_stats(cn, r1, r2, m, v);
    float cln = (cn - m) * rsqrtf(v + 1e-5f) * g_c[d] + be_c[d];
    bf16 hv = (bf16)hln;
    xh[(long)b * 3072 + 2560 + d] = hv;
    hseq[((long)t * B_ + b) * 512 + d] = hv;
    c[(long)b * 512 + d] = cln;
    h_s[d] = hln;
    __syncthreads();
    att2gate_mv(h_s, Wd, Wbt, att2g, b);
}

// -------- zero-fill inactive pred rows --------
__global__ __launch_bounds__(256) void k_zero(const int* __restrict__ declen_i, float* __restrict__ out)
{
    int x = blockIdx.x;
    int b = x / T_, t = x - b * T_;
    if (t < declen_i[b]) return;
    float4 z = {0.f, 0.f, 0.f, 0.f};
    long base = OUT_PREDS + ((long)b * T_ + t) * V_;
    for (int i = threadIdx.x * 4; i < V_; i += 1024)
        *(float4*)(out + base + i) = z;
}

// -------- preds over compacted active rows; LDS-staged coalesced epilogue --------
__global__ __launch_bounds__(256)
void k_preds(const bf16* __restrict__ hseq, const bf16* __restrict__ Wfc,
             const float* __restrict__ bias,
             const int* __restrict__ rmap, const int* __restrict__ orow,
             const int* __restrict__ mact, float* __restrict__ out)
{
    int o = blockIdx.x; int xcd = o & 7;
    int base = xcd < 6 ? xcd * 969 : 5814 + (xcd - 6) * 968;
    int wg = base + (o >> 3);
    int nt = wg / 31, mt = wg - 31 * nt;
    if (mt * 64 >= mact[0]) return;
    __shared__ int rs[64], os[64];
    __shared__ __align__(16) float ct[64][132];
    const int tid = threadIdx.x, lane = tid & 63, w = tid >> 6;
    const int r16 = lane & 15, kq = lane >> 4, koff = kq * 8;
    if (tid < 64) { rs[tid] = rmap[mt * 64 + tid]; os[tid] = orow[mt * 64 + tid]; }
    __syncthreads();
    const int ncol0 = nt * 128 + w * 32;
    const bf16* Ap[4];
#pragma unroll
    for (int mi = 0; mi < 4; ++mi)
        Ap[mi] = hseq + (long)rs[mi * 16 + r16] * 512 + koff;
    const bf16* Bp[2];
#pragma unroll
    for (int ni = 0; ni < 2; ++ni)
        Bp[ni] = Wfc + (long)(ncol0 + ni * 16 + r16) * 512 + koff;

    f32x4 acc[4][2] = {};
    bf16x8 af[4], bfr[2];
#pragma unroll
    for (int mi = 0; mi < 4; ++mi) af[mi] = *(const bf16x8*)(Ap[mi]);
#pragma unroll
    for (int ni = 0; ni < 2; ++ni) bfr[ni] = *(const bf16x8*)(Bp[ni]);
    for (int kk = 32; kk < 512; kk += 32) {
        bf16x8 af2[4], bf2[2];
#pragma unroll
        for (int mi = 0; mi < 4; ++mi) af2[mi] = *(const bf16x8*)(Ap[mi] + kk);
#pragma unroll
        for (int ni = 0; ni < 2; ++ni) bf2[ni] = *(const bf16x8*)(Bp[ni] + kk);
#pragma unroll
        for (int mi = 0; mi < 4; ++mi)
#pragma unroll
            for (int ni = 0; ni < 2; ++ni)
                acc[mi][ni] = __builtin_amdgcn_mfma_f32_16x16x32_bf16(bfr[ni], af[mi], acc[mi][ni], 0, 0, 0);
#pragma unroll
        for (int mi = 0; mi < 4; ++mi) af[mi] = af2[mi];
#pragma unroll
        for (int ni = 0; ni < 2; ++ni) bfr[ni] = bf2[ni];
    }
#pragma unroll
    for (int mi = 0; mi < 4; ++mi)
#pragma unroll
        for (int ni = 0; ni < 2; ++ni)
            acc[mi][ni] = __builtin_amdgcn_mfma_f32_16x16x32_bf16(bfr[ni], af[mi], acc[mi][ni], 0, 0, 0);

    // stage tile to LDS, then coalesced row stores (512B contiguous per row)
#pragma unroll
    for (int mi = 0; mi < 4; ++mi)
#pragma unroll
        for (int ni = 0; ni < 2; ++ni)
            *(f32x4*)&ct[mi * 16 + r16][w * 32 + ni * 16 + kq * 4] = acc[mi][ni];
    __syncthreads();
    const int r0 = tid >> 5, cc = (tid & 31) * 4;
    const int gcol = nt * 128 + cc;
    f32x4 bv = *(const f32x4*)(bias + gcol);
#pragma unroll
    for (int it = 0; it < 8; ++it) {
        int r = it * 8 + r0;
        int orv = os[r];
        if (orv >= 0) {
            f32x4 v = *(f32x4*)&ct[r][cc];
            f32x4 oo;
            oo[0] = v[0] + bv[0]; oo[1] = v[1] + bv[1];
            oo[2] = v[2] + bv[2]; oo[3] = v[3] + bv[3];
            *(f32x4*)(out + OUT_PREDS + (long)orv * V_ + gcol) = oo;
        }
    }
}

extern "C" void kernel_launch(void* const* d_in, const int* in_sizes, int n_in,
                              void* d_out, int out_size, void* d_ws, size_t ws_size,
                              hipStream_t stream)
{
    const float* enc       = (const float*)d_in[0];
    const int*   caps      = (const int*)  d_in[1];
    const int*   caplen    = (const int*)  d_in[2];
    const float* emb       = (const float*)d_in[3];
    const float* W_enc_att = (const float*)d_in[4];
    const float* b_enc_att = (const float*)d_in[5];
    const float* W_dec_att = (const float*)d_in[6];
    const float* b_dec_att = (const float*)d_in[7];
    const float* W_full    = (const float*)d_in[8];
    // d_in[9] = b_full (softmax-invariant, unused)
    const float* W_ih      = (const float*)d_in[10];
    const float* b_ih      = (const float*)d_in[11];
    const float* W_hh      = (const float*)d_in[12];
    const float* b_hh      = (const float*)d_in[13];
    const float* g_h       = (const float*)d_in[14];
    const float* be_h      = (const float*)d_in[15];
    const float* g_c       = (const float*)d_in[16];
    const float* be_c      = (const float*)d_in[17];
    const float* W_init_h  = (const float*)d_in[18];
    const float* b_init_h  = (const float*)d_in[19];
    const float* W_init_c  = (const float*)d_in[20];
    const float* b_init_c  = (const float*)d_in[21];
    const float* W_beta    = (const float*)d_in[22];
    const float* b_beta    = (const float*)d_in[23];
    const float* W_fc      = (const float*)d_in[24];
    const float* b_fc      = (const float*)d_in[25];
    float* out = (float*)d_out;

    char* w = (char*)d_ws;
    auto alloc = [&](size_t bytes) { char* p = w; w += (bytes + 255) & ~(size_t)255; return p; };
    int*   order_i  = (int*)  alloc(B_ * 4);
    int*   declen_i = (int*)  alloc(B_ * 4);
    int*   caps_i   = (int*)  alloc(B_ * L_ * 4);
    int*   rmap     = (int*)  alloc(2048 * 4);
    int*   orow     = (int*)  alloc(2048 * 4);
    int*   mact     = (int*)  alloc(256);
    bf16*  enc_s    = (bf16*) alloc((size_t)B_ * P_ * ENC_ * 2);
    bf16*  mean_b   = (bf16*) alloc((size_t)B_ * ENC_ * 2);
    bf16*  att1_b   = (bf16*) alloc((size_t)B_ * P_ * 512 * 2);
    float* pi       = (float*)alloc((size_t)B_ * 1024 * 4);
    float* att2g    = (float*)alloc((size_t)B_ * 2560 * 4);
    bf16*  xh       = (bf16*) alloc((size_t)B_ * 3072 * 2);
    float* gp       = (float*)alloc((size_t)8 * B_ * 2048 * 4);
    float* cbuf     = (float*)alloc((size_t)B_ * 512 * 4);
    bf16*  hseq     = (bf16*) alloc((size_t)T_ * B_ * 512 * 2);
    bf16*  W_enc_b  = (bf16*) alloc((size_t)512 * 2048 * 2);
    bf16*  W_dec_b  = (bf16*) alloc((size_t)512 * 512 * 2);
    bf16*  W_beta_b = (bf16*) alloc((size_t)2048 * 512 * 2);
    bf16*  W_ih_b   = (bf16*) alloc((size_t)2048 * 2560 * 2);
    bf16*  W_hh_b   = (bf16*) alloc((size_t)2048 * 512 * 2);
    bf16*  W_fc_b   = (bf16*) alloc((size_t)32000 * 512 * 2);
    bf16*  W_inh_b  = (bf16*) alloc((size_t)512 * 2048 * 2);
    bf16*  W_inc_b  = (bf16*) alloc((size_t)512 * 2048 * 2);

    k_order<<<1, B_, 0, stream>>>(caplen, caps, order_i, declen_i, caps_i, out, rmap, orow, mact);
    k_cvt_enc<<<12544, 256, 0, stream>>>(enc, order_i, enc_s);
    k_meanb<<<dim3(B_, 8), 256, 0, stream>>>(enc_s, mean_b);

    auto cvt = [&](const float* src, bf16* dst, long n) {
        k_cvt<<<(int)((n / 8 + 255) / 256), 256, 0, stream>>>(src, dst, n);
    };
    cvt(W_enc_att, W_enc_b, 512L * 2048);
    cvt(W_dec_att, W_dec_b, 512L * 512);
    cvt(W_beta,    W_beta_b, 2048L * 512);
    cvt(W_ih,      W_ih_b,  2048L * 2560);
    cvt(W_hh,      W_hh_b,  2048L * 512);
    cvt(W_fc,      W_fc_b,  32000L * 512);
    cvt(W_init_h,  W_inh_b, 512L * 2048);
    cvt(W_init_c,  W_inc_b, 512L * 2048);

    // init: [h|c] = mean_b @ [W_init_h|W_init_c]^T (N-split), then LN + att2gate(t=0)
    k_mgemm<4, 1, 0, 0><<<dim3(1, 8, 1), 256, 0, stream>>>(mean_b, 2048, W_inh_b, W_inc_b,
        nullptr, pi, nullptr, 1024, 2048, 1, 512, 0);
    k_initln<<<B_, 512, 0, stream>>>(pi, b_init_h, b_init_c, g_h, be_h, g_c, be_c,
        W_dec_b, W_beta_b, xh, cbuf, att2g);

    // att1 = enc_s @ W_enc^T + b -> bf16 [12544][512]; BM=128, 392 blocks XCD-chunked
    k_mgemm<8, 0, 1, 1><<<392, 256, 0, stream>>>(enc_s, 2048, W_enc_b, nullptr,
        b_enc_att, nullptr, att1_b, 512, 2048, 1, 0, 0);

    for (int t = 0; t < T_; ++t) {
        k_attn<<<256, 256, 0, stream>>>(att2g, b_dec_att, b_beta, W_full, att1_b, enc_s,
            caps_i, declen_i, emb, xh, out, t);
        // gates = xh @ [W_ih ; W_hh]^T (K-split at 2560, split-K S=8)
        k_mgemm<4, 2, 0, 0><<<dim3(1, 16, 8), 256, 0, stream>>>(xh, 3072, W_ih_b, W_hh_b,
            nullptr, gp, nullptr, 2048, 3072, 8, 0, 2560);
        k_lstm<<<B_, 512, 0, stream>>>(gp, b_ih, b_hh, g_h, be_h, g_c, be_c,
            W_dec_b, W_beta_b, xh, cbuf, hseq, att2g, declen_i, t);
    }

    // inactive rows -> zeros; active rows -> compacted GEMM with coalesced epilogue
    k_zero<<<B_ * T_, 256, 0, stream>>>(declen_i, out);
    k_preds<<<7750, 256, 0, stream>>>(hseq, W_fc_b, b_fc, rmap, orow, mact, out);
}

// Round 7
// 4089.495 us; speedup vs baseline: 2.1867x; 1.0993x over previous
//
#include <hip/hip_runtime.h>
#include <cfloat>
#include <math.h>

#define B_ 64
#define P_ 196
#define ENC_ 2048
#define D_ 512
#define V_ 32000
#define L_ 32
#define T_ 31

// flat f32 output layout (reference return order)
#define OUT_PREDS 0L
#define OUT_CAPS  63488000L              // 64*31*32000
#define OUT_DECL  63490048L              // +64*32
#define OUT_ALPH  63490112L              // +64
#define OUT_ORDER 63878976L              // +64*31*196

typedef __bf16 bf16;
typedef __bf16 bf16x8 __attribute__((ext_vector_type(8)));
typedef __bf16 bf16x4 __attribute__((ext_vector_type(4)));
typedef float  f32x4  __attribute__((ext_vector_type(4)));

static __device__ __forceinline__ float sigmoidf_(float x) { return 1.f / (1.f + __expf(-x)); }

// ------- sort by length, caps gather, scalar outputs, active-row compaction -------
__global__ void k_order(const int* __restrict__ cap_len, const int* __restrict__ caps,
                        int* __restrict__ order_i, int* __restrict__ declen_i,
                        int* __restrict__ caps_i, float* __restrict__ out,
                        int* __restrict__ rmap, int* __restrict__ orow, int* __restrict__ mact)
{
    __shared__ int len_s[B_], dl_s[B_];
    int tid = threadIdx.x;
    len_s[tid] = cap_len[tid];
    __syncthreads();
    int li = len_s[tid];
    int pos = 0;
    for (int j = 0; j < B_; ++j) {
        int lj = len_s[j];
        pos += (lj > li) || (lj == li && j < tid);   // stable descending rank
    }
    order_i[pos]  = tid;
    declen_i[pos] = li - 1;
    dl_s[pos]     = li - 1;
    out[OUT_ORDER + pos] = (float)tid;
    out[OUT_DECL  + pos] = (float)(li - 1);
    for (int l = 0; l < L_; ++l) {
        int tok = caps[tid * L_ + l];
        caps_i[pos * L_ + l] = tok;
        out[OUT_CAPS + pos * L_ + l] = (float)tok;
    }
    __syncthreads();
    int p = tid;
    int off = 0;
    for (int j = 0; j < p; ++j) off += dl_s[j];
    int dl = dl_s[p];
    for (int tt = 0; tt < dl; ++tt) {
        rmap[off + tt] = tt * B_ + p;
        orow[off + tt] = p * T_ + tt;
    }
    if (p == B_ - 1) {
        int M = off + dl;
        mact[0] = M;
        int Mr = (M + 63) & ~63;
        for (int i = M; i < Mr; ++i) { rmap[i] = 0; orow[i] = -1; }
    }
}

// ---------------- merged f32 -> bf16 convert for all 8 weight mats ----------------
struct CvtSegs { const float* s[8]; bf16* d[8]; long cum[9]; };
__global__ __launch_bounds__(256) void k_cvt_all(CvtSegs cs)
{
    long i8 = ((long)blockIdx.x * 256 + threadIdx.x) * 8;
    if (i8 >= cs.cum[8]) return;
    int k = 0;
    while (i8 >= cs.cum[k + 1]) ++k;
    long loc = i8 - cs.cum[k];
    const float* src = cs.s[k] + loc;
    float4 a = *(const float4*)(src);
    float4 b = *(const float4*)(src + 4);
    bf16x8 v;
    v[0]=(bf16)a.x; v[1]=(bf16)a.y; v[2]=(bf16)a.z; v[3]=(bf16)a.w;
    v[4]=(bf16)b.x; v[5]=(bf16)b.y; v[6]=(bf16)b.z; v[7]=(bf16)b.w;
    *(bf16x8*)(cs.d[k] + loc) = v;
}

// ---------------- enc gather-by-order + convert to bf16 ----------------
__global__ __launch_bounds__(256) void k_cvt_enc(const float* __restrict__ enc,
                                                 const int* __restrict__ order_i,
                                                 bf16* __restrict__ enc_s)
{
    long i = ((long)blockIdx.x * 256 + threadIdx.x) * 8;
    int b = (int)(i / ((long)P_ * ENC_));
    long rem = i - (long)b * P_ * ENC_;
    const float* src = enc + (long)order_i[b] * P_ * ENC_ + rem;
    float4 a = *(const float4*)(src);
    float4 c = *(const float4*)(src + 4);
    bf16x8 v;
    v[0]=(bf16)a.x; v[1]=(bf16)a.y; v[2]=(bf16)a.z; v[3]=(bf16)a.w;
    v[4]=(bf16)c.x; v[5]=(bf16)c.y; v[6]=(bf16)c.z; v[7]=(bf16)c.w;
    *(bf16x8*)(enc_s + i) = v;
}

// ---------------- mean over pixels ----------------
__global__ __launch_bounds__(256) void k_meanb(const bf16* __restrict__ enc_s, bf16* __restrict__ mean_b)
{
    int b = blockIdx.x, col = blockIdx.y * 256 + threadIdx.x;
    float s = 0.f;
    const bf16* eb = enc_s + (long)b * P_ * ENC_ + col;
    for (int p = 0; p < P_; ++p) s += (float)eb[(long)p * ENC_];
    mean_b[(long)b * ENC_ + col] = (bf16)(s * (1.f / (float)P_));
}

// ---------------- MFMA GEMM (init / att1 / gates) ----------------
template<int MI, int FUSE, int EPI, int SWZ>
__global__ void __launch_bounds__(256)
k_mgemm(const bf16* __restrict__ A, long lda,
        const bf16* __restrict__ B1, const bf16* __restrict__ B2,
        const float* __restrict__ bias,
        float* __restrict__ Cf, bf16* __restrict__ Cb,
        int N, int K, int kspl, int Nsp, int Ksp)
{
    const int tid = threadIdx.x;
    const int lane = tid & 63, w = tid >> 6;
    int mt, nt, z;
    if (SWZ == 0) { mt = blockIdx.x; nt = blockIdx.y; z = blockIdx.z; }
    else          { int o = blockIdx.x; int wg = (o & 7) * 49 + (o >> 3);
                    mt = wg >> 2; nt = wg & 3; z = 0; }
    const int krange = K / kspl;
    const int k0 = z * krange, k1 = k0 + krange;
    const int r16 = lane & 15, kq = lane >> 4;
    const int koff = kq * 8;

    const bf16* Ap = A + (long)(mt * (MI * 16) + r16) * lda + koff;
    const int ncol0 = nt * 128 + w * 32;

    const bf16* Bp[2];
    const bf16* B2p[2];
#pragma unroll
    for (int ni = 0; ni < 2; ++ni) {
        int n = ncol0 + ni * 16 + r16;
        if (FUSE == 1)
            Bp[ni] = (n < Nsp) ? B1 + (long)n * K + koff
                               : B2 + (long)(n - Nsp) * K + koff;
        else if (FUSE == 2) {
            Bp[ni]  = B1 + (long)n * Ksp + koff;
            B2p[ni] = B2 + (long)n * (K - Ksp) + koff - Ksp;
        } else
            Bp[ni] = B1 + (long)n * K + koff;
    }

    auto loadA = [&](int kk, bf16x8* dst) {
#pragma unroll
        for (int mi = 0; mi < MI; ++mi)
            dst[mi] = *(const bf16x8*)(Ap + (long)mi * 16 * lda + kk);
    };
    auto loadB = [&](int kk, bf16x8* dst) {
#pragma unroll
        for (int ni = 0; ni < 2; ++ni) {
            if (FUSE == 2 && kk >= Ksp) dst[ni] = *(const bf16x8*)(B2p[ni] + kk);
            else                        dst[ni] = *(const bf16x8*)(Bp[ni] + kk);
        }
    };

    f32x4 acc[MI][2] = {};
    bf16x8 af[MI], bfr[2];
    loadA(k0, af); loadB(k0, bfr);
    for (int kk = k0 + 32; kk < k1; kk += 32) {
        bf16x8 af2[MI], bf2[2];
        loadA(kk, af2); loadB(kk, bf2);
#pragma unroll
        for (int mi = 0; mi < MI; ++mi)
#pragma unroll
            for (int ni = 0; ni < 2; ++ni)
                acc[mi][ni] = __builtin_amdgcn_mfma_f32_16x16x32_bf16(bfr[ni], af[mi], acc[mi][ni], 0, 0, 0);
#pragma unroll
        for (int mi = 0; mi < MI; ++mi) af[mi] = af2[mi];
#pragma unroll
        for (int ni = 0; ni < 2; ++ni) bfr[ni] = bf2[ni];
    }
#pragma unroll
    for (int mi = 0; mi < MI; ++mi)
#pragma unroll
        for (int ni = 0; ni < 2; ++ni)
            acc[mi][ni] = __builtin_amdgcn_mfma_f32_16x16x32_bf16(bfr[ni], af[mi], acc[mi][ni], 0, 0, 0);

#pragma unroll
    for (int mi = 0; mi < MI; ++mi) {
        const int row = mt * (MI * 16) + mi * 16 + r16;
#pragma unroll
        for (int ni = 0; ni < 2; ++ni) {
            const int col = ncol0 + ni * 16 + kq * 4;
            f32x4 v = acc[mi][ni];
            if (EPI == 0) {
                *(f32x4*)(Cf + (long)z * 64 * N + (long)row * N + col) = v;
            } else {
                f32x4 bv = *(const f32x4*)(bias + col);
                bf16x4 o;
                o[0]=(bf16)(v[0]+bv[0]); o[1]=(bf16)(v[1]+bv[1]);
                o[2]=(bf16)(v[2]+bv[2]); o[3]=(bf16)(v[3]+bv[3]);
                *(bf16x4*)(Cb + (long)row * N + col) = o;
            }
        }
    }
}

// ---------------- init h,c = LN(mean_enc @ W^T + b) ----------------
__global__ __launch_bounds__(512)
void k_initln(const float* __restrict__ pi,
              const float* __restrict__ b_h, const float* __restrict__ b_c,
              const float* __restrict__ g_h, const float* __restrict__ be_h,
              const float* __restrict__ g_c, const float* __restrict__ be_c,
              bf16* __restrict__ xh, float* __restrict__ hf, float* __restrict__ cbuf)
{
    int b = blockIdx.x, d = threadIdx.x;
    float yh = pi[(long)b * 1024 + d]       + b_h[d];
    float yc = pi[(long)b * 1024 + 512 + d] + b_c[d];
    __shared__ float r1[512], r2[512], r3[512], r4[512];
    r1[d] = yh; r2[d] = yh * yh; r3[d] = yc; r4[d] = yc * yc;
    __syncthreads();
    for (int s = 256; s > 0; s >>= 1) {
        if (d < s) { r1[d]+=r1[d+s]; r2[d]+=r2[d+s]; r3[d]+=r3[d+s]; r4[d]+=r4[d+s]; }
        __syncthreads();
    }
    float mh = r1[0] * (1.f/512.f), vh = r2[0] * (1.f/512.f) - mh*mh;
    float mc = r3[0] * (1.f/512.f), vc = r4[0] * (1.f/512.f) - mc*mc;
    float hln = (yh - mh) * rsqrtf(vh + 1e-5f) * g_h[d] + be_h[d];
    float cln = (yc - mc) * rsqrtf(vc + 1e-5f) * g_c[d] + be_c[d];
    xh[(long)b * 3072 + 2560 + d] = (bf16)hln;
    hf[(long)b * 512 + d] = hln;
    cbuf[(long)b * 512 + d] = cln;           // c(0) in slot 0
}

// ---- LSTM-finish of step (t-1): gates gp -> h(t), c(t); shared LN reduce ----
static __device__ __forceinline__ void lstm_finish(
    const float* gp, const float* b_ih, const float* b_hh,
    const float* g_h, const float* be_h, const float* g_c, const float* be_c,
    const float* c_old, float* r_s, int b, float& hln_out, float& cln_out)
{
    const int d = threadIdx.x;
    float iv = b_ih[d]        + b_hh[d];
    float fv = b_ih[512 + d]  + b_hh[512 + d];
    float gv = b_ih[1024 + d] + b_hh[1024 + d];
    float ov = b_ih[1536 + d] + b_hh[1536 + d];
#pragma unroll
    for (int z = 0; z < 8; ++z) {
        const float* gs = gp + ((long)z * B_ + b) * 2048;
        iv += gs[d]; fv += gs[512 + d]; gv += gs[1024 + d]; ov += gs[1536 + d];
    }
    float cn = sigmoidf_(fv) * c_old[d] + sigmoidf_(iv) * tanhf(gv);
    float hn = sigmoidf_(ov) * tanhf(cn);
    r_s[d] = hn; r_s[512 + d] = hn * hn; r_s[1024 + d] = cn; r_s[1536 + d] = cn * cn;
    __syncthreads();
    for (int s = 256; s > 0; s >>= 1) {
        if (d < s) { r_s[d]+=r_s[d+s]; r_s[512+d]+=r_s[512+d+s];
                     r_s[1024+d]+=r_s[1024+d+s]; r_s[1536+d]+=r_s[1536+d+s]; }
        __syncthreads();
    }
    float mh = r_s[0] * (1.f/512.f),    vh = r_s[512] * (1.f/512.f) - mh*mh;
    float mc = r_s[1024] * (1.f/512.f), vc = r_s[1536] * (1.f/512.f) - mc*mc;
    __syncthreads();
    hln_out = (hn - mh) * rsqrtf(vh + 1e-5f) * g_h[d] + be_h[d];
    cln_out = (cn - mc) * rsqrtf(vc + 1e-5f) * g_c[d] + be_c[d];
}

// ------- mega step kernel: LSTM-finish(t-1) + att2/gate matvec + softmax + awe -------
// 256 blocks = (b, seg); 512 threads
__global__ __launch_bounds__(512)
void k_mega(const float* __restrict__ gp,
            const float* __restrict__ b_ih, const float* __restrict__ b_hh,
            const float* __restrict__ g_h, const float* __restrict__ be_h,
            const float* __restrict__ g_c, const float* __restrict__ be_c,
            const bf16* __restrict__ Wd, const bf16* __restrict__ Wbt,
            const float* __restrict__ b_dec, const float* __restrict__ b_beta,
            const float* __restrict__ Wfull,
            const bf16* __restrict__ att1_b, const bf16* __restrict__ enc_s,
            const int* __restrict__ caps_i, const int* __restrict__ declen_i,
            const float* __restrict__ emb, const float* __restrict__ hf,
            bf16* __restrict__ xh, float* __restrict__ cbuf, bf16* __restrict__ hseq,
            float* __restrict__ out, int t)
{
    const int b = blockIdx.x >> 2, seg = blockIdx.x & 3, tid = threadIdx.x;
    const int dl = declen_i[b];
    const bool fin = (t >= 1) && (t - 1 < dl);
    const bool act = (t < dl);
    __shared__ float h_s[512];
    __shared__ float y_s[1024];     // [0:512]=att2 raw, [512:1024]=gate raw (this seg)
    __shared__ float r_s[2048];
    __shared__ float alp[P_];

    if (fin) {
        float hln, cln;
        lstm_finish(gp, b_ih, b_hh, g_h, be_h, g_c, be_c,
                    cbuf + ((long)((t - 1) & 1) * B_ + b) * 512, r_s, b, hln, cln);
        h_s[tid] = hln;
        if (seg == 0) {
            bf16 hv = (bf16)hln;
            xh[(long)b * 3072 + 2560 + tid] = hv;
            hseq[((long)(t - 1) * B_ + b) * 512 + tid] = hv;
            cbuf[((long)(t & 1) * B_ + b) * 512 + tid] = cln;
        }
    } else if (t == 0) {
        h_s[tid] = hf[(long)b * 512 + tid];
    }
    if (!act) {
        if (seg == 1 && tid < P_) out[OUT_ALPH + ((long)b * T_ + t) * P_ + tid] = 0.f;
        return;
    }
    __syncthreads();

    // --- att2 + gate matvec: wave-per-row, coalesced 1KB row reads ---
    {
        const int lane = tid & 63, wv = tid >> 6;
        float h8[8];
#pragma unroll
        for (int q = 0; q < 8; ++q) h8[q] = h_s[lane * 8 + q];
        for (int r = wv; r < 1024; r += 8) {
            const bf16* wr = (r < 512) ? (Wd + (long)r * 512)
                                       : (Wbt + (long)(seg * 512 + r - 512) * 512);
            bf16x8 w8 = *(const bf16x8*)(wr + lane * 8);
            float p = 0.f;
#pragma unroll
            for (int q = 0; q < 8; ++q) p += h8[q] * (float)w8[q];
#pragma unroll
            for (int off = 32; off > 0; off >>= 1) p += __shfl_xor(p, off);
            if (lane == 0) y_s[r] = p;
        }
    }
    __syncthreads();
    // att2s (reuse r_s[0:512]), wf (r_s[512:1024])
    r_s[tid] = y_s[tid] + b_dec[tid];
    r_s[512 + tid] = Wfull[tid];
    __syncthreads();

    // --- e + softmax ---
    float ev = -FLT_MAX;
    if (tid < P_) {
        const bf16* ar = att1_b + ((long)b * P_ + tid) * 512;
        float acc = 0.f;
        for (int a0 = 0; a0 < 512; a0 += 8) {
            bf16x8 v = *(const bf16x8*)(ar + a0);
#pragma unroll
            for (int j = 0; j < 8; ++j)
                acc += fmaxf((float)v[j] + r_s[a0 + j], 0.f) * r_s[512 + a0 + j];
        }
        ev = acc;
    }
    __shared__ float red[512];
    red[tid] = ev;
    __syncthreads();
    for (int s = 256; s > 0; s >>= 1) { if (tid < s) red[tid] = fmaxf(red[tid], red[tid + s]); __syncthreads(); }
    float mx = red[0];
    __syncthreads();
    float ex = (tid < P_) ? __expf(ev - mx) : 0.f;
    red[tid] = ex;
    __syncthreads();
    for (int s = 256; s > 0; s >>= 1) { if (tid < s) red[tid] += red[tid + s]; __syncthreads(); }
    float inv = 1.f / red[0];
    if (tid < P_) alp[tid] = ex * inv;
    __syncthreads();
    if (seg == 1 && tid < P_)
        out[OUT_ALPH + ((long)b * T_ + t) * P_ + tid] = alp[tid];

    // --- awe (1 col/thread) * sigmoid(gate) -> xh ---
    {
        const int col = seg * 512 + tid;
        const bf16* eb = enc_s + (long)b * P_ * ENC_ + col;
        float acc = 0.f;
#pragma unroll 4
        for (int p = 0; p < P_; ++p) acc += alp[p] * (float)eb[(long)p * ENC_];
        float g = sigmoidf_(y_s[512 + tid] + b_beta[col]);
        xh[(long)b * 3072 + 512 + col] = (bf16)(acc * g);
    }
    if (seg == 0) {
        int tok = caps_i[b * L_ + t];
        xh[(long)b * 3072 + tid] = (bf16)emb[(long)tok * 512 + tid];
    }
}

// ---- tail: finish step T-1 (only b with dl == T) -> hseq[T-1] ----
__global__ __launch_bounds__(512)
void k_lstm_tail(const float* __restrict__ gp,
                 const float* __restrict__ b_ih, const float* __restrict__ b_hh,
                 const float* __restrict__ g_h, const float* __restrict__ be_h,
                 const float* __restrict__ g_c, const float* __restrict__ be_c,
                 const float* __restrict__ cbuf, bf16* __restrict__ hseq,
                 const int* __restrict__ declen_i)
{
    const int b = blockIdx.x, tid = threadIdx.x;
    if (T_ - 1 >= declen_i[b]) return;
    __shared__ float r_s[2048];
    float hln, cln;
    lstm_finish(gp, b_ih, b_hh, g_h, be_h, g_c, be_c,
                cbuf + ((long)((T_ - 1) & 1) * B_ + b) * 512, r_s, b, hln, cln);
    hseq[((long)(T_ - 1) * B_ + b) * 512 + tid] = (bf16)hln;
}

// -------- zero-fill inactive pred rows --------
__global__ __launch_bounds__(256) void k_zero(const int* __restrict__ declen_i, float* __restrict__ out)
{
    int x = blockIdx.x;
    int b = x / T_, t = x - b * T_;
    if (t < declen_i[b]) return;
    float4 z = {0.f, 0.f, 0.f, 0.f};
    long base = OUT_PREDS + ((long)b * T_ + t) * V_;
    for (int i = threadIdx.x * 4; i < V_; i += 1024)
        *(float4*)(out + base + i) = z;
}

// -------- preds over compacted active rows; LDS-staged coalesced epilogue --------
__global__ __launch_bounds__(256)
void k_preds(const bf16* __restrict__ hseq, const bf16* __restrict__ Wfc,
             const float* __restrict__ bias,
             const int* __restrict__ rmap, const int* __restrict__ orow,
             const int* __restrict__ mact, float* __restrict__ out)
{
    int o = blockIdx.x; int xcd = o & 7;
    int base = xcd < 6 ? xcd * 969 : 5814 + (xcd - 6) * 968;
    int wg = base + (o >> 3);
    int nt = wg / 31, mt = wg - 31 * nt;
    if (mt * 64 >= mact[0]) return;
    __shared__ int rs[64], os[64];
    __shared__ __align__(16) float ct[64][132];
    const int tid = threadIdx.x, lane = tid & 63, w = tid >> 6;
    const int r16 = lane & 15, kq = lane >> 4, koff = kq * 8;
    if (tid < 64) { rs[tid] = rmap[mt * 64 + tid]; os[tid] = orow[mt * 64 + tid]; }
    __syncthreads();
    const int ncol0 = nt * 128 + w * 32;
    const bf16* Ap[4];
#pragma unroll
    for (int mi = 0; mi < 4; ++mi)
        Ap[mi] = hseq + (long)rs[mi * 16 + r16] * 512 + koff;
    const bf16* Bp[2];
#pragma unroll
    for (int ni = 0; ni < 2; ++ni)
        Bp[ni] = Wfc + (long)(ncol0 + ni * 16 + r16) * 512 + koff;

    f32x4 acc[4][2] = {};
    bf16x8 af[4], bfr[2];
#pragma unroll
    for (int mi = 0; mi < 4; ++mi) af[mi] = *(const bf16x8*)(Ap[mi]);
#pragma unroll
    for (int ni = 0; ni < 2; ++ni) bfr[ni] = *(const bf16x8*)(Bp[ni]);
    for (int kk = 32; kk < 512; kk += 32) {
        bf16x8 af2[4], bf2[2];
#pragma unroll
        for (int mi = 0; mi < 4; ++mi) af2[mi] = *(const bf16x8*)(Ap[mi] + kk);
#pragma unroll
        for (int ni = 0; ni < 2; ++ni) bf2[ni] = *(const bf16x8*)(Bp[ni] + kk);
#pragma unroll
        for (int mi = 0; mi < 4; ++mi)
#pragma unroll
            for (int ni = 0; ni < 2; ++ni)
                acc[mi][ni] = __builtin_amdgcn_mfma_f32_16x16x32_bf16(bfr[ni], af[mi], acc[mi][ni], 0, 0, 0);
#pragma unroll
        for (int mi = 0; mi < 4; ++mi) af[mi] = af2[mi];
#pragma unroll
        for (int ni = 0; ni < 2; ++ni) bfr[ni] = bf2[ni];
    }
#pragma unroll
    for (int mi = 0; mi < 4; ++mi)
#pragma unroll
        for (int ni = 0; ni < 2; ++ni)
            acc[mi][ni] = __builtin_amdgcn_mfma_f32_16x16x32_bf16(bfr[ni], af[mi], acc[mi][ni], 0, 0, 0);

#pragma unroll
    for (int mi = 0; mi < 4; ++mi)
#pragma unroll
        for (int ni = 0; ni < 2; ++ni)
            *(f32x4*)&ct[mi * 16 + r16][w * 32 + ni * 16 + kq * 4] = acc[mi][ni];
    __syncthreads();
    const int r0 = tid >> 5, cc = (tid & 31) * 4;
    const int gcol = nt * 128 + cc;
    f32x4 bv = *(const f32x4*)(bias + gcol);
#pragma unroll
    for (int it = 0; it < 8; ++it) {
        int r = it * 8 + r0;
        int orv = os[r];
        if (orv >= 0) {
            f32x4 v = *(f32x4*)&ct[r][cc];
            f32x4 oo;
            oo[0] = v[0] + bv[0]; oo[1] = v[1] + bv[1];
            oo[2] = v[2] + bv[2]; oo[3] = v[3] + bv[3];
            *(f32x4*)(out + OUT_PREDS + (long)orv * V_ + gcol) = oo;
        }
    }
}

extern "C" void kernel_launch(void* const* d_in, const int* in_sizes, int n_in,
                              void* d_out, int out_size, void* d_ws, size_t ws_size,
                              hipStream_t stream)
{
    const float* enc       = (const float*)d_in[0];
    const int*   caps      = (const int*)  d_in[1];
    const int*   caplen    = (const int*)  d_in[2];
    const float* emb       = (const float*)d_in[3];
    const float* W_enc_att = (const float*)d_in[4];
    const float* b_enc_att = (const float*)d_in[5];
    const float* W_dec_att = (const float*)d_in[6];
    const float* b_dec_att = (const float*)d_in[7];
    const float* W_full    = (const float*)d_in[8];
    // d_in[9] = b_full (softmax-invariant, unused)
    const float* W_ih      = (const float*)d_in[10];
    const float* b_ih      = (const float*)d_in[11];
    const float* W_hh      = (const float*)d_in[12];
    const float* b_hh      = (const float*)d_in[13];
    const float* g_h       = (const float*)d_in[14];
    const float* be_h      = (const float*)d_in[15];
    const float* g_c       = (const float*)d_in[16];
    const float* be_c      = (const float*)d_in[17];
    const float* W_init_h  = (const float*)d_in[18];
    const float* b_init_h  = (const float*)d_in[19];
    const float* W_init_c  = (const float*)d_in[20];
    const float* b_init_c  = (const float*)d_in[21];
    const float* W_beta    = (const float*)d_in[22];
    const float* b_beta    = (const float*)d_in[23];
    const float* W_fc      = (const float*)d_in[24];
    const float* b_fc      = (const float*)d_in[25];
    float* out = (float*)d_out;

    char* w = (char*)d_ws;
    auto alloc = [&](size_t bytes) { char* p = w; w += (bytes + 255) & ~(size_t)255; return p; };
    int*   order_i  = (int*)  alloc(B_ * 4);
    int*   declen_i = (int*)  alloc(B_ * 4);
    int*   caps_i   = (int*)  alloc(B_ * L_ * 4);
    int*   rmap     = (int*)  alloc(2048 * 4);
    int*   orow     = (int*)  alloc(2048 * 4);
    int*   mact     = (int*)  alloc(256);
    bf16*  enc_s    = (bf16*) alloc((size_t)B_ * P_ * ENC_ * 2);
    bf16*  mean_b   = (bf16*) alloc((size_t)B_ * ENC_ * 2);
    bf16*  att1_b   = (bf16*) alloc((size_t)B_ * P_ * 512 * 2);
    float* pi       = (float*)alloc((size_t)B_ * 1024 * 4);
    float* hf       = (float*)alloc((size_t)B_ * 512 * 4);
    bf16*  xh       = (bf16*) alloc((size_t)B_ * 3072 * 2);
    float* gp       = (float*)alloc((size_t)8 * B_ * 2048 * 4);
    float* cbuf     = (float*)alloc((size_t)2 * B_ * 512 * 4);
    bf16*  hseq     = (bf16*) alloc((size_t)T_ * B_ * 512 * 2);
    bf16*  W_enc_b  = (bf16*) alloc((size_t)512 * 2048 * 2);
    bf16*  W_dec_b  = (bf16*) alloc((size_t)512 * 512 * 2);
    bf16*  W_beta_b = (bf16*) alloc((size_t)2048 * 512 * 2);
    bf16*  W_ih_b   = (bf16*) alloc((size_t)2048 * 2560 * 2);
    bf16*  W_hh_b   = (bf16*) alloc((size_t)2048 * 512 * 2);
    bf16*  W_fc_b   = (bf16*) alloc((size_t)32000 * 512 * 2);
    bf16*  W_inh_b  = (bf16*) alloc((size_t)512 * 2048 * 2);
    bf16*  W_inc_b  = (bf16*) alloc((size_t)512 * 2048 * 2);

    k_order<<<1, B_, 0, stream>>>(caplen, caps, order_i, declen_i, caps_i, out, rmap, orow, mact);
    k_cvt_enc<<<12544, 256, 0, stream>>>(enc, order_i, enc_s);
    k_meanb<<<dim3(B_, 8), 256, 0, stream>>>(enc_s, mean_b);

    // merged weight converts (one launch)
    CvtSegs cs;
    const float* srcs[8] = {W_enc_att, W_dec_att, W_beta, W_ih, W_hh, W_fc, W_init_h, W_init_c};
    bf16* dsts[8] = {W_enc_b, W_dec_b, W_beta_b, W_ih_b, W_hh_b, W_fc_b, W_inh_b, W_inc_b};
    long ns[8] = {512L*2048, 512L*512, 2048L*512, 2048L*2560, 2048L*512, 32000L*512, 512L*2048, 512L*2048};
    long cum = 0;
    for (int i = 0; i < 8; ++i) { cs.s[i] = srcs[i]; cs.d[i] = dsts[i]; cs.cum[i] = cum; cum += ns[i]; }
    cs.cum[8] = cum;
    k_cvt_all<<<(int)((cum / 8 + 255) / 256), 256, 0, stream>>>(cs);

    // init: [h|c] = mean_b @ [W_init_h|W_init_c]^T (N-split), then LN
    k_mgemm<4, 1, 0, 0><<<dim3(1, 8, 1), 256, 0, stream>>>(mean_b, 2048, W_inh_b, W_inc_b,
        nullptr, pi, nullptr, 1024, 2048, 1, 512, 0);
    k_initln<<<B_, 512, 0, stream>>>(pi, b_init_h, b_init_c, g_h, be_h, g_c, be_c, xh, hf, cbuf);

    // att1 = enc_s @ W_enc^T + b -> bf16 [12544][512]; BM=128, 392 blocks XCD-chunked
    k_mgemm<8, 0, 1, 1><<<392, 256, 0, stream>>>(enc_s, 2048, W_enc_b, nullptr,
        b_enc_att, nullptr, att1_b, 512, 2048, 1, 0, 0);

    for (int t = 0; t < T_; ++t) {
        k_mega<<<256, 512, 0, stream>>>(gp, b_ih, b_hh, g_h, be_h, g_c, be_c,
            W_dec_b, W_beta_b, b_dec_att, b_beta, W_full, att1_b, enc_s,
            caps_i, declen_i, emb, hf, xh, cbuf, hseq, out, t);
        k_mgemm<4, 2, 0, 0><<<dim3(1, 16, 8), 256, 0, stream>>>(xh, 3072, W_ih_b, W_hh_b,
            nullptr, gp, nullptr, 2048, 3072, 8, 0, 2560);
    }
    k_lstm_tail<<<B_, 512, 0, stream>>>(gp, b_ih, b_hh, g_h, be_h, g_c, be_c,
        cbuf, hseq, declen_i);

    k_zero<<<B_ * T_, 256, 0, stream>>>(declen_i, out);
    k_preds<<<7750, 256, 0, stream>>>(hseq, W_fc_b, b_fc, rmap, orow, mact, out);
}

// Round 8
// 2264.849 us; speedup vs baseline: 3.9483x; 1.8056x over previous
//
#include <hip/hip_runtime.h>
#include <cfloat>
#include <math.h>

#define B_ 64
#define P_ 196
#define ENC_ 2048
#define D_ 512
#define V_ 32000
#define L_ 32
#define T_ 31

// flat f32 output layout (reference return order)
#define OUT_PREDS 0L
#define OUT_CAPS  63488000L              // 64*31*32000
#define OUT_DECL  63490048L              // +64*32
#define OUT_ALPH  63490112L              // +64
#define OUT_ORDER 63878976L              // +64*31*196

typedef __bf16 bf16;
typedef __bf16 bf16x8 __attribute__((ext_vector_type(8)));
typedef __bf16 bf16x4 __attribute__((ext_vector_type(4)));
typedef __bf16 bf16x2 __attribute__((ext_vector_type(2)));
typedef float  f32x4  __attribute__((ext_vector_type(4)));

static __device__ __forceinline__ float sigmoidf_(float x) { return 1.f / (1.f + __expf(-x)); }

// ------- sort by length, caps gather, scalar outputs, active-row compaction -------
__global__ void k_order(const int* __restrict__ cap_len, const int* __restrict__ caps,
                        int* __restrict__ order_i, int* __restrict__ declen_i,
                        int* __restrict__ caps_i, float* __restrict__ out,
                        int* __restrict__ rmap, int* __restrict__ orow, int* __restrict__ mact)
{
    __shared__ int len_s[B_], dl_s[B_];
    int tid = threadIdx.x;
    len_s[tid] = cap_len[tid];
    __syncthreads();
    int li = len_s[tid];
    int pos = 0;
    for (int j = 0; j < B_; ++j) {
        int lj = len_s[j];
        pos += (lj > li) || (lj == li && j < tid);   // stable descending rank
    }
    order_i[pos]  = tid;
    declen_i[pos] = li - 1;
    dl_s[pos]     = li - 1;
    out[OUT_ORDER + pos] = (float)tid;
    out[OUT_DECL  + pos] = (float)(li - 1);
    for (int l = 0; l < L_; ++l) {
        int tok = caps[tid * L_ + l];
        caps_i[pos * L_ + l] = tok;
        out[OUT_CAPS + pos * L_ + l] = (float)tok;
    }
    __syncthreads();
    int p = tid;
    int off = 0;
    for (int j = 0; j < p; ++j) off += dl_s[j];
    int dl = dl_s[p];
    for (int tt = 0; tt < dl; ++tt) {
        rmap[off + tt] = tt * B_ + p;
        orow[off + tt] = p * T_ + tt;
    }
    if (p == B_ - 1) {
        int M = off + dl;
        mact[0] = M;
        int Mr = (M + 63) & ~63;
        for (int i = M; i < Mr; ++i) { rmap[i] = 0; orow[i] = -1; }
    }
}

// ---------------- merged f32 -> bf16 convert for all 8 weight mats ----------------
struct CvtSegs { const float* s[8]; bf16* d[8]; long cum[9]; };
__global__ __launch_bounds__(256) void k_cvt_all(CvtSegs cs)
{
    long i8 = ((long)blockIdx.x * 256 + threadIdx.x) * 8;
    if (i8 >= cs.cum[8]) return;
    int k = 0;
    while (i8 >= cs.cum[k + 1]) ++k;
    long loc = i8 - cs.cum[k];
    const float* src = cs.s[k] + loc;
    float4 a = *(const float4*)(src);
    float4 b = *(const float4*)(src + 4);
    bf16x8 v;
    v[0]=(bf16)a.x; v[1]=(bf16)a.y; v[2]=(bf16)a.z; v[3]=(bf16)a.w;
    v[4]=(bf16)b.x; v[5]=(bf16)b.y; v[6]=(bf16)b.z; v[7]=(bf16)b.w;
    *(bf16x8*)(cs.d[k] + loc) = v;
}

// ---------------- enc gather-by-order + convert to bf16 ----------------
__global__ __launch_bounds__(256) void k_cvt_enc(const float* __restrict__ enc,
                                                 const int* __restrict__ order_i,
                                                 bf16* __restrict__ enc_s)
{
    long i = ((long)blockIdx.x * 256 + threadIdx.x) * 8;
    int b = (int)(i / ((long)P_ * ENC_));
    long rem = i - (long)b * P_ * ENC_;
    const float* src = enc + (long)order_i[b] * P_ * ENC_ + rem;
    float4 a = *(const float4*)(src);
    float4 c = *(const float4*)(src + 4);
    bf16x8 v;
    v[0]=(bf16)a.x; v[1]=(bf16)a.y; v[2]=(bf16)a.z; v[3]=(bf16)a.w;
    v[4]=(bf16)c.x; v[5]=(bf16)c.y; v[6]=(bf16)c.z; v[7]=(bf16)c.w;
    *(bf16x8*)(enc_s + i) = v;
}

// ---------------- mean over pixels ----------------
__global__ __launch_bounds__(256) void k_meanb(const bf16* __restrict__ enc_s, bf16* __restrict__ mean_b)
{
    int b = blockIdx.x, col = blockIdx.y * 256 + threadIdx.x;
    float s = 0.f;
    const bf16* eb = enc_s + (long)b * P_ * ENC_ + col;
    for (int p = 0; p < P_; ++p) s += (float)eb[(long)p * ENC_];
    mean_b[(long)b * ENC_ + col] = (bf16)(s * (1.f / (float)P_));
}

// ---------------- MFMA GEMM: C[M][N] = A[M][K](bf16) * B[N][K]^T(bf16) ------
// 256 thr = 4 waves; tile (MI*16) x 128; swapped-operand mfma -> dwordx4 stores.
// FUSE: 0=single B, 1=N-split at Nsp, 2=K-split at Ksp
// EPI:  0=RAW f32 partial slot z (M=64), 1=bf16 +bias
// SWZ:  0=3D grid; 1=att1 392 blocks XCD-chunked
template<int MI, int FUSE, int EPI, int SWZ>
__global__ void __launch_bounds__(256)
k_mgemm(const bf16* __restrict__ A, long lda,
        const bf16* __restrict__ B1, const bf16* __restrict__ B2,
        const float* __restrict__ bias,
        float* __restrict__ Cf, bf16* __restrict__ Cb,
        int N, int K, int kspl, int Nsp, int Ksp)
{
    const int tid = threadIdx.x;
    const int lane = tid & 63, w = tid >> 6;
    int mt, nt, z;
    if (SWZ == 0) { mt = blockIdx.x; nt = blockIdx.y; z = blockIdx.z; }
    else          { int o = blockIdx.x; int wg = (o & 7) * 49 + (o >> 3);
                    mt = wg >> 2; nt = wg & 3; z = 0; }
    const int krange = K / kspl;
    const int k0 = z * krange, k1 = k0 + krange;
    const int r16 = lane & 15, kq = lane >> 4;
    const int koff = kq * 8;

    const bf16* Ap = A + (long)(mt * (MI * 16) + r16) * lda + koff;
    const int ncol0 = nt * 128 + w * 32;

    const bf16* Bp[2];
    const bf16* B2p[2];
#pragma unroll
    for (int ni = 0; ni < 2; ++ni) {
        int n = ncol0 + ni * 16 + r16;
        if (FUSE == 1)
            Bp[ni] = (n < Nsp) ? B1 + (long)n * K + koff
                               : B2 + (long)(n - Nsp) * K + koff;
        else if (FUSE == 2) {
            Bp[ni]  = B1 + (long)n * Ksp + koff;
            B2p[ni] = B2 + (long)n * (K - Ksp) + koff - Ksp;
        } else
            Bp[ni] = B1 + (long)n * K + koff;
    }

    auto loadA = [&](int kk, bf16x8* dst) {
#pragma unroll
        for (int mi = 0; mi < MI; ++mi)
            dst[mi] = *(const bf16x8*)(Ap + (long)mi * 16 * lda + kk);
    };
    auto loadB = [&](int kk, bf16x8* dst) {
#pragma unroll
        for (int ni = 0; ni < 2; ++ni) {
            if (FUSE == 2 && kk >= Ksp) dst[ni] = *(const bf16x8*)(B2p[ni] + kk);
            else                        dst[ni] = *(const bf16x8*)(Bp[ni] + kk);
        }
    };

    f32x4 acc[MI][2] = {};
    bf16x8 af[MI], bfr[2];
    loadA(k0, af); loadB(k0, bfr);
    for (int kk = k0 + 32; kk < k1; kk += 32) {
        bf16x8 af2[MI], bf2[2];
        loadA(kk, af2); loadB(kk, bf2);
#pragma unroll
        for (int mi = 0; mi < MI; ++mi)
#pragma unroll
            for (int ni = 0; ni < 2; ++ni)
                acc[mi][ni] = __builtin_amdgcn_mfma_f32_16x16x32_bf16(bfr[ni], af[mi], acc[mi][ni], 0, 0, 0);
#pragma unroll
        for (int mi = 0; mi < MI; ++mi) af[mi] = af2[mi];
#pragma unroll
        for (int ni = 0; ni < 2; ++ni) bfr[ni] = bf2[ni];
    }
#pragma unroll
    for (int mi = 0; mi < MI; ++mi)
#pragma unroll
        for (int ni = 0; ni < 2; ++ni)
            acc[mi][ni] = __builtin_amdgcn_mfma_f32_16x16x32_bf16(bfr[ni], af[mi], acc[mi][ni], 0, 0, 0);

#pragma unroll
    for (int mi = 0; mi < MI; ++mi) {
        const int row = mt * (MI * 16) + mi * 16 + r16;
#pragma unroll
        for (int ni = 0; ni < 2; ++ni) {
            const int col = ncol0 + ni * 16 + kq * 4;
            f32x4 v = acc[mi][ni];
            if (EPI == 0) {
                *(f32x4*)(Cf + (long)z * 64 * N + (long)row * N + col) = v;
            } else {
                f32x4 bv = *(const f32x4*)(bias + col);
                bf16x4 o;
                o[0]=(bf16)(v[0]+bv[0]); o[1]=(bf16)(v[1]+bv[1]);
                o[2]=(bf16)(v[2]+bv[2]); o[3]=(bf16)(v[3]+bv[3]);
                *(bf16x4*)(Cb + (long)row * N + col) = o;
            }
        }
    }
}

// ---------------- init h,c = LN(mean_enc @ W^T + b) ----------------
__global__ __launch_bounds__(512)
void k_initln(const float* __restrict__ pi,
              const float* __restrict__ b_h, const float* __restrict__ b_c,
              const float* __restrict__ g_h, const float* __restrict__ be_h,
              const float* __restrict__ g_c, const float* __restrict__ be_c,
              bf16* __restrict__ xh, float* __restrict__ cbuf)
{
    int b = blockIdx.x, d = threadIdx.x;
    float yh = pi[(long)b * 1024 + d]       + b_h[d];
    float yc = pi[(long)b * 1024 + 512 + d] + b_c[d];
    __shared__ float r1[512], r2[512], r3[512], r4[512];
    r1[d] = yh; r2[d] = yh * yh; r3[d] = yc; r4[d] = yc * yc;
    __syncthreads();
    for (int s = 256; s > 0; s >>= 1) {
        if (d < s) { r1[d]+=r1[d+s]; r2[d]+=r2[d+s]; r3[d]+=r3[d+s]; r4[d]+=r4[d+s]; }
        __syncthreads();
    }
    float mh = r1[0] * (1.f/512.f), vh = r2[0] * (1.f/512.f) - mh*mh;
    float mc = r3[0] * (1.f/512.f), vc = r4[0] * (1.f/512.f) - mc*mc;
    float hln = (yh - mh) * rsqrtf(vh + 1e-5f) * g_h[d] + be_h[d];
    float cln = (yc - mc) * rsqrtf(vc + 1e-5f) * g_c[d] + be_c[d];
    xh[(long)b * 3072 + 2560 + d] = (bf16)hln;
    cbuf[(long)b * 512 + d] = cln;
}

// ------- fused attention: alpha + awe*gate + emb; 256 blocks = (b, seg) -------
// att2gate: 4 raw split-K slots of [64][2560] f32
__global__ __launch_bounds__(256)
void k_attn(const float* __restrict__ att2gate, const float* __restrict__ b_dec,
            const float* __restrict__ b_beta, const float* __restrict__ Wfull,
            const bf16* __restrict__ att1_b, const bf16* __restrict__ enc_s,
            const int* __restrict__ caps_i, const int* __restrict__ declen_i,
            const float* __restrict__ emb,
            bf16* __restrict__ xh, float* __restrict__ out, int t)
{
    const int b = blockIdx.x >> 2, seg = blockIdx.x & 3, tid = threadIdx.x;
    if (t >= declen_i[b]) {
        if (seg == 1 && tid < P_) out[OUT_ALPH + ((long)b * T_ + t) * P_ + tid] = 0.f;
        return;
    }
    __shared__ float att2s[512], wf[512], red[256], alp[P_];
    for (int i = tid; i < 512; i += 256) {
        float s = b_dec[i];
#pragma unroll
        for (int zz = 0; zz < 4; ++zz) s += att2gate[((long)zz * 64 + b) * 2560 + i];
        att2s[i] = s;
        wf[i] = Wfull[i];
    }
    __syncthreads();
    float ev = -FLT_MAX;
    if (tid < P_) {
        const bf16* ar = att1_b + ((long)b * P_ + tid) * 512;
        float acc = 0.f;
        for (int a0 = 0; a0 < 512; a0 += 8) {
            bf16x8 v = *(const bf16x8*)(ar + a0);
#pragma unroll
            for (int j = 0; j < 8; ++j)
                acc += fmaxf((float)v[j] + att2s[a0 + j], 0.f) * wf[a0 + j];
        }
        ev = acc;   // + b_full: softmax-invariant
    }
    red[tid] = ev;
    __syncthreads();
    for (int s = 128; s > 0; s >>= 1) { if (tid < s) red[tid] = fmaxf(red[tid], red[tid + s]); __syncthreads(); }
    float mx = red[0];
    __syncthreads();
    float ex = (tid < P_) ? __expf(ev - mx) : 0.f;
    red[tid] = ex;
    __syncthreads();
    for (int s = 128; s > 0; s >>= 1) { if (tid < s) red[tid] += red[tid + s]; __syncthreads(); }
    float inv = 1.f / red[0];
    if (tid < P_) alp[tid] = ex * inv;
    __syncthreads();
    if (seg == 1 && tid < P_)
        out[OUT_ALPH + ((long)b * T_ + t) * P_ + tid] = alp[tid];
    // awe for this 512-col segment (bf16x2 per thread)
    const int c0 = seg * 512 + tid * 2;
    const bf16* eb = enc_s + (long)b * P_ * ENC_ + c0;
    float a0 = 0.f, a1 = 0.f;
#pragma unroll 4
    for (int p = 0; p < P_; ++p) {
        bf16x2 v = *(const bf16x2*)(eb + (long)p * ENC_);
        float al = alp[p];
        a0 += al * (float)v[0]; a1 += al * (float)v[1];
    }
    float g0 = b_beta[c0], g1 = b_beta[c0 + 1];
#pragma unroll
    for (int zz = 0; zz < 4; ++zz) {
        const float* gs = att2gate + ((long)zz * 64 + b) * 2560 + 512 + c0;
        g0 += gs[0]; g1 += gs[1];
    }
    bf16x2 o;
    o[0] = (bf16)(a0 * sigmoidf_(g0));
    o[1] = (bf16)(a1 * sigmoidf_(g1));
    *(bf16x2*)(xh + (long)b * 3072 + 512 + c0) = o;
    if (seg == 0) {
        int tok = caps_i[b * L_ + t];
        for (int i = tid; i < 512; i += 256)
            xh[(long)b * 3072 + i] = (bf16)emb[(long)tok * 512 + i];
    }
}

// -------- LSTM + 2x LN + state update + hseq record --------
__global__ __launch_bounds__(512)
void k_lstm(const float* __restrict__ gp, const float* __restrict__ b_ih, const float* __restrict__ b_hh,
            const float* __restrict__ g_h, const float* __restrict__ be_h,
            const float* __restrict__ g_c, const float* __restrict__ be_c,
            bf16* __restrict__ xh, float* __restrict__ cbuf, bf16* __restrict__ hseq,
            const int* __restrict__ declen_i, int t)
{
    int b = blockIdx.x, d = threadIdx.x;
    if (t >= declen_i[b]) return;
    float iv = b_ih[d]        + b_hh[d];
    float fv = b_ih[512 + d]  + b_hh[512 + d];
    float gv = b_ih[1024 + d] + b_hh[1024 + d];
    float ov = b_ih[1536 + d] + b_hh[1536 + d];
#pragma unroll
    for (int s = 0; s < 8; ++s) {
        const float* gs = gp + ((long)s * B_ + b) * 2048;
        iv += gs[d]; fv += gs[512 + d]; gv += gs[1024 + d]; ov += gs[1536 + d];
    }
    float cn = sigmoidf_(fv) * cbuf[(long)b * 512 + d] + sigmoidf_(iv) * tanhf(gv);
    float hn = sigmoidf_(ov) * tanhf(cn);
    __shared__ float r1[512], r2[512], r3[512], r4[512];
    r1[d] = hn; r2[d] = hn * hn; r3[d] = cn; r4[d] = cn * cn;
    __syncthreads();
    for (int s = 256; s > 0; s >>= 1) {
        if (d < s) { r1[d]+=r1[d+s]; r2[d]+=r2[d+s]; r3[d]+=r3[d+s]; r4[d]+=r4[d+s]; }
        __syncthreads();
    }
    float mh = r1[0] * (1.f/512.f), vh = r2[0] * (1.f/512.f) - mh*mh;
    float mc = r3[0] * (1.f/512.f), vc = r4[0] * (1.f/512.f) - mc*mc;
    float hln = (hn - mh) * rsqrtf(vh + 1e-5f) * g_h[d] + be_h[d];
    float cln = (cn - mc) * rsqrtf(vc + 1e-5f) * g_c[d] + be_c[d];
    bf16 hv = (bf16)hln;
    xh[(long)b * 3072 + 2560 + d] = hv;
    hseq[((long)t * B_ + b) * 512 + d] = hv;
    cbuf[(long)b * 512 + d] = cln;
}

// -------- zero-fill inactive pred rows --------
__global__ __launch_bounds__(256) void k_zero(const int* __restrict__ declen_i, float* __restrict__ out)
{
    int x = blockIdx.x;
    int b = x / T_, t = x - b * T_;
    if (t < declen_i[b]) return;
    float4 z = {0.f, 0.f, 0.f, 0.f};
    long base = OUT_PREDS + ((long)b * T_ + t) * V_;
    for (int i = threadIdx.x * 4; i < V_; i += 1024)
        *(float4*)(out + base + i) = z;
}

// -------- preds over compacted active rows; LDS-staged coalesced epilogue --------
__global__ __launch_bounds__(256)
void k_preds(const bf16* __restrict__ hseq, const bf16* __restrict__ Wfc,
             const float* __restrict__ bias,
             const int* __restrict__ rmap, const int* __restrict__ orow,
             const int* __restrict__ mact, float* __restrict__ out)
{
    int o = blockIdx.x; int xcd = o & 7;
    int base = xcd < 6 ? xcd * 969 : 5814 + (xcd - 6) * 968;
    int wg = base + (o >> 3);
    int nt = wg / 31, mt = wg - 31 * nt;
    if (mt * 64 >= mact[0]) return;
    __shared__ int rs[64], os[64];
    __shared__ __align__(16) float ct[64][132];
    const int tid = threadIdx.x, lane = tid & 63, w = tid >> 6;
    const int r16 = lane & 15, kq = lane >> 4, koff = kq * 8;
    if (tid < 64) { rs[tid] = rmap[mt * 64 + tid]; os[tid] = orow[mt * 64 + tid]; }
    __syncthreads();
    const int ncol0 = nt * 128 + w * 32;
    const bf16* Ap[4];
#pragma unroll
    for (int mi = 0; mi < 4; ++mi)
        Ap[mi] = hseq + (long)rs[mi * 16 + r16] * 512 + koff;
    const bf16* Bp[2];
#pragma unroll
    for (int ni = 0; ni < 2; ++ni)
        Bp[ni] = Wfc + (long)(ncol0 + ni * 16 + r16) * 512 + koff;

    f32x4 acc[4][2] = {};
    bf16x8 af[4], bfr[2];
#pragma unroll
    for (int mi = 0; mi < 4; ++mi) af[mi] = *(const bf16x8*)(Ap[mi]);
#pragma unroll
    for (int ni = 0; ni < 2; ++ni) bfr[ni] = *(const bf16x8*)(Bp[ni]);
    for (int kk = 32; kk < 512; kk += 32) {
        bf16x8 af2[4], bf2[2];
#pragma unroll
        for (int mi = 0; mi < 4; ++mi) af2[mi] = *(const bf16x8*)(Ap[mi] + kk);
#pragma unroll
        for (int ni = 0; ni < 2; ++ni) bf2[ni] = *(const bf16x8*)(Bp[ni] + kk);
#pragma unroll
        for (int mi = 0; mi < 4; ++mi)
#pragma unroll
            for (int ni = 0; ni < 2; ++ni)
                acc[mi][ni] = __builtin_amdgcn_mfma_f32_16x16x32_bf16(bfr[ni], af[mi], acc[mi][ni], 0, 0, 0);
#pragma unroll
        for (int mi = 0; mi < 4; ++mi) af[mi] = af2[mi];
#pragma unroll
        for (int ni = 0; ni < 2; ++ni) bfr[ni] = bf2[ni];
    }
#pragma unroll
    for (int mi = 0; mi < 4; ++mi)
#pragma unroll
        for (int ni = 0; ni < 2; ++ni)
            acc[mi][ni] = __builtin_amdgcn_mfma_f32_16x16x32_bf16(bfr[ni], af[mi], acc[mi][ni], 0, 0, 0);

#pragma unroll
    for (int mi = 0; mi < 4; ++mi)
#pragma unroll
        for (int ni = 0; ni < 2; ++ni)
            *(f32x4*)&ct[mi * 16 + r16][w * 32 + ni * 16 + kq * 4] = acc[mi][ni];
    __syncthreads();
    const int r0 = tid >> 5, cc = (tid & 31) * 4;
    const int gcol = nt * 128 + cc;
    f32x4 bv = *(const f32x4*)(bias + gcol);
#pragma unroll
    for (int it = 0; it < 8; ++it) {
        int r = it * 8 + r0;
        int orv = os[r];
        if (orv >= 0) {
            f32x4 v = *(f32x4*)&ct[r][cc];
            f32x4 oo;
            oo[0] = v[0] + bv[0]; oo[1] = v[1] + bv[1];
            oo[2] = v[2] + bv[2]; oo[3] = v[3] + bv[3];
            *(f32x4*)(out + OUT_PREDS + (long)orv * V_ + gcol) = oo;
        }
    }
}

extern "C" void kernel_launch(void* const* d_in, const int* in_sizes, int n_in,
                              void* d_out, int out_size, void* d_ws, size_t ws_size,
                              hipStream_t stream)
{
    const float* enc       = (const float*)d_in[0];
    const int*   caps      = (const int*)  d_in[1];
    const int*   caplen    = (const int*)  d_in[2];
    const float* emb       = (const float*)d_in[3];
    const float* W_enc_att = (const float*)d_in[4];
    const float* b_enc_att = (const float*)d_in[5];
    const float* W_dec_att = (const float*)d_in[6];
    const float* b_dec_att = (const float*)d_in[7];
    const float* W_full    = (const float*)d_in[8];
    // d_in[9] = b_full (softmax-invariant, unused)
    const float* W_ih      = (const float*)d_in[10];
    const float* b_ih      = (const float*)d_in[11];
    const float* W_hh      = (const float*)d_in[12];
    const float* b_hh      = (const float*)d_in[13];
    const float* g_h       = (const float*)d_in[14];
    const float* be_h      = (const float*)d_in[15];
    const float* g_c       = (const float*)d_in[16];
    const float* be_c      = (const float*)d_in[17];
    const float* W_init_h  = (const float*)d_in[18];
    const float* b_init_h  = (const float*)d_in[19];
    const float* W_init_c  = (const float*)d_in[20];
    const float* b_init_c  = (const float*)d_in[21];
    const float* W_beta    = (const float*)d_in[22];
    const float* b_beta    = (const float*)d_in[23];
    const float* W_fc      = (const float*)d_in[24];
    const float* b_fc      = (const float*)d_in[25];
    float* out = (float*)d_out;

    char* w = (char*)d_ws;
    auto alloc = [&](size_t bytes) { char* p = w; w += (bytes + 255) & ~(size_t)255; return p; };
    int*   order_i  = (int*)  alloc(B_ * 4);
    int*   declen_i = (int*)  alloc(B_ * 4);
    int*   caps_i   = (int*)  alloc(B_ * L_ * 4);
    int*   rmap     = (int*)  alloc(2048 * 4);
    int*   orow     = (int*)  alloc(2048 * 4);
    int*   mact     = (int*)  alloc(256);
    bf16*  enc_s    = (bf16*) alloc((size_t)B_ * P_ * ENC_ * 2);
    bf16*  mean_b   = (bf16*) alloc((size_t)B_ * ENC_ * 2);
    bf16*  att1_b   = (bf16*) alloc((size_t)B_ * P_ * 512 * 2);
    float* pi       = (float*)alloc((size_t)B_ * 1024 * 4);
    float* att2gate = (float*)alloc((size_t)4 * B_ * 2560 * 4);
    bf16*  xh       = (bf16*) alloc((size_t)B_ * 3072 * 2);
    float* gp       = (float*)alloc((size_t)8 * B_ * 2048 * 4);
    float* cbuf     = (float*)alloc((size_t)B_ * 512 * 4);
    bf16*  hseq     = (bf16*) alloc((size_t)T_ * B_ * 512 * 2);
    bf16*  W_enc_b  = (bf16*) alloc((size_t)512 * 2048 * 2);
    bf16*  W_dec_b  = (bf16*) alloc((size_t)512 * 512 * 2);
    bf16*  W_beta_b = (bf16*) alloc((size_t)2048 * 512 * 2);
    bf16*  W_ih_b   = (bf16*) alloc((size_t)2048 * 2560 * 2);
    bf16*  W_hh_b   = (bf16*) alloc((size_t)2048 * 512 * 2);
    bf16*  W_fc_b   = (bf16*) alloc((size_t)32000 * 512 * 2);
    bf16*  W_inh_b  = (bf16*) alloc((size_t)512 * 2048 * 2);
    bf16*  W_inc_b  = (bf16*) alloc((size_t)512 * 2048 * 2);

    k_order<<<1, B_, 0, stream>>>(caplen, caps, order_i, declen_i, caps_i, out, rmap, orow, mact);
    k_cvt_enc<<<12544, 256, 0, stream>>>(enc, order_i, enc_s);
    k_meanb<<<dim3(B_, 8), 256, 0, stream>>>(enc_s, mean_b);

    // merged weight converts (one launch)
    CvtSegs cs;
    const float* srcs[8] = {W_enc_att, W_dec_att, W_beta, W_ih, W_hh, W_fc, W_init_h, W_init_c};
    bf16* dsts[8] = {W_enc_b, W_dec_b, W_beta_b, W_ih_b, W_hh_b, W_fc_b, W_inh_b, W_inc_b};
    long ns[8] = {512L*2048, 512L*512, 2048L*512, 2048L*2560, 2048L*512, 32000L*512, 512L*2048, 512L*2048};
    long cum = 0;
    for (int i = 0; i < 8; ++i) { cs.s[i] = srcs[i]; cs.d[i] = dsts[i]; cs.cum[i] = cum; cum += ns[i]; }
    cs.cum[8] = cum;
    k_cvt_all<<<(int)((cum / 8 + 255) / 256), 256, 0, stream>>>(cs);

    // init: [h|c] = mean_b @ [W_init_h|W_init_c]^T (N-split), then LN
    k_mgemm<4, 1, 0, 0><<<dim3(1, 8, 1), 256, 0, stream>>>(mean_b, 2048, W_inh_b, W_inc_b,
        nullptr, pi, nullptr, 1024, 2048, 1, 512, 0);
    k_initln<<<B_, 512, 0, stream>>>(pi, b_init_h, b_init_c, g_h, be_h, g_c, be_c, xh, cbuf);

    // att1 = enc_s @ W_enc^T + b -> bf16 [12544][512]; BM=128, 392 blocks XCD-chunked
    k_mgemm<8, 0, 1, 1><<<392, 256, 0, stream>>>(enc_s, 2048, W_enc_b, nullptr,
        b_enc_att, nullptr, att1_b, 512, 2048, 1, 0, 0);

    for (int t = 0; t < T_; ++t) {
        // [att2|gate_pre] = h @ [W_dec|W_beta]^T  (N-split, split-K S=4 raw slots)
        k_mgemm<4, 1, 0, 0><<<dim3(1, 20, 4), 256, 0, stream>>>(xh + 2560, 3072, W_dec_b, W_beta_b,
            nullptr, att2gate, nullptr, 2560, 512, 4, 512, 0);
        k_attn<<<256, 256, 0, stream>>>(att2gate, b_dec_att, b_beta, W_full, att1_b, enc_s,
            caps_i, declen_i, emb, xh, out, t);
        // gates = xh @ [W_ih ; W_hh]^T (K-split at 2560, split-K S=8)
        k_mgemm<4, 2, 0, 0><<<dim3(1, 16, 8), 256, 0, stream>>>(xh, 3072, W_ih_b, W_hh_b,
            nullptr, gp, nullptr, 2048, 3072, 8, 0, 2560);
        k_lstm<<<B_, 512, 0, stream>>>(gp, b_ih, b_hh, g_h, be_h, g_c, be_c,
            xh, cbuf, hseq, declen_i, t);
    }

    // inactive rows -> zeros; active rows -> compacted GEMM with coalesced epilogue
    k_zero<<<B_ * T_, 256, 0, stream>>>(declen_i, out);
    k_preds<<<7750, 256, 0, stream>>>(hseq, W_fc_b, b_fc, rmap, orow, mact, out);
}

// Round 9
// 2257.581 us; speedup vs baseline: 3.9610x; 1.0032x over previous
//
#include <hip/hip_runtime.h>
#include <cfloat>
#include <math.h>

#define B_ 64
#define P_ 196
#define ENC_ 2048
#define D_ 512
#define V_ 32000
#define L_ 32
#define T_ 31

// flat f32 output layout (reference return order)
#define OUT_PREDS 0L
#define OUT_CAPS  63488000L              // 64*31*32000
#define OUT_DECL  63490048L              // +64*32
#define OUT_ALPH  63490112L              // +64
#define OUT_ORDER 63878976L              // +64*31*196

typedef __bf16 bf16;
typedef __bf16 bf16x8 __attribute__((ext_vector_type(8)));
typedef __bf16 bf16x4 __attribute__((ext_vector_type(4)));
typedef __bf16 bf16x2 __attribute__((ext_vector_type(2)));
typedef float  f32x4  __attribute__((ext_vector_type(4)));

static __device__ __forceinline__ float sigmoidf_(float x) { return 1.f / (1.f + __expf(-x)); }

// ------- sort by length, caps gather, scalar outputs, active-row compaction -------
__global__ void k_order(const int* __restrict__ cap_len, const int* __restrict__ caps,
                        int* __restrict__ order_i, int* __restrict__ declen_i,
                        int* __restrict__ caps_i, float* __restrict__ out,
                        int* __restrict__ rmap, int* __restrict__ orow, int* __restrict__ mact)
{
    __shared__ int len_s[B_], dl_s[B_];
    int tid = threadIdx.x;
    len_s[tid] = cap_len[tid];
    __syncthreads();
    int li = len_s[tid];
    int pos = 0;
    for (int j = 0; j < B_; ++j) {
        int lj = len_s[j];
        pos += (lj > li) || (lj == li && j < tid);   // stable descending rank
    }
    order_i[pos]  = tid;
    declen_i[pos] = li - 1;
    dl_s[pos]     = li - 1;
    out[OUT_ORDER + pos] = (float)tid;
    out[OUT_DECL  + pos] = (float)(li - 1);
    for (int l = 0; l < L_; ++l) {
        int tok = caps[tid * L_ + l];
        caps_i[pos * L_ + l] = tok;
        out[OUT_CAPS + pos * L_ + l] = (float)tok;
    }
    __syncthreads();
    int p = tid;
    int off = 0;
    for (int j = 0; j < p; ++j) off += dl_s[j];
    int dl = dl_s[p];
    for (int tt = 0; tt < dl; ++tt) {
        rmap[off + tt] = tt * B_ + p;
        orow[off + tt] = p * T_ + tt;
    }
    if (p == B_ - 1) {
        int M = off + dl;
        mact[0] = M;
        int Mr = (M + 63) & ~63;
        for (int i = M; i < Mr; ++i) { rmap[i] = 0; orow[i] = -1; }
    }
}

// ---------------- merged f32 -> bf16 convert for all 8 weight mats ----------------
struct CvtSegs { const float* s[8]; bf16* d[8]; long cum[9]; };
__global__ __launch_bounds__(256) void k_cvt_all(CvtSegs cs)
{
    long i8 = ((long)blockIdx.x * 256 + threadIdx.x) * 8;
    if (i8 >= cs.cum[8]) return;
    int k = 0;
    while (i8 >= cs.cum[k + 1]) ++k;
    long loc = i8 - cs.cum[k];
    const float* src = cs.s[k] + loc;
    float4 a = *(const float4*)(src);
    float4 b = *(const float4*)(src + 4);
    bf16x8 v;
    v[0]=(bf16)a.x; v[1]=(bf16)a.y; v[2]=(bf16)a.z; v[3]=(bf16)a.w;
    v[4]=(bf16)b.x; v[5]=(bf16)b.y; v[6]=(bf16)b.z; v[7]=(bf16)b.w;
    *(bf16x8*)(cs.d[k] + loc) = v;
}

// ---------------- enc gather-by-order + convert to bf16 ----------------
__global__ __launch_bounds__(256) void k_cvt_enc(const float* __restrict__ enc,
                                                 const int* __restrict__ order_i,
                                                 bf16* __restrict__ enc_s)
{
    long i = ((long)blockIdx.x * 256 + threadIdx.x) * 8;
    int b = (int)(i / ((long)P_ * ENC_));
    long rem = i - (long)b * P_ * ENC_;
    const float* src = enc + (long)order_i[b] * P_ * ENC_ + rem;
    float4 a = *(const float4*)(src);
    float4 c = *(const float4*)(src + 4);
    bf16x8 v;
    v[0]=(bf16)a.x; v[1]=(bf16)a.y; v[2]=(bf16)a.z; v[3]=(bf16)a.w;
    v[4]=(bf16)c.x; v[5]=(bf16)c.y; v[6]=(bf16)c.z; v[7]=(bf16)c.w;
    *(bf16x8*)(enc_s + i) = v;
}

// ---------------- mean over pixels ----------------
__global__ __launch_bounds__(256) void k_meanb(const bf16* __restrict__ enc_s, bf16* __restrict__ mean_b)
{
    int b = blockIdx.x, col = blockIdx.y * 256 + threadIdx.x;
    float s = 0.f;
    const bf16* eb = enc_s + (long)b * P_ * ENC_ + col;
    for (int p = 0; p < P_; ++p) s += (float)eb[(long)p * ENC_];
    mean_b[(long)b * ENC_ + col] = (bf16)(s * (1.f / (float)P_));
}

// ---------------- MFMA GEMM: C[M][N] = A[M][K](bf16) * B[N][K]^T(bf16) ------
// 256 thr = 4 waves; tile (MI*16) x 128; swapped-operand mfma -> dwordx4 stores.
// FUSE: 0=single B, 1=N-split at Nsp, 2=K-split at Ksp
// EPI:  0=RAW f32 partial slot z (Mtot rows), 1=bf16 +bias
// SWZ:  0=3D grid; 1=att1 1568 blocks XCD-chunked, mt-major per XCD (A-panel L2 reuse)
template<int MI, int FUSE, int EPI, int SWZ>
__global__ void __launch_bounds__(256)
k_mgemm(const bf16* __restrict__ A, long lda,
        const bf16* __restrict__ B1, const bf16* __restrict__ B2,
        const float* __restrict__ bias,
        float* __restrict__ Cf, bf16* __restrict__ Cb,
        int N, int K, int kspl, int Nsp, int Ksp, int Mtot)
{
    const int tid = threadIdx.x;
    const int lane = tid & 63, w = tid >> 6;
    int mt, nt, z;
    if (SWZ == 0) { mt = blockIdx.x; nt = blockIdx.y; z = blockIdx.z; }
    else          { int o = blockIdx.x; int wg = (o & 7) * 196 + (o >> 3);
                    mt = wg >> 3; nt = (wg >> 1) & 3; z = wg & 1; }
    const int krange = K / kspl;
    const int k0 = z * krange, k1 = k0 + krange;
    const int r16 = lane & 15, kq = lane >> 4;
    const int koff = kq * 8;

    const bf16* Ap = A + (long)(mt * (MI * 16) + r16) * lda + koff;
    const int ncol0 = nt * 128 + w * 32;

    const bf16* Bp[2];
    const bf16* B2p[2];
#pragma unroll
    for (int ni = 0; ni < 2; ++ni) {
        int n = ncol0 + ni * 16 + r16;
        if (FUSE == 1)
            Bp[ni] = (n < Nsp) ? B1 + (long)n * K + koff
                               : B2 + (long)(n - Nsp) * K + koff;
        else if (FUSE == 2) {
            Bp[ni]  = B1 + (long)n * Ksp + koff;
            B2p[ni] = B2 + (long)n * (K - Ksp) + koff - Ksp;
        } else
            Bp[ni] = B1 + (long)n * K + koff;
    }

    auto loadA = [&](int kk, bf16x8* dst) {
#pragma unroll
        for (int mi = 0; mi < MI; ++mi)
            dst[mi] = *(const bf16x8*)(Ap + (long)mi * 16 * lda + kk);
    };
    auto loadB = [&](int kk, bf16x8* dst) {
#pragma unroll
        for (int ni = 0; ni < 2; ++ni) {
            if (FUSE == 2 && kk >= Ksp) dst[ni] = *(const bf16x8*)(B2p[ni] + kk);
            else                        dst[ni] = *(const bf16x8*)(Bp[ni] + kk);
        }
    };

    f32x4 acc[MI][2] = {};
    bf16x8 af[MI], bfr[2];
    loadA(k0, af); loadB(k0, bfr);
    for (int kk = k0 + 32; kk < k1; kk += 32) {
        bf16x8 af2[MI], bf2[2];
        loadA(kk, af2); loadB(kk, bf2);
#pragma unroll
        for (int mi = 0; mi < MI; ++mi)
#pragma unroll
            for (int ni = 0; ni < 2; ++ni)
                acc[mi][ni] = __builtin_amdgcn_mfma_f32_16x16x32_bf16(bfr[ni], af[mi], acc[mi][ni], 0, 0, 0);
#pragma unroll
        for (int mi = 0; mi < MI; ++mi) af[mi] = af2[mi];
#pragma unroll
        for (int ni = 0; ni < 2; ++ni) bfr[ni] = bf2[ni];
    }
#pragma unroll
    for (int mi = 0; mi < MI; ++mi)
#pragma unroll
        for (int ni = 0; ni < 2; ++ni)
            acc[mi][ni] = __builtin_amdgcn_mfma_f32_16x16x32_bf16(bfr[ni], af[mi], acc[mi][ni], 0, 0, 0);

#pragma unroll
    for (int mi = 0; mi < MI; ++mi) {
        const int row = mt * (MI * 16) + mi * 16 + r16;
#pragma unroll
        for (int ni = 0; ni < 2; ++ni) {
            const int col = ncol0 + ni * 16 + kq * 4;
            f32x4 v = acc[mi][ni];
            if (EPI == 0) {
                *(f32x4*)(Cf + (long)z * Mtot * N + (long)row * N + col) = v;
            } else {
                f32x4 bv = *(const f32x4*)(bias + col);
                bf16x4 o;
                o[0]=(bf16)(v[0]+bv[0]); o[1]=(bf16)(v[1]+bv[1]);
                o[2]=(bf16)(v[2]+bv[2]); o[3]=(bf16)(v[3]+bv[3]);
                *(bf16x4*)(Cb + (long)row * N + col) = o;
            }
        }
    }
}

// ------- att1 split-K reduce: att1_b = bf16(p0 + p1 + bias), 8 elems/thread -------
__global__ __launch_bounds__(256)
void k_red(const float* __restrict__ p, const float* __restrict__ bias, bf16* __restrict__ ob)
{
    const long TOT = (long)12544 * 512;
    long i = ((long)blockIdx.x * 256 + threadIdx.x) * 8;
    f32x4 a0 = *(const f32x4*)(p + i);
    f32x4 a1 = *(const f32x4*)(p + i + 4);
    f32x4 b0 = *(const f32x4*)(p + TOT + i);
    f32x4 b1 = *(const f32x4*)(p + TOT + i + 4);
    int col = (int)(i & 511);
    f32x4 c0 = *(const f32x4*)(bias + col);
    f32x4 c1 = *(const f32x4*)(bias + col + 4);
    bf16x8 v;
    v[0]=(bf16)(a0[0]+b0[0]+c0[0]); v[1]=(bf16)(a0[1]+b0[1]+c0[1]);
    v[2]=(bf16)(a0[2]+b0[2]+c0[2]); v[3]=(bf16)(a0[3]+b0[3]+c0[3]);
    v[4]=(bf16)(a1[0]+b1[0]+c1[0]); v[5]=(bf16)(a1[1]+b1[1]+c1[1]);
    v[6]=(bf16)(a1[2]+b1[2]+c1[2]); v[7]=(bf16)(a1[3]+b1[3]+c1[3]);
    *(bf16x8*)(ob + i) = v;
}

// ---------------- init h,c = LN(mean_enc @ W^T + b) ----------------
__global__ __launch_bounds__(512)
void k_initln(const float* __restrict__ pi,
              const float* __restrict__ b_h, const float* __restrict__ b_c,
              const float* __restrict__ g_h, const float* __restrict__ be_h,
              const float* __restrict__ g_c, const float* __restrict__ be_c,
              bf16* __restrict__ xh, float* __restrict__ cbuf)
{
    int b = blockIdx.x, d = threadIdx.x;
    float yh = pi[(long)b * 1024 + d]       + b_h[d];
    float yc = pi[(long)b * 1024 + 512 + d] + b_c[d];
    __shared__ float r1[512], r2[512], r3[512], r4[512];
    r1[d] = yh; r2[d] = yh * yh; r3[d] = yc; r4[d] = yc * yc;
    __syncthreads();
    for (int s = 256; s > 0; s >>= 1) {
        if (d < s) { r1[d]+=r1[d+s]; r2[d]+=r2[d+s]; r3[d]+=r3[d+s]; r4[d]+=r4[d+s]; }
        __syncthreads();
    }
    float mh = r1[0] * (1.f/512.f), vh = r2[0] * (1.f/512.f) - mh*mh;
    float mc = r3[0] * (1.f/512.f), vc = r4[0] * (1.f/512.f) - mc*mc;
    float hln = (yh - mh) * rsqrtf(vh + 1e-5f) * g_h[d] + be_h[d];
    float cln = (yc - mc) * rsqrtf(vc + 1e-5f) * g_c[d] + be_c[d];
    xh[(long)b * 3072 + 2560 + d] = (bf16)hln;
    cbuf[(long)b * 512 + d] = cln;
}

// ------- fused attention: alpha + awe*gate + emb; 128 blocks = (b, seg of 1024 cols) -------
// att2gate: 4 raw split-K slots of [64][2560] f32
__global__ __launch_bounds__(512)
void k_attn(const float* __restrict__ att2gate, const float* __restrict__ b_dec,
            const float* __restrict__ b_beta, const float* __restrict__ Wfull,
            const bf16* __restrict__ att1_b, const bf16* __restrict__ enc_s,
            const int* __restrict__ caps_i, const int* __restrict__ declen_i,
            const float* __restrict__ emb,
            bf16* __restrict__ xh, float* __restrict__ out, int t)
{
    const int b = blockIdx.x >> 1, seg = blockIdx.x & 1, tid = threadIdx.x;
    if (t >= declen_i[b]) {
        if (seg == 1 && tid < P_) out[OUT_ALPH + ((long)b * T_ + t) * P_ + tid] = 0.f;
        return;
    }
    __shared__ float att2s[512], wf[512], red[512], alp[P_];
    {
        float s = b_dec[tid];
#pragma unroll
        for (int zz = 0; zz < 4; ++zz) s += att2gate[((long)zz * 64 + b) * 2560 + tid];
        att2s[tid] = s;
        wf[tid] = Wfull[tid];
    }
    __syncthreads();
    float ev = -FLT_MAX;
    if (tid < P_) {
        const bf16* ar = att1_b + ((long)b * P_ + tid) * 512;
        float acc = 0.f;
        for (int a0 = 0; a0 < 512; a0 += 8) {
            bf16x8 v = *(const bf16x8*)(ar + a0);
#pragma unroll
            for (int j = 0; j < 8; ++j)
                acc += fmaxf((float)v[j] + att2s[a0 + j], 0.f) * wf[a0 + j];
        }
        ev = acc;   // + b_full: softmax-invariant
    }
    red[tid] = ev;
    __syncthreads();
    for (int s = 256; s > 0; s >>= 1) { if (tid < s) red[tid] = fmaxf(red[tid], red[tid + s]); __syncthreads(); }
    float mx = red[0];
    __syncthreads();
    float ex = (tid < P_) ? __expf(ev - mx) : 0.f;
    red[tid] = ex;
    __syncthreads();
    for (int s = 256; s > 0; s >>= 1) { if (tid < s) red[tid] += red[tid + s]; __syncthreads(); }
    float inv = 1.f / red[0];
    if (tid < P_) alp[tid] = ex * inv;
    __syncthreads();
    if (seg == 1 && tid < P_)
        out[OUT_ALPH + ((long)b * T_ + t) * P_ + tid] = alp[tid];
    // awe for this 1024-col segment (bf16x2 per thread)
    const int c0 = seg * 1024 + tid * 2;
    const bf16* eb = enc_s + (long)b * P_ * ENC_ + c0;
    float a0 = 0.f, a1 = 0.f;
#pragma unroll 4
    for (int p = 0; p < P_; ++p) {
        bf16x2 v = *(const bf16x2*)(eb + (long)p * ENC_);
        float al = alp[p];
        a0 += al * (float)v[0]; a1 += al * (float)v[1];
    }
    float g0 = b_beta[c0], g1 = b_beta[c0 + 1];
#pragma unroll
    for (int zz = 0; zz < 4; ++zz) {
        const float* gs = att2gate + ((long)zz * 64 + b) * 2560 + 512 + c0;
        g0 += gs[0]; g1 += gs[1];
    }
    bf16x2 o;
    o[0] = (bf16)(a0 * sigmoidf_(g0));
    o[1] = (bf16)(a1 * sigmoidf_(g1));
    *(bf16x2*)(xh + (long)b * 3072 + 512 + c0) = o;
    if (seg == 0) {
        int tok = caps_i[b * L_ + t];
        xh[(long)b * 3072 + tid] = (bf16)emb[(long)tok * 512 + tid];
    }
}

// -------- LSTM + 2x LN + state update + hseq record --------
__global__ __launch_bounds__(512)
void k_lstm(const float* __restrict__ gp, const float* __restrict__ b_ih, const float* __restrict__ b_hh,
            const float* __restrict__ g_h, const float* __restrict__ be_h,
            const float* __restrict__ g_c, const float* __restrict__ be_c,
            bf16* __restrict__ xh, float* __restrict__ cbuf, bf16* __restrict__ hseq,
            const int* __restrict__ declen_i, int t)
{
    int b = blockIdx.x, d = threadIdx.x;
    if (t >= declen_i[b]) return;
    float iv = b_ih[d]        + b_hh[d];
    float fv = b_ih[512 + d]  + b_hh[512 + d];
    float gv = b_ih[1024 + d] + b_hh[1024 + d];
    float ov = b_ih[1536 + d] + b_hh[1536 + d];
#pragma unroll
    for (int s = 0; s < 8; ++s) {
        const float* gs = gp + ((long)s * B_ + b) * 2048;
        iv += gs[d]; fv += gs[512 + d]; gv += gs[1024 + d]; ov += gs[1536 + d];
    }
    float cn = sigmoidf_(fv) * cbuf[(long)b * 512 + d] + sigmoidf_(iv) * tanhf(gv);
    float hn = sigmoidf_(ov) * tanhf(cn);
    __shared__ float r1[512], r2[512], r3[512], r4[512];
    r1[d] = hn; r2[d] = hn * hn; r3[d] = cn; r4[d] = cn * cn;
    __syncthreads();
    for (int s = 256; s > 0; s >>= 1) {
        if (d < s) { r1[d]+=r1[d+s]; r2[d]+=r2[d+s]; r3[d]+=r3[d+s]; r4[d]+=r4[d+s]; }
        __syncthreads();
    }
    float mh = r1[0] * (1.f/512.f), vh = r2[0] * (1.f/512.f) - mh*mh;
    float mc = r3[0] * (1.f/512.f), vc = r4[0] * (1.f/512.f) - mc*mc;
    float hln = (hn - mh) * rsqrtf(vh + 1e-5f) * g_h[d] + be_h[d];
    float cln = (cn - mc) * rsqrtf(vc + 1e-5f) * g_c[d] + be_c[d];
    bf16 hv = (bf16)hln;
    xh[(long)b * 3072 + 2560 + d] = hv;
    hseq[((long)t * B_ + b) * 512 + d] = hv;
    cbuf[(long)b * 512 + d] = cln;
}

// -------- zero-fill inactive pred rows --------
__global__ __launch_bounds__(256) void k_zero(const int* __restrict__ declen_i, float* __restrict__ out)
{
    int x = blockIdx.x;
    int b = x / T_, t = x - b * T_;
    if (t < declen_i[b]) return;
    float4 z = {0.f, 0.f, 0.f, 0.f};
    long base = OUT_PREDS + ((long)b * T_ + t) * V_;
    for (int i = threadIdx.x * 4; i < V_; i += 1024)
        *(float4*)(out + base + i) = z;
}

// -------- preds over compacted active rows; LDS-staged coalesced epilogue --------
__global__ __launch_bounds__(256)
void k_preds(const bf16* __restrict__ hseq, const bf16* __restrict__ Wfc,
             const float* __restrict__ bias,
             const int* __restrict__ rmap, const int* __restrict__ orow,
             const int* __restrict__ mact, float* __restrict__ out)
{
    int o = blockIdx.x; int xcd = o & 7;
    int base = xcd < 6 ? xcd * 969 : 5814 + (xcd - 6) * 968;
    int wg = base + (o >> 3);
    int nt = wg / 31, mt = wg - 31 * nt;
    if (mt * 64 >= mact[0]) return;
    __shared__ int rs[64], os[64];
    __shared__ __align__(16) float ct[64][132];
    const int tid = threadIdx.x, lane = tid & 63, w = tid >> 6;
    const int r16 = lane & 15, kq = lane >> 4, koff = kq * 8;
    if (tid < 64) { rs[tid] = rmap[mt * 64 + tid]; os[tid] = orow[mt * 64 + tid]; }
    __syncthreads();
    const int ncol0 = nt * 128 + w * 32;
    const bf16* Ap[4];
#pragma unroll
    for (int mi = 0; mi < 4; ++mi)
        Ap[mi] = hseq + (long)rs[mi * 16 + r16] * 512 + koff;
    const bf16* Bp[2];
#pragma unroll
    for (int ni = 0; ni < 2; ++ni)
        Bp[ni] = Wfc + (long)(ncol0 + ni * 16 + r16) * 512 + koff;

    f32x4 acc[4][2] = {};
    bf16x8 af[4], bfr[2];
#pragma unroll
    for (int mi = 0; mi < 4; ++mi) af[mi] = *(const bf16x8*)(Ap[mi]);
#pragma unroll
    for (int ni = 0; ni < 2; ++ni) bfr[ni] = *(const bf16x8*)(Bp[ni]);
    for (int kk = 32; kk < 512; kk += 32) {
        bf16x8 af2[4], bf2[2];
#pragma unroll
        for (int mi = 0; mi < 4; ++mi) af2[mi] = *(const bf16x8*)(Ap[mi] + kk);
#pragma unroll
        for (int ni = 0; ni < 2; ++ni) bf2[ni] = *(const bf16x8*)(Bp[ni] + kk);
#pragma unroll
        for (int mi = 0; mi < 4; ++mi)
#pragma unroll
            for (int ni = 0; ni < 2; ++ni)
                acc[mi][ni] = __builtin_amdgcn_mfma_f32_16x16x32_bf16(bfr[ni], af[mi], acc[mi][ni], 0, 0, 0);
#pragma unroll
        for (int mi = 0; mi < 4; ++mi) af[mi] = af2[mi];
#pragma unroll
        for (int ni = 0; ni < 2; ++ni) bfr[ni] = bf2[ni];
    }
#pragma unroll
    for (int mi = 0; mi < 4; ++mi)
#pragma unroll
        for (int ni = 0; ni < 2; ++ni)
            acc[mi][ni] = __builtin_amdgcn_mfma_f32_16x16x32_bf16(bfr[ni], af[mi], acc[mi][ni], 0, 0, 0);

#pragma unroll
    for (int mi = 0; mi < 4; ++mi)
#pragma unroll
        for (int ni = 0; ni < 2; ++ni)
            *(f32x4*)&ct[mi * 16 + r16][w * 32 + ni * 16 + kq * 4] = acc[mi][ni];
    __syncthreads();
    const int r0 = tid >> 5, cc = (tid & 31) * 4;
    const int gcol = nt * 128 + cc;
    f32x4 bv = *(const f32x4*)(bias + gcol);
#pragma unroll
    for (int it = 0; it < 8; ++it) {
        int r = it * 8 + r0;
        int orv = os[r];
        if (orv >= 0) {
            f32x4 v = *(f32x4*)&ct[r][cc];
            f32x4 oo;
            oo[0] = v[0] + bv[0]; oo[1] = v[1] + bv[1];
            oo[2] = v[2] + bv[2]; oo[3] = v[3] + bv[3];
            *(f32x4*)(out + OUT_PREDS + (long)orv * V_ + gcol) = oo;
        }
    }
}

extern "C" void kernel_launch(void* const* d_in, const int* in_sizes, int n_in,
                              void* d_out, int out_size, void* d_ws, size_t ws_size,
                              hipStream_t stream)
{
    const float* enc       = (const float*)d_in[0];
    const int*   caps      = (const int*)  d_in[1];
    const int*   caplen    = (const int*)  d_in[2];
    const float* emb       = (const float*)d_in[3];
    const float* W_enc_att = (const float*)d_in[4];
    const float* b_enc_att = (const float*)d_in[5];
    const float* W_dec_att = (const float*)d_in[6];
    const float* b_dec_att = (const float*)d_in[7];
    const float* W_full    = (const float*)d_in[8];
    // d_in[9] = b_full (softmax-invariant, unused)
    const float* W_ih      = (const float*)d_in[10];
    const float* b_ih      = (const float*)d_in[11];
    const float* W_hh      = (const float*)d_in[12];
    const float* b_hh      = (const float*)d_in[13];
    const float* g_h       = (const float*)d_in[14];
    const float* be_h      = (const float*)d_in[15];
    const float* g_c       = (const float*)d_in[16];
    const float* be_c      = (const float*)d_in[17];
    const float* W_init_h  = (const float*)d_in[18];
    const float* b_init_h  = (const float*)d_in[19];
    const float* W_init_c  = (const float*)d_in[20];
    const float* b_init_c  = (const float*)d_in[21];
    const float* W_beta    = (const float*)d_in[22];
    const float* b_beta    = (const float*)d_in[23];
    const float* W_fc      = (const float*)d_in[24];
    const float* b_fc      = (const float*)d_in[25];
    float* out = (float*)d_out;

    char* w = (char*)d_ws;
    auto alloc = [&](size_t bytes) { char* p = w; w += (bytes + 255) & ~(size_t)255; return p; };
    int*   order_i  = (int*)  alloc(B_ * 4);
    int*   declen_i = (int*)  alloc(B_ * 4);
    int*   caps_i   = (int*)  alloc(B_ * L_ * 4);
    int*   rmap     = (int*)  alloc(2048 * 4);
    int*   orow     = (int*)  alloc(2048 * 4);
    int*   mact     = (int*)  alloc(256);
    bf16*  enc_s    = (bf16*) alloc((size_t)B_ * P_ * ENC_ * 2);
    bf16*  mean_b   = (bf16*) alloc((size_t)B_ * ENC_ * 2);
    bf16*  att1_b   = (bf16*) alloc((size_t)B_ * P_ * 512 * 2);
    float* pi       = (float*)alloc((size_t)B_ * 1024 * 4);
    float* cbuf     = (float*)alloc((size_t)B_ * 512 * 4);
    bf16*  xh       = (bf16*) alloc((size_t)B_ * 3072 * 2);
    // att1 split-K partial buffer (dead after k_red) overlaid with loop-only buffers
    float* att1_p   = (float*)alloc((size_t)2 * 12544 * 512 * 4);     // 51.4 MB
    float* gp       = att1_p;                                          // 4.19 MB
    float* att2gate = (float*)((char*)att1_p + ((size_t)8 * B_ * 2048 * 4 + 255 & ~(size_t)255));
    bf16*  hseq     = (bf16*)((char*)att2gate + ((size_t)4 * B_ * 2560 * 4 + 255 & ~(size_t)255));
    bf16*  W_enc_b  = (bf16*) alloc((size_t)512 * 2048 * 2);
    bf16*  W_dec_b  = (bf16*) alloc((size_t)512 * 512 * 2);
    bf16*  W_beta_b = (bf16*) alloc((size_t)2048 * 512 * 2);
    bf16*  W_ih_b   = (bf16*) alloc((size_t)2048 * 2560 * 2);
    bf16*  W_hh_b   = (bf16*) alloc((size_t)2048 * 512 * 2);
    bf16*  W_fc_b   = (bf16*) alloc((size_t)32000 * 512 * 2);
    bf16*  W_inh_b  = (bf16*) alloc((size_t)512 * 2048 * 2);
    bf16*  W_inc_b  = (bf16*) alloc((size_t)512 * 2048 * 2);

    k_order<<<1, B_, 0, stream>>>(caplen, caps, order_i, declen_i, caps_i, out, rmap, orow, mact);
    k_cvt_enc<<<12544, 256, 0, stream>>>(enc, order_i, enc_s);
    k_meanb<<<dim3(B_, 8), 256, 0, stream>>>(enc_s, mean_b);

    // merged weight converts (one launch)
    CvtSegs cs;
    const float* srcs[8] = {W_enc_att, W_dec_att, W_beta, W_ih, W_hh, W_fc, W_init_h, W_init_c};
    bf16* dsts[8] = {W_enc_b, W_dec_b, W_beta_b, W_ih_b, W_hh_b, W_fc_b, W_inh_b, W_inc_b};
    long ns[8] = {512L*2048, 512L*512, 2048L*512, 2048L*2560, 2048L*512, 32000L*512, 512L*2048, 512L*2048};
    long cum = 0;
    for (int i = 0; i < 8; ++i) { cs.s[i] = srcs[i]; cs.d[i] = dsts[i]; cs.cum[i] = cum; cum += ns[i]; }
    cs.cum[8] = cum;
    k_cvt_all<<<(int)((cum / 8 + 255) / 256), 256, 0, stream>>>(cs);

    // init: [h|c] = mean_b @ [W_init_h|W_init_c]^T (N-split), then LN
    k_mgemm<4, 1, 0, 0><<<dim3(1, 8, 1), 256, 0, stream>>>(mean_b, 2048, W_inh_b, W_inc_b,
        nullptr, pi, nullptr, 1024, 2048, 1, 512, 0, 64);
    k_initln<<<B_, 512, 0, stream>>>(pi, b_init_h, b_init_c, g_h, be_h, g_c, be_c, xh, cbuf);

    // att1 = enc_s @ W_enc^T (split-K S=2, f32 partials, 1568 blocks XCD-chunked) + reduce
    k_mgemm<4, 0, 0, 1><<<1568, 256, 0, stream>>>(enc_s, 2048, W_enc_b, nullptr,
        nullptr, att1_p, nullptr, 512, 2048, 2, 0, 0, 12544);
    k_red<<<3136, 256, 0, stream>>>(att1_p, b_enc_att, att1_b);

    for (int t = 0; t < T_; ++t) {
        // [att2|gate_pre] = h @ [W_dec|W_beta]^T  (N-split, split-K S=4 raw slots)
        k_mgemm<4, 1, 0, 0><<<dim3(1, 20, 4), 256, 0, stream>>>(xh + 2560, 3072, W_dec_b, W_beta_b,
            nullptr, att2gate, nullptr, 2560, 512, 4, 512, 0, 64);
        k_attn<<<128, 512, 0, stream>>>(att2gate, b_dec_att, b_beta, W_full, att1_b, enc_s,
            caps_i, declen_i, emb, xh, out, t);
        // gates = xh @ [W_ih ; W_hh]^T (K-split at 2560, split-K S=8)
        k_mgemm<4, 2, 0, 0><<<dim3(1, 16, 8), 256, 0, stream>>>(xh, 3072, W_ih_b, W_hh_b,
            nullptr, gp, nullptr, 2048, 3072, 8, 0, 2560, 64);
        k_lstm<<<B_, 512, 0, stream>>>(gp, b_ih, b_hh, g_h, be_h, g_c, be_c,
            xh, cbuf, hseq, declen_i, t);
    }

    // inactive rows -> zeros; active rows -> compacted GEMM with coalesced epilogue
    k_zero<<<B_ * T_, 256, 0, stream>>>(declen_i, out);
    k_preds<<<7750, 256, 0, stream>>>(hseq, W_fc_b, b_fc, rmap, orow, mact, out);
}

// Round 10
// 2086.156 us; speedup vs baseline: 4.2865x; 1.0822x over previous
//
#include <hip/hip_runtime.h>
#include <cfloat>
#include <math.h>

#define B_ 64
#define P_ 196
#define ENC_ 2048
#define D_ 512
#define V_ 32000
#define L_ 32
#define T_ 31

// flat f32 output layout (reference return order)
#define OUT_PREDS 0L
#define OUT_CAPS  63488000L              // 64*31*32000
#define OUT_DECL  63490048L              // +64*32
#define OUT_ALPH  63490112L              // +64
#define OUT_ORDER 63878976L              // +64*31*196

typedef __bf16 bf16;
typedef __bf16 bf16x8 __attribute__((ext_vector_type(8)));
typedef __bf16 bf16x4 __attribute__((ext_vector_type(4)));
typedef __bf16 bf16x2 __attribute__((ext_vector_type(2)));
typedef float  f32x4  __attribute__((ext_vector_type(4)));

static __device__ __forceinline__ float sigmoidf_(float x) { return 1.f / (1.f + __expf(-x)); }

// ------- sort, caps gather, scalar outputs, full-row map (active + inactive) -------
__global__ void k_order(const int* __restrict__ cap_len, const int* __restrict__ caps,
                        int* __restrict__ order_i, int* __restrict__ declen_i,
                        int* __restrict__ caps_i, float* __restrict__ out,
                        int* __restrict__ rmap, int* __restrict__ orow, int* __restrict__ mact)
{
    __shared__ int len_s[B_], dl_s[B_];
    __shared__ int Msh;
    int tid = threadIdx.x;
    len_s[tid] = cap_len[tid];
    __syncthreads();
    int li = len_s[tid];
    int pos = 0;
    for (int j = 0; j < B_; ++j) {
        int lj = len_s[j];
        pos += (lj > li) || (lj == li && j < tid);   // stable descending rank
    }
    order_i[pos]  = tid;
    declen_i[pos] = li - 1;
    dl_s[pos]     = li - 1;
    out[OUT_ORDER + pos] = (float)tid;
    out[OUT_DECL  + pos] = (float)(li - 1);
    for (int l = 0; l < L_; ++l) {
        int tok = caps[tid * L_ + l];
        caps_i[pos * L_ + l] = tok;
        out[OUT_CAPS + pos * L_ + l] = (float)tok;
    }
    __syncthreads();
    int p = tid;
    int off = 0;
    for (int j = 0; j < p; ++j) off += dl_s[j];
    int dl = dl_s[p];
    if (p == B_ - 1) { Msh = off + dl; mact[0] = off + dl; }
    __syncthreads();
    // active slots [off, off+dl): GEMM rows; inactive slots: zero rows (sign-encoded)
    for (int tt = 0; tt < dl; ++tt) {
        rmap[off + tt] = tt * B_ + p;
        orow[off + tt] = p * T_ + tt;
    }
    int ibase = Msh + p * T_ - off;
    for (int tt = dl; tt < T_; ++tt) {
        rmap[ibase + (tt - dl)] = 0;
        orow[ibase + (tt - dl)] = -(p * T_ + tt) - 1;
    }
}

// ---------------- merged f32 -> bf16 convert (plain row-major mats) ----------------
struct CvtSegs { const float* s[3]; bf16* d[3]; long cum[4]; };
__global__ __launch_bounds__(256) void k_cvt_all(CvtSegs cs)
{
    long i8 = ((long)blockIdx.x * 256 + threadIdx.x) * 8;
    if (i8 >= cs.cum[3]) return;
    int k = 0;
    while (i8 >= cs.cum[k + 1]) ++k;
    long loc = i8 - cs.cum[k];
    const float* src = cs.s[k] + loc;
    float4 a = *(const float4*)(src);
    float4 b = *(const float4*)(src + 4);
    bf16x8 v;
    v[0]=(bf16)a.x; v[1]=(bf16)a.y; v[2]=(bf16)a.z; v[3]=(bf16)a.w;
    v[4]=(bf16)b.x; v[5]=(bf16)b.y; v[6]=(bf16)b.z; v[7]=(bf16)b.w;
    *(bf16x8*)(cs.d[k] + loc) = v;
}

// ------- pack f32 weights -> MFMA-fragment-ordered bf16 -------
// layout: dst[(n>>4)*Kv*16 + (k>>3)*128 + (n&15)*8 + (k&7)]
// MODE 0: plain s1[N][Kv]; 1: N-split at Nsp (both row-len Kv); 2: K-split at Ksp
template<int MODE>
__global__ __launch_bounds__(256)
void k_packB(const float* __restrict__ s1, const float* __restrict__ s2,
             bf16* __restrict__ dst, int Kv, int Nsp, int Ksp)
{
    const int ntile = blockIdx.x, tid = threadIdx.x;
    long tbase = (long)ntile * Kv * 16;
    const int groups = Kv * 2;                    // (Kv/8) * 16
    for (int g = tid; g < groups; g += 256) {
        int kkq = g >> 4, r16 = g & 15;
        int n = ntile * 16 + r16, k0 = kkq * 8;
        const float* src;
        if (MODE == 0)      src = s1 + (long)n * Kv + k0;
        else if (MODE == 1) src = (n < Nsp) ? s1 + (long)n * Kv + k0
                                            : s2 + (long)(n - Nsp) * Kv + k0;
        else                src = (k0 < Ksp) ? s1 + (long)n * Ksp + k0
                                             : s2 + (long)n * (Kv - Ksp) + (k0 - Ksp);
        float4 a = *(const float4*)src;
        float4 b = *(const float4*)(src + 4);
        bf16x8 v;
        v[0]=(bf16)a.x; v[1]=(bf16)a.y; v[2]=(bf16)a.z; v[3]=(bf16)a.w;
        v[4]=(bf16)b.x; v[5]=(bf16)b.y; v[6]=(bf16)b.z; v[7]=(bf16)b.w;
        *(bf16x8*)(dst + tbase + (long)kkq * 128 + r16 * 8) = v;
    }
}

// ------- pack hseq (gathered by rmap) -> fragment order for preds A -------
__global__ __launch_bounds__(256)
void k_packA(const bf16* __restrict__ hseq, const int* __restrict__ rmap, bf16* __restrict__ dst)
{
    const int mt = blockIdx.x, tid = threadIdx.x;
    long tbase = (long)mt * 32768;
    for (int g = tid; g < 4096; g += 256) {       // mi(4) x kkq(64) x r16(16)
        int mi = g >> 10, rem = g & 1023, kkq = rem >> 4, r16 = rem & 15;
        int row = rmap[mt * 64 + mi * 16 + r16];
        bf16x8 v = *(const bf16x8*)(hseq + (long)row * 512 + kkq * 8);
        *(bf16x8*)(dst + tbase + mi * 8192 + (long)kkq * 128 + r16 * 8) = v;
    }
}

// ---------------- enc gather-by-order + convert to bf16 ----------------
__global__ __launch_bounds__(256) void k_cvt_enc(const float* __restrict__ enc,
                                                 const int* __restrict__ order_i,
                                                 bf16* __restrict__ enc_s)
{
    long i = ((long)blockIdx.x * 256 + threadIdx.x) * 8;
    int b = (int)(i / ((long)P_ * ENC_));
    long rem = i - (long)b * P_ * ENC_;
    const float* src = enc + (long)order_i[b] * P_ * ENC_ + rem;
    float4 a = *(const float4*)(src);
    float4 c = *(const float4*)(src + 4);
    bf16x8 v;
    v[0]=(bf16)a.x; v[1]=(bf16)a.y; v[2]=(bf16)a.z; v[3]=(bf16)a.w;
    v[4]=(bf16)c.x; v[5]=(bf16)c.y; v[6]=(bf16)c.z; v[7]=(bf16)c.w;
    *(bf16x8*)(enc_s + i) = v;
}

// ---------------- mean over pixels ----------------
__global__ __launch_bounds__(256) void k_meanb(const bf16* __restrict__ enc_s, bf16* __restrict__ mean_b)
{
    int b = blockIdx.x, col = blockIdx.y * 256 + threadIdx.x;
    float s = 0.f;
    const bf16* eb = enc_s + (long)b * P_ * ENC_ + col;
    for (int p = 0; p < P_; ++p) s += (float)eb[(long)p * ENC_];
    mean_b[(long)b * ENC_ + col] = (bf16)(s * (1.f / (float)P_));
}

// ---------------- MFMA GEMM: C[M][N] = A[M][K](bf16) * B[N][K]^T(bf16) ------
// 256 thr = 4 waves; tile (MI*16) x 128; swapped-operand mfma -> dwordx4 stores.
// PK=1: B is fragment-packed (seams resolved at pack time; FUSE ignored).
// FUSE: 0=single B, 1=N-split at Nsp. EPI: 0=RAW f32 slot z, 1=bf16 +bias.
// SWZ:  0=3D grid; 1=att1 392 blocks XCD-chunked
template<int MI, int FUSE, int EPI, int SWZ, int PK>
__global__ void __launch_bounds__(256)
k_mgemm(const bf16* __restrict__ A, long lda,
        const bf16* __restrict__ B1, const bf16* __restrict__ B2,
        const float* __restrict__ bias,
        float* __restrict__ Cf, bf16* __restrict__ Cb,
        int N, int K, int kspl, int Nsp, int Mtot)
{
    const int tid = threadIdx.x;
    const int lane = tid & 63, w = tid >> 6;
    int mt, nt, z;
    if (SWZ == 0) { mt = blockIdx.x; nt = blockIdx.y; z = blockIdx.z; }
    else          { int o = blockIdx.x; int wg = (o & 7) * 49 + (o >> 3);
                    mt = wg >> 2; nt = wg & 3; z = 0; }
    const int krange = K / kspl;
    const int k0 = z * krange, k1 = k0 + krange;
    const int r16 = lane & 15, kq = lane >> 4;
    const int koff = kq * 8;

    const bf16* Ap = A + (long)(mt * (MI * 16) + r16) * lda + koff;
    const int ncol0 = nt * 128 + w * 32;

    const bf16* Bp[2];
#pragma unroll
    for (int ni = 0; ni < 2; ++ni) {
        if (PK) {
            Bp[ni] = B1 + (long)((ncol0 + ni * 16) >> 4) * ((long)K * 16) + kq * 128 + r16 * 8;
        } else {
            int n = ncol0 + ni * 16 + r16;
            if (FUSE == 1)
                Bp[ni] = (n < Nsp) ? B1 + (long)n * K + koff
                                   : B2 + (long)(n - Nsp) * K + koff;
            else
                Bp[ni] = B1 + (long)n * K + koff;
        }
    }

    auto loadA = [&](int kk, bf16x8* dst) {
#pragma unroll
        for (int mi = 0; mi < MI; ++mi)
            dst[mi] = *(const bf16x8*)(Ap + (long)mi * 16 * lda + kk);
    };
    auto loadB = [&](int kk, bf16x8* dst) {
#pragma unroll
        for (int ni = 0; ni < 2; ++ni)
            dst[ni] = PK ? *(const bf16x8*)(Bp[ni] + (long)kk * 16)
                         : *(const bf16x8*)(Bp[ni] + kk);
    };

    f32x4 acc[MI][2] = {};
    bf16x8 af[MI], bfr[2];
    loadA(k0, af); loadB(k0, bfr);
    for (int kk = k0 + 32; kk < k1; kk += 32) {
        bf16x8 af2[MI], bf2[2];
        loadA(kk, af2); loadB(kk, bf2);
#pragma unroll
        for (int mi = 0; mi < MI; ++mi)
#pragma unroll
            for (int ni = 0; ni < 2; ++ni)
                acc[mi][ni] = __builtin_amdgcn_mfma_f32_16x16x32_bf16(bfr[ni], af[mi], acc[mi][ni], 0, 0, 0);
#pragma unroll
        for (int mi = 0; mi < MI; ++mi) af[mi] = af2[mi];
#pragma unroll
        for (int ni = 0; ni < 2; ++ni) bfr[ni] = bf2[ni];
    }
#pragma unroll
    for (int mi = 0; mi < MI; ++mi)
#pragma unroll
        for (int ni = 0; ni < 2; ++ni)
            acc[mi][ni] = __builtin_amdgcn_mfma_f32_16x16x32_bf16(bfr[ni], af[mi], acc[mi][ni], 0, 0, 0);

#pragma unroll
    for (int mi = 0; mi < MI; ++mi) {
        const int row = mt * (MI * 16) + mi * 16 + r16;
#pragma unroll
        for (int ni = 0; ni < 2; ++ni) {
            const int col = ncol0 + ni * 16 + kq * 4;
            f32x4 v = acc[mi][ni];
            if (EPI == 0) {
                *(f32x4*)(Cf + (long)z * Mtot * N + (long)row * N + col) = v;
            } else {
                f32x4 bv = *(const f32x4*)(bias + col);
                bf16x4 o;
                o[0]=(bf16)(v[0]+bv[0]); o[1]=(bf16)(v[1]+bv[1]);
                o[2]=(bf16)(v[2]+bv[2]); o[3]=(bf16)(v[3]+bv[3]);
                *(bf16x4*)(Cb + (long)row * N + col) = o;
            }
        }
    }
}

// ---------------- init h,c = LN(mean_enc @ W^T + b) ----------------
__global__ __launch_bounds__(512)
void k_initln(const float* __restrict__ pi,
              const float* __restrict__ b_h, const float* __restrict__ b_c,
              const float* __restrict__ g_h, const float* __restrict__ be_h,
              const float* __restrict__ g_c, const float* __restrict__ be_c,
              bf16* __restrict__ xh, float* __restrict__ cbuf)
{
    int b = blockIdx.x, d = threadIdx.x;
    float yh = pi[(long)b * 1024 + d]       + b_h[d];
    float yc = pi[(long)b * 1024 + 512 + d] + b_c[d];
    __shared__ float r1[512], r2[512], r3[512], r4[512];
    r1[d] = yh; r2[d] = yh * yh; r3[d] = yc; r4[d] = yc * yc;
    __syncthreads();
    for (int s = 256; s > 0; s >>= 1) {
        if (d < s) { r1[d]+=r1[d+s]; r2[d]+=r2[d+s]; r3[d]+=r3[d+s]; r4[d]+=r4[d+s]; }
        __syncthreads();
    }
    float mh = r1[0] * (1.f/512.f), vh = r2[0] * (1.f/512.f) - mh*mh;
    float mc = r3[0] * (1.f/512.f), vc = r4[0] * (1.f/512.f) - mc*mc;
    float hln = (yh - mh) * rsqrtf(vh + 1e-5f) * g_h[d] + be_h[d];
    float cln = (yc - mc) * rsqrtf(vc + 1e-5f) * g_c[d] + be_c[d];
    xh[(long)b * 3072 + 2560 + d] = (bf16)hln;
    cbuf[(long)b * 512 + d] = cln;
}

// ------- fused attention: alpha + awe*gate + emb; 128 blocks = (b, seg of 1024 cols) -------
__global__ __launch_bounds__(512)
void k_attn(const float* __restrict__ att2gate, const float* __restrict__ b_dec,
            const float* __restrict__ b_beta, const float* __restrict__ Wfull,
            const bf16* __restrict__ att1_b, const bf16* __restrict__ enc_s,
            const int* __restrict__ caps_i, const int* __restrict__ declen_i,
            const float* __restrict__ emb,
            bf16* __restrict__ xh, float* __restrict__ out, int t)
{
    const int b = blockIdx.x >> 1, seg = blockIdx.x & 1, tid = threadIdx.x;
    if (t >= declen_i[b]) {
        if (seg == 1 && tid < P_) out[OUT_ALPH + ((long)b * T_ + t) * P_ + tid] = 0.f;
        return;
    }
    __shared__ float att2s[512], wf[512], red[512], alp[P_];
    {
        float s = b_dec[tid];
#pragma unroll
        for (int zz = 0; zz < 4; ++zz) s += att2gate[((long)zz * 64 + b) * 2560 + tid];
        att2s[tid] = s;
        wf[tid] = Wfull[tid];
    }
    __syncthreads();
    float ev = -FLT_MAX;
    if (tid < P_) {
        const bf16* ar = att1_b + ((long)b * P_ + tid) * 512;
        float acc = 0.f;
        for (int a0 = 0; a0 < 512; a0 += 8) {
            bf16x8 v = *(const bf16x8*)(ar + a0);
#pragma unroll
            for (int j = 0; j < 8; ++j)
                acc += fmaxf((float)v[j] + att2s[a0 + j], 0.f) * wf[a0 + j];
        }
        ev = acc;   // + b_full: softmax-invariant
    }
    red[tid] = ev;
    __syncthreads();
    for (int s = 256; s > 0; s >>= 1) { if (tid < s) red[tid] = fmaxf(red[tid], red[tid + s]); __syncthreads(); }
    float mx = red[0];
    __syncthreads();
    float ex = (tid < P_) ? __expf(ev - mx) : 0.f;
    red[tid] = ex;
    __syncthreads();
    for (int s = 256; s > 0; s >>= 1) { if (tid < s) red[tid] += red[tid + s]; __syncthreads(); }
    float inv = 1.f / red[0];
    if (tid < P_) alp[tid] = ex * inv;
    __syncthreads();
    if (seg == 1 && tid < P_)
        out[OUT_ALPH + ((long)b * T_ + t) * P_ + tid] = alp[tid];
    // awe for this 1024-col segment (bf16x2 per thread)
    const int c0 = seg * 1024 + tid * 2;
    const bf16* eb = enc_s + (long)b * P_ * ENC_ + c0;
    float a0 = 0.f, a1 = 0.f;
#pragma unroll 4
    for (int p = 0; p < P_; ++p) {
        bf16x2 v = *(const bf16x2*)(eb + (long)p * ENC_);
        float al = alp[p];
        a0 += al * (float)v[0]; a1 += al * (float)v[1];
    }
    float g0 = b_beta[c0], g1 = b_beta[c0 + 1];
#pragma unroll
    for (int zz = 0; zz < 4; ++zz) {
        const float* gs = att2gate + ((long)zz * 64 + b) * 2560 + 512 + c0;
        g0 += gs[0]; g1 += gs[1];
    }
    bf16x2 o;
    o[0] = (bf16)(a0 * sigmoidf_(g0));
    o[1] = (bf16)(a1 * sigmoidf_(g1));
    *(bf16x2*)(xh + (long)b * 3072 + 512 + c0) = o;
    if (seg == 0) {
        int tok = caps_i[b * L_ + t];
        xh[(long)b * 3072 + tid] = (bf16)emb[(long)tok * 512 + tid];
    }
}

// -------- LSTM + 2x LN + state update + hseq record --------
__global__ __launch_bounds__(512)
void k_lstm(const float* __restrict__ gp, const float* __restrict__ b_ih, const float* __restrict__ b_hh,
            const float* __restrict__ g_h, const float* __restrict__ be_h,
            const float* __restrict__ g_c, const float* __restrict__ be_c,
            bf16* __restrict__ xh, float* __restrict__ cbuf, bf16* __restrict__ hseq,
            const int* __restrict__ declen_i, int t)
{
    int b = blockIdx.x, d = threadIdx.x;
    if (t >= declen_i[b]) return;
    float iv = b_ih[d]        + b_hh[d];
    float fv = b_ih[512 + d]  + b_hh[512 + d];
    float gv = b_ih[1024 + d] + b_hh[1024 + d];
    float ov = b_ih[1536 + d] + b_hh[1536 + d];
#pragma unroll
    for (int s = 0; s < 8; ++s) {
        const float* gs = gp + ((long)s * B_ + b) * 2048;
        iv += gs[d]; fv += gs[512 + d]; gv += gs[1024 + d]; ov += gs[1536 + d];
    }
    float cn = sigmoidf_(fv) * cbuf[(long)b * 512 + d] + sigmoidf_(iv) * tanhf(gv);
    float hn = sigmoidf_(ov) * tanhf(cn);
    __shared__ float r1[512], r2[512], r3[512], r4[512];
    r1[d] = hn; r2[d] = hn * hn; r3[d] = cn; r4[d] = cn * cn;
    __syncthreads();
    for (int s = 256; s > 0; s >>= 1) {
        if (d < s) { r1[d]+=r1[d+s]; r2[d]+=r2[d+s]; r3[d]+=r3[d+s]; r4[d]+=r4[d+s]; }
        __syncthreads();
    }
    float mh = r1[0] * (1.f/512.f), vh = r2[0] * (1.f/512.f) - mh*mh;
    float mc = r3[0] * (1.f/512.f), vc = r4[0] * (1.f/512.f) - mc*mc;
    float hln = (hn - mh) * rsqrtf(vh + 1e-5f) * g_h[d] + be_h[d];
    float cln = (cn - mc) * rsqrtf(vc + 1e-5f) * g_c[d] + be_c[d];
    bf16 hv = (bf16)hln;
    xh[(long)b * 3072 + 2560 + d] = hv;
    hseq[((long)t * B_ + b) * 512 + d] = hv;
    cbuf[(long)b * 512 + d] = cln;
}

// -------- preds: packed A/B fragment loads; zero-fill merged (sign-encoded orow) --------
__global__ __launch_bounds__(256)
void k_preds(const bf16* __restrict__ Apk, const bf16* __restrict__ Bpk,
             const float* __restrict__ bias, const int* __restrict__ orow,
             const int* __restrict__ mact, float* __restrict__ out)
{
    int o = blockIdx.x; int xcd = o & 7;
    int base = xcd < 6 ? xcd * 969 : 5814 + (xcd - 6) * 968;
    int wg = base + (o >> 3);
    int nt = wg / 31, mt = wg - 31 * nt;
    __shared__ int os[64];
    __shared__ __align__(16) float ct[64][132];
    const int tid = threadIdx.x, lane = tid & 63, w = tid >> 6;
    const int r16 = lane & 15, kq = lane >> 4;
    if (tid < 64) os[tid] = orow[mt * 64 + tid];
    __syncthreads();
    const int r0 = tid >> 5, cc = (tid & 31) * 4;
    const int gcol = nt * 128 + cc;
    if (mt * 64 >= mact[0]) {          // pure-inactive tile: zero-fill only
        f32x4 zz = {0.f, 0.f, 0.f, 0.f};
#pragma unroll
        for (int it = 0; it < 8; ++it) {
            int r = it * 8 + r0;
            int row = -os[r] - 1;
            *(f32x4*)(out + OUT_PREDS + (long)row * V_ + gcol) = zz;
        }
        return;
    }
    const bf16* Ap[4];
#pragma unroll
    for (int mi = 0; mi < 4; ++mi)
        Ap[mi] = Apk + (long)mt * 32768 + mi * 8192 + kq * 128 + r16 * 8;
    const bf16* Bp[2];
#pragma unroll
    for (int ni = 0; ni < 2; ++ni)
        Bp[ni] = Bpk + (long)((nt * 128 + w * 32 + ni * 16) >> 4) * 8192 + kq * 128 + r16 * 8;

    f32x4 acc[4][2] = {};
    bf16x8 af[4], bfr[2];
#pragma unroll
    for (int mi = 0; mi < 4; ++mi) af[mi] = *(const bf16x8*)(Ap[mi]);
#pragma unroll
    for (int ni = 0; ni < 2; ++ni) bfr[ni] = *(const bf16x8*)(Bp[ni]);
    for (int kk = 32; kk < 512; kk += 32) {
        bf16x8 af2[4], bf2[2];
#pragma unroll
        for (int mi = 0; mi < 4; ++mi) af2[mi] = *(const bf16x8*)(Ap[mi] + kk * 16);
#pragma unroll
        for (int ni = 0; ni < 2; ++ni) bf2[ni] = *(const bf16x8*)(Bp[ni] + kk * 16);
#pragma unroll
        for (int mi = 0; mi < 4; ++mi)
#pragma unroll
            for (int ni = 0; ni < 2; ++ni)
                acc[mi][ni] = __builtin_amdgcn_mfma_f32_16x16x32_bf16(bfr[ni], af[mi], acc[mi][ni], 0, 0, 0);
#pragma unroll
        for (int mi = 0; mi < 4; ++mi) af[mi] = af2[mi];
#pragma unroll
        for (int ni = 0; ni < 2; ++ni) bfr[ni] = bf2[ni];
    }
#pragma unroll
    for (int mi = 0; mi < 4; ++mi)
#pragma unroll
        for (int ni = 0; ni < 2; ++ni)
            acc[mi][ni] = __builtin_amdgcn_mfma_f32_16x16x32_bf16(bfr[ni], af[mi], acc[mi][ni], 0, 0, 0);

#pragma unroll
    for (int mi = 0; mi < 4; ++mi)
#pragma unroll
        for (int ni = 0; ni < 2; ++ni)
            *(f32x4*)&ct[mi * 16 + r16][w * 32 + ni * 16 + kq * 4] = acc[mi][ni];
    __syncthreads();
    f32x4 bv = *(const f32x4*)(bias + gcol);
    f32x4 zz = {0.f, 0.f, 0.f, 0.f};
#pragma unroll
    for (int it = 0; it < 8; ++it) {
        int r = it * 8 + r0;
        int orv = os[r];
        if (orv >= 0) {
            f32x4 v = *(f32x4*)&ct[r][cc];
            f32x4 oo;
            oo[0] = v[0] + bv[0]; oo[1] = v[1] + bv[1];
            oo[2] = v[2] + bv[2]; oo[3] = v[3] + bv[3];
            *(f32x4*)(out + OUT_PREDS + (long)orv * V_ + gcol) = oo;
        } else {
            int row = -orv - 1;
            *(f32x4*)(out + OUT_PREDS + (long)row * V_ + gcol) = zz;
        }
    }
}

extern "C" void kernel_launch(void* const* d_in, const int* in_sizes, int n_in,
                              void* d_out, int out_size, void* d_ws, size_t ws_size,
                              hipStream_t stream)
{
    const float* enc       = (const float*)d_in[0];
    const int*   caps      = (const int*)  d_in[1];
    const int*   caplen    = (const int*)  d_in[2];
    const float* emb       = (const float*)d_in[3];
    const float* W_enc_att = (const float*)d_in[4];
    const float* b_enc_att = (const float*)d_in[5];
    const float* W_dec_att = (const float*)d_in[6];
    const float* b_dec_att = (const float*)d_in[7];
    const float* W_full    = (const float*)d_in[8];
    // d_in[9] = b_full (softmax-invariant, unused)
    const float* W_ih      = (const float*)d_in[10];
    const float* b_ih      = (const float*)d_in[11];
    const float* W_hh      = (const float*)d_in[12];
    const float* b_hh      = (const float*)d_in[13];
    const float* g_h       = (const float*)d_in[14];
    const float* be_h      = (const float*)d_in[15];
    const float* g_c       = (const float*)d_in[16];
    const float* be_c      = (const float*)d_in[17];
    const float* W_init_h  = (const float*)d_in[18];
    const float* b_init_h  = (const float*)d_in[19];
    const float* W_init_c  = (const float*)d_in[20];
    const float* b_init_c  = (const float*)d_in[21];
    const float* W_beta    = (const float*)d_in[22];
    const float* b_beta    = (const float*)d_in[23];
    const float* W_fc      = (const float*)d_in[24];
    const float* b_fc      = (const float*)d_in[25];
    float* out = (float*)d_out;

    char* w = (char*)d_ws;
    auto alloc = [&](size_t bytes) { char* p = w; w += (bytes + 255) & ~(size_t)255; return p; };
    int*   order_i  = (int*)  alloc(B_ * 4);
    int*   declen_i = (int*)  alloc(B_ * 4);
    int*   caps_i   = (int*)  alloc(B_ * L_ * 4);
    int*   rmap     = (int*)  alloc(2048 * 4);
    int*   orow     = (int*)  alloc(2048 * 4);
    int*   mact     = (int*)  alloc(256);
    bf16*  enc_s    = (bf16*) alloc((size_t)B_ * P_ * ENC_ * 2);
    bf16*  mean_b   = (bf16*) alloc((size_t)B_ * ENC_ * 2);
    bf16*  att1_b   = (bf16*) alloc((size_t)B_ * P_ * 512 * 2);
    float* pi       = (float*)alloc((size_t)B_ * 1024 * 4);
    float* cbuf     = (float*)alloc((size_t)B_ * 512 * 4);
    bf16*  xh       = (bf16*) alloc((size_t)B_ * 3072 * 2);
    float* att2gate = (float*)alloc((size_t)4 * B_ * 2560 * 4);
    float* gp       = (float*)alloc((size_t)8 * B_ * 2048 * 4);
    bf16*  hseq     = (bf16*) alloc((size_t)T_ * B_ * 512 * 2);
    bf16*  Apk      = (bf16*) alloc((size_t)31 * 32768 * 2);
    bf16*  W_enc_b  = (bf16*) alloc((size_t)512 * 2048 * 2);
    bf16*  W_inh_b  = (bf16*) alloc((size_t)512 * 2048 * 2);
    bf16*  W_inc_b  = (bf16*) alloc((size_t)512 * 2048 * 2);
    bf16*  Wab_pk   = (bf16*) alloc((size_t)2560 * 512 * 2);    // [W_dec|W_beta] packed
    bf16*  Wg_pk    = (bf16*) alloc((size_t)2048 * 3072 * 2);   // [W_ih;W_hh] packed
    bf16*  Wfc_pk   = (bf16*) alloc((size_t)32000 * 512 * 2);   // W_fc packed

    k_order<<<1, B_, 0, stream>>>(caplen, caps, order_i, declen_i, caps_i, out, rmap, orow, mact);
    k_cvt_enc<<<12544, 256, 0, stream>>>(enc, order_i, enc_s);
    k_meanb<<<dim3(B_, 8), 256, 0, stream>>>(enc_s, mean_b);

    // plain converts for unpacked-path weights
    CvtSegs cs;
    const float* srcs[3] = {W_enc_att, W_init_h, W_init_c};
    bf16* dsts[3] = {W_enc_b, W_inh_b, W_inc_b};
    long ns[3] = {512L*2048, 512L*2048, 512L*2048};
    long cum = 0;
    for (int i = 0; i < 3; ++i) { cs.s[i] = srcs[i]; cs.d[i] = dsts[i]; cs.cum[i] = cum; cum += ns[i]; }
    cs.cum[3] = cum;
    k_cvt_all<<<(int)((cum / 8 + 255) / 256), 256, 0, stream>>>(cs);

    // fragment-packed weights
    k_packB<1><<<160, 256, 0, stream>>>(W_dec_att, W_beta, Wab_pk, 512, 512, 0);
    k_packB<2><<<128, 256, 0, stream>>>(W_ih, W_hh, Wg_pk, 3072, 0, 2560);
    k_packB<0><<<2000, 256, 0, stream>>>(W_fc, nullptr, Wfc_pk, 512, 0, 0);

    // init: [h|c] = mean_b @ [W_init_h|W_init_c]^T (N-split), then LN
    k_mgemm<4, 1, 0, 0, 0><<<dim3(1, 8, 1), 256, 0, stream>>>(mean_b, 2048, W_inh_b, W_inc_b,
        nullptr, pi, nullptr, 1024, 2048, 1, 512, 64);
    k_initln<<<B_, 512, 0, stream>>>(pi, b_init_h, b_init_c, g_h, be_h, g_c, be_c, xh, cbuf);

    // att1 = enc_s @ W_enc^T + b -> bf16 [12544][512]; BM=128, 392 blocks XCD-chunked
    k_mgemm<8, 0, 1, 1, 0><<<392, 256, 0, stream>>>(enc_s, 2048, W_enc_b, nullptr,
        b_enc_att, nullptr, att1_b, 512, 2048, 1, 0, 12544);

    for (int t = 0; t < T_; ++t) {
        // [att2|gate_pre] = h @ packed[W_dec|W_beta]^T (split-K S=4 raw slots)
        k_mgemm<4, 0, 0, 0, 1><<<dim3(1, 20, 4), 256, 0, stream>>>(xh + 2560, 3072, Wab_pk, nullptr,
            nullptr, att2gate, nullptr, 2560, 512, 4, 0, 64);
        k_attn<<<128, 512, 0, stream>>>(att2gate, b_dec_att, b_beta, W_full, att1_b, enc_s,
            caps_i, declen_i, emb, xh, out, t);
        // gates = xh @ packed[W_ih;W_hh]^T (split-K S=8)
        k_mgemm<4, 0, 0, 0, 1><<<dim3(1, 16, 8), 256, 0, stream>>>(xh, 3072, Wg_pk, nullptr,
            nullptr, gp, nullptr, 2048, 3072, 8, 0, 64);
        k_lstm<<<B_, 512, 0, stream>>>(gp, b_ih, b_hh, g_h, be_h, g_c, be_c,
            xh, cbuf, hseq, declen_i, t);
    }

    // pack hseq (rmap gather) then preds with zero-fill merged
    k_packA<<<31, 256, 0, stream>>>(hseq, rmap, Apk);
    k_preds<<<7750, 256, 0, stream>>>(Apk, Wfc_pk, b_fc, orow, mact, out);
}

// Round 11
// 2084.740 us; speedup vs baseline: 4.2894x; 1.0007x over previous
//
#include <hip/hip_runtime.h>
#include <cfloat>
#include <math.h>

#define B_ 64
#define P_ 196
#define ENC_ 2048
#define D_ 512
#define V_ 32000
#define L_ 32
#define T_ 31

// flat f32 output layout (reference return order)
#define OUT_PREDS 0L
#define OUT_CAPS  63488000L              // 64*31*32000
#define OUT_DECL  63490048L              // +64*32
#define OUT_ALPH  63490112L              // +64
#define OUT_ORDER 63878976L              // +64*31*196

typedef __bf16 bf16;
typedef __bf16 bf16x8 __attribute__((ext_vector_type(8)));
typedef __bf16 bf16x4 __attribute__((ext_vector_type(4)));
typedef __bf16 bf16x2 __attribute__((ext_vector_type(2)));
typedef float  f32x4  __attribute__((ext_vector_type(4)));

static __device__ __forceinline__ float sigmoidf_(float x) { return 1.f / (1.f + __expf(-x)); }

// ------- sort, caps gather, scalar outputs, full-row map (active + inactive) -------
__global__ void k_order(const int* __restrict__ cap_len, const int* __restrict__ caps,
                        int* __restrict__ order_i, int* __restrict__ declen_i,
                        int* __restrict__ caps_i, float* __restrict__ out,
                        int* __restrict__ rmap, int* __restrict__ orow, int* __restrict__ mact)
{
    __shared__ int len_s[B_], dl_s[B_];
    __shared__ int Msh;
    int tid = threadIdx.x;
    len_s[tid] = cap_len[tid];
    __syncthreads();
    int li = len_s[tid];
    int pos = 0;
    for (int j = 0; j < B_; ++j) {
        int lj = len_s[j];
        pos += (lj > li) || (lj == li && j < tid);   // stable descending rank
    }
    order_i[pos]  = tid;
    declen_i[pos] = li - 1;
    dl_s[pos]     = li - 1;
    out[OUT_ORDER + pos] = (float)tid;
    out[OUT_DECL  + pos] = (float)(li - 1);
    for (int l = 0; l < L_; ++l) {
        int tok = caps[tid * L_ + l];
        caps_i[pos * L_ + l] = tok;
        out[OUT_CAPS + pos * L_ + l] = (float)tok;
    }
    __syncthreads();
    int p = tid;
    int off = 0;
    for (int j = 0; j < p; ++j) off += dl_s[j];
    int dl = dl_s[p];
    if (p == B_ - 1) { Msh = off + dl; mact[0] = off + dl; }
    __syncthreads();
    // active slots [off, off+dl): GEMM rows; inactive slots: zero rows (sign-encoded)
    for (int tt = 0; tt < dl; ++tt) {
        rmap[off + tt] = tt * B_ + p;
        orow[off + tt] = p * T_ + tt;
    }
    int ibase = Msh + p * T_ - off;
    for (int tt = dl; tt < T_; ++tt) {
        rmap[ibase + (tt - dl)] = 0;
        orow[ibase + (tt - dl)] = -(p * T_ + tt) - 1;
    }
}

// ---------------- merged f32 -> bf16 convert (plain row-major mats) ----------------
struct CvtSegs { const float* s[2]; bf16* d[2]; long cum[3]; };
__global__ __launch_bounds__(256) void k_cvt_all(CvtSegs cs)
{
    long i8 = ((long)blockIdx.x * 256 + threadIdx.x) * 8;
    if (i8 >= cs.cum[2]) return;
    int k = 0;
    while (i8 >= cs.cum[k + 1]) ++k;
    long loc = i8 - cs.cum[k];
    const float* src = cs.s[k] + loc;
    float4 a = *(const float4*)(src);
    float4 b = *(const float4*)(src + 4);
    bf16x8 v;
    v[0]=(bf16)a.x; v[1]=(bf16)a.y; v[2]=(bf16)a.z; v[3]=(bf16)a.w;
    v[4]=(bf16)b.x; v[5]=(bf16)b.y; v[6]=(bf16)b.z; v[7]=(bf16)b.w;
    *(bf16x8*)(cs.d[k] + loc) = v;
}

// ------- pack f32 weights -> MFMA-fragment-ordered bf16 -------
// layout: dst[(n>>4)*Kv*16 + (k>>3)*128 + (n&15)*8 + (k&7)]
// MODE 0: plain s1[N][Kv]; 1: N-split at Nsp (both row-len Kv); 2: K-split at Ksp
template<int MODE>
__global__ __launch_bounds__(256)
void k_packB(const float* __restrict__ s1, const float* __restrict__ s2,
             bf16* __restrict__ dst, int Kv, int Nsp, int Ksp)
{
    const int ntile = blockIdx.x, tid = threadIdx.x;
    long tbase = (long)ntile * Kv * 16;
    const int groups = Kv * 2;                    // (Kv/8) * 16
    for (int g = tid; g < groups; g += 256) {
        int kkq = g >> 4, r16 = g & 15;
        int n = ntile * 16 + r16, k0 = kkq * 8;
        const float* src;
        if (MODE == 0)      src = s1 + (long)n * Kv + k0;
        else if (MODE == 1) src = (n < Nsp) ? s1 + (long)n * Kv + k0
                                            : s2 + (long)(n - Nsp) * Kv + k0;
        else                src = (k0 < Ksp) ? s1 + (long)n * Ksp + k0
                                             : s2 + (long)n * (Kv - Ksp) + (k0 - Ksp);
        float4 a = *(const float4*)src;
        float4 b = *(const float4*)(src + 4);
        bf16x8 v;
        v[0]=(bf16)a.x; v[1]=(bf16)a.y; v[2]=(bf16)a.z; v[3]=(bf16)a.w;
        v[4]=(bf16)b.x; v[5]=(bf16)b.y; v[6]=(bf16)b.z; v[7]=(bf16)b.w;
        *(bf16x8*)(dst + tbase + (long)kkq * 128 + r16 * 8) = v;
    }
}

// ------- pack hseq (gathered by rmap) -> fragment order for preds A -------
__global__ __launch_bounds__(256)
void k_packA(const bf16* __restrict__ hseq, const int* __restrict__ rmap, bf16* __restrict__ dst)
{
    const int mt = blockIdx.x, tid = threadIdx.x;
    long tbase = (long)mt * 32768;
    for (int g = tid; g < 4096; g += 256) {       // mi(4) x kkq(64) x r16(16)
        int mi = g >> 10, rem = g & 1023, kkq = rem >> 4, r16 = rem & 15;
        int row = rmap[mt * 64 + mi * 16 + r16];
        bf16x8 v = *(const bf16x8*)(hseq + (long)row * 512 + kkq * 8);
        *(bf16x8*)(dst + tbase + mi * 8192 + (long)kkq * 128 + r16 * 8) = v;
    }
}

// --- enc gather-by-order -> bf16, DUAL write: row-major enc_s + fragment enc_pk ---
__global__ __launch_bounds__(256) void k_cvt_enc(const float* __restrict__ enc,
                                                 const int* __restrict__ order_i,
                                                 bf16* __restrict__ enc_s,
                                                 bf16* __restrict__ enc_pk)
{
    long i = ((long)blockIdx.x * 256 + threadIdx.x) * 8;
    int r = (int)(i >> 11);                 // global sorted row (b*196+p)
    int k0 = (int)(i & 2047);
    int b = (int)(i / ((long)P_ * ENC_));
    long rem = i - (long)b * P_ * ENC_;
    const float* src = enc + (long)order_i[b] * P_ * ENC_ + rem;
    float4 a = *(const float4*)(src);
    float4 c = *(const float4*)(src + 4);
    bf16x8 v;
    v[0]=(bf16)a.x; v[1]=(bf16)a.y; v[2]=(bf16)a.z; v[3]=(bf16)a.w;
    v[4]=(bf16)c.x; v[5]=(bf16)c.y; v[6]=(bf16)c.z; v[7]=(bf16)c.w;
    *(bf16x8*)(enc_s + i) = v;
    *(bf16x8*)(enc_pk + (long)(r >> 4) * 32768 + (long)(k0 >> 3) * 128 + (r & 15) * 8) = v;
}

// ---------------- mean over pixels ----------------
__global__ __launch_bounds__(256) void k_meanb(const bf16* __restrict__ enc_s, bf16* __restrict__ mean_b)
{
    int b = blockIdx.x, col = blockIdx.y * 256 + threadIdx.x;
    float s = 0.f;
    const bf16* eb = enc_s + (long)b * P_ * ENC_ + col;
    for (int p = 0; p < P_; ++p) s += (float)eb[(long)p * ENC_];
    mean_b[(long)b * ENC_ + col] = (bf16)(s * (1.f / (float)P_));
}

// ---------------- MFMA GEMM: C[M][N] = A[M][K](bf16) * B[N][K]^T(bf16) ------
// 256 thr = 4 waves; tile (MI*16) x 128; swapped-operand mfma -> dwordx4 stores.
// PK=1: B fragment-packed. PA=1: A fragment-packed (row-tiles of 16).
// FUSE: 0=single B, 1=N-split at Nsp. EPI: 0=RAW f32 slot z, 1=bf16 +bias.
// SWZ:  0=3D grid; 1=att1 784 blocks XCD-chunked mt-major
template<int MI, int FUSE, int EPI, int SWZ, int PK, int PA>
__global__ void __launch_bounds__(256)
k_mgemm(const bf16* __restrict__ A, long lda,
        const bf16* __restrict__ B1, const bf16* __restrict__ B2,
        const float* __restrict__ bias,
        float* __restrict__ Cf, bf16* __restrict__ Cb,
        int N, int K, int kspl, int Nsp, int Mtot)
{
    const int tid = threadIdx.x;
    const int lane = tid & 63, w = tid >> 6;
    int mt, nt, z;
    if (SWZ == 0) { mt = blockIdx.x; nt = blockIdx.y; z = blockIdx.z; }
    else          { int o = blockIdx.x; int wg = (o & 7) * 98 + (o >> 3);
                    mt = wg >> 2; nt = wg & 3; z = 0; }
    const int krange = K / kspl;
    const int k0 = z * krange, k1 = k0 + krange;
    const int r16 = lane & 15, kq = lane >> 4;
    const int koff = kq * 8;

    const bf16* Ap[MI];
#pragma unroll
    for (int mi = 0; mi < MI; ++mi) {
        if (PA) Ap[mi] = A + (long)(mt * MI + mi) * ((long)K * 16) + kq * 128 + r16 * 8;
        else    Ap[mi] = A + (long)(mt * (MI * 16) + mi * 16 + r16) * lda + koff;
    }
    const int ncol0 = nt * 128 + w * 32;

    const bf16* Bp[2];
#pragma unroll
    for (int ni = 0; ni < 2; ++ni) {
        if (PK) {
            Bp[ni] = B1 + (long)((ncol0 + ni * 16) >> 4) * ((long)K * 16) + kq * 128 + r16 * 8;
        } else {
            int n = ncol0 + ni * 16 + r16;
            if (FUSE == 1)
                Bp[ni] = (n < Nsp) ? B1 + (long)n * K + koff
                                   : B2 + (long)(n - Nsp) * K + koff;
            else
                Bp[ni] = B1 + (long)n * K + koff;
        }
    }

    auto loadA = [&](int kk, bf16x8* dst) {
#pragma unroll
        for (int mi = 0; mi < MI; ++mi)
            dst[mi] = PA ? *(const bf16x8*)(Ap[mi] + (long)kk * 16)
                         : *(const bf16x8*)(Ap[mi] + kk);
    };
    auto loadB = [&](int kk, bf16x8* dst) {
#pragma unroll
        for (int ni = 0; ni < 2; ++ni)
            dst[ni] = PK ? *(const bf16x8*)(Bp[ni] + (long)kk * 16)
                         : *(const bf16x8*)(Bp[ni] + kk);
    };

    f32x4 acc[MI][2] = {};
    bf16x8 af[MI], bfr[2];
    loadA(k0, af); loadB(k0, bfr);
    for (int kk = k0 + 32; kk < k1; kk += 32) {
        bf16x8 af2[MI], bf2[2];
        loadA(kk, af2); loadB(kk, bf2);
#pragma unroll
        for (int mi = 0; mi < MI; ++mi)
#pragma unroll
            for (int ni = 0; ni < 2; ++ni)
                acc[mi][ni] = __builtin_amdgcn_mfma_f32_16x16x32_bf16(bfr[ni], af[mi], acc[mi][ni], 0, 0, 0);
#pragma unroll
        for (int mi = 0; mi < MI; ++mi) af[mi] = af2[mi];
#pragma unroll
        for (int ni = 0; ni < 2; ++ni) bfr[ni] = bf2[ni];
    }
#pragma unroll
    for (int mi = 0; mi < MI; ++mi)
#pragma unroll
        for (int ni = 0; ni < 2; ++ni)
            acc[mi][ni] = __builtin_amdgcn_mfma_f32_16x16x32_bf16(bfr[ni], af[mi], acc[mi][ni], 0, 0, 0);

#pragma unroll
    for (int mi = 0; mi < MI; ++mi) {
        const int row = mt * (MI * 16) + mi * 16 + r16;
#pragma unroll
        for (int ni = 0; ni < 2; ++ni) {
            const int col = ncol0 + ni * 16 + kq * 4;
            f32x4 v = acc[mi][ni];
            if (EPI == 0) {
                *(f32x4*)(Cf + (long)z * Mtot * N + (long)row * N + col) = v;
            } else {
                f32x4 bv = *(const f32x4*)(bias + col);
                bf16x4 o;
                o[0]=(bf16)(v[0]+bv[0]); o[1]=(bf16)(v[1]+bv[1]);
                o[2]=(bf16)(v[2]+bv[2]); o[3]=(bf16)(v[3]+bv[3]);
                *(bf16x4*)(Cb + (long)row * N + col) = o;
            }
        }
    }
}

// ---------------- init h,c = LN(mean_enc @ W^T + b) ----------------
__global__ __launch_bounds__(512)
void k_initln(const float* __restrict__ pi,
              const float* __restrict__ b_h, const float* __restrict__ b_c,
              const float* __restrict__ g_h, const float* __restrict__ be_h,
              const float* __restrict__ g_c, const float* __restrict__ be_c,
              bf16* __restrict__ xh, float* __restrict__ cbuf)
{
    int b = blockIdx.x, d = threadIdx.x;
    float yh = pi[(long)b * 1024 + d]       + b_h[d];
    float yc = pi[(long)b * 1024 + 512 + d] + b_c[d];
    __shared__ float r1[512], r2[512], r3[512], r4[512];
    r1[d] = yh; r2[d] = yh * yh; r3[d] = yc; r4[d] = yc * yc;
    __syncthreads();
    for (int s = 256; s > 0; s >>= 1) {
        if (d < s) { r1[d]+=r1[d+s]; r2[d]+=r2[d+s]; r3[d]+=r3[d+s]; r4[d]+=r4[d+s]; }
        __syncthreads();
    }
    float mh = r1[0] * (1.f/512.f), vh = r2[0] * (1.f/512.f) - mh*mh;
    float mc = r3[0] * (1.f/512.f), vc = r4[0] * (1.f/512.f) - mc*mc;
    float hln = (yh - mh) * rsqrtf(vh + 1e-5f) * g_h[d] + be_h[d];
    float cln = (yc - mc) * rsqrtf(vc + 1e-5f) * g_c[d] + be_c[d];
    xh[(long)b * 3072 + 2560 + d] = (bf16)hln;
    cbuf[(long)b * 512 + d] = cln;
}

// ------- fused attention: alpha + awe*gate + emb; 128 blocks = (b, seg of 1024 cols) -------
__global__ __launch_bounds__(512)
void k_attn(const float* __restrict__ att2gate, const float* __restrict__ b_dec,
            const float* __restrict__ b_beta, const float* __restrict__ Wfull,
            const bf16* __restrict__ att1_b, const bf16* __restrict__ enc_s,
            const int* __restrict__ caps_i, const int* __restrict__ declen_i,
            const float* __restrict__ emb,
            bf16* __restrict__ xh, float* __restrict__ out, int t)
{
    const int b = blockIdx.x >> 1, seg = blockIdx.x & 1, tid = threadIdx.x;
    if (t >= declen_i[b]) {
        if (seg == 1 && tid < P_) out[OUT_ALPH + ((long)b * T_ + t) * P_ + tid] = 0.f;
        return;
    }
    __shared__ float att2s[512], wf[512], red[512], alp[P_];
    {
        float s = b_dec[tid];
#pragma unroll
        for (int zz = 0; zz < 4; ++zz) s += att2gate[((long)zz * 64 + b) * 2560 + tid];
        att2s[tid] = s;
        wf[tid] = Wfull[tid];
    }
    __syncthreads();
    float ev = -FLT_MAX;
    if (tid < P_) {
        const bf16* ar = att1_b + ((long)b * P_ + tid) * 512;
        float acc = 0.f;
        for (int a0 = 0; a0 < 512; a0 += 8) {
            bf16x8 v = *(const bf16x8*)(ar + a0);
#pragma unroll
            for (int j = 0; j < 8; ++j)
                acc += fmaxf((float)v[j] + att2s[a0 + j], 0.f) * wf[a0 + j];
        }
        ev = acc;   // + b_full: softmax-invariant
    }
    red[tid] = ev;
    __syncthreads();
    for (int s = 256; s > 0; s >>= 1) { if (tid < s) red[tid] = fmaxf(red[tid], red[tid + s]); __syncthreads(); }
    float mx = red[0];
    __syncthreads();
    float ex = (tid < P_) ? __expf(ev - mx) : 0.f;
    red[tid] = ex;
    __syncthreads();
    for (int s = 256; s > 0; s >>= 1) { if (tid < s) red[tid] += red[tid + s]; __syncthreads(); }
    float inv = 1.f / red[0];
    if (tid < P_) alp[tid] = ex * inv;
    __syncthreads();
    if (seg == 1 && tid < P_)
        out[OUT_ALPH + ((long)b * T_ + t) * P_ + tid] = alp[tid];
    // awe for this 1024-col segment (bf16x2 per thread)
    const int c0 = seg * 1024 + tid * 2;
    const bf16* eb = enc_s + (long)b * P_ * ENC_ + c0;
    float a0 = 0.f, a1 = 0.f;
#pragma unroll 4
    for (int p = 0; p < P_; ++p) {
        bf16x2 v = *(const bf16x2*)(eb + (long)p * ENC_);
        float al = alp[p];
        a0 += al * (float)v[0]; a1 += al * (float)v[1];
    }
    float g0 = b_beta[c0], g1 = b_beta[c0 + 1];
#pragma unroll
    for (int zz = 0; zz < 4; ++zz) {
        const float* gs = att2gate + ((long)zz * 64 + b) * 2560 + 512 + c0;
        g0 += gs[0]; g1 += gs[1];
    }
    bf16x2 o;
    o[0] = (bf16)(a0 * sigmoidf_(g0));
    o[1] = (bf16)(a1 * sigmoidf_(g1));
    *(bf16x2*)(xh + (long)b * 3072 + 512 + c0) = o;
    if (seg == 0) {
        int tok = caps_i[b * L_ + t];
        xh[(long)b * 3072 + tid] = (bf16)emb[(long)tok * 512 + tid];
    }
}

// -------- LSTM + 2x LN + state update + hseq record --------
__global__ __launch_bounds__(512)
void k_lstm(const float* __restrict__ gp, const float* __restrict__ b_ih, const float* __restrict__ b_hh,
            const float* __restrict__ g_h, const float* __restrict__ be_h,
            const float* __restrict__ g_c, const float* __restrict__ be_c,
            bf16* __restrict__ xh, float* __restrict__ cbuf, bf16* __restrict__ hseq,
            const int* __restrict__ declen_i, int t)
{
    int b = blockIdx.x, d = threadIdx.x;
    if (t >= declen_i[b]) return;
    float iv = b_ih[d]        + b_hh[d];
    float fv = b_ih[512 + d]  + b_hh[512 + d];
    float gv = b_ih[1024 + d] + b_hh[1024 + d];
    float ov = b_ih[1536 + d] + b_hh[1536 + d];
#pragma unroll
    for (int s = 0; s < 8; ++s) {
        const float* gs = gp + ((long)s * B_ + b) * 2048;
        iv += gs[d]; fv += gs[512 + d]; gv += gs[1024 + d]; ov += gs[1536 + d];
    }
    float cn = sigmoidf_(fv) * cbuf[(long)b * 512 + d] + sigmoidf_(iv) * tanhf(gv);
    float hn = sigmoidf_(ov) * tanhf(cn);
    __shared__ float r1[512], r2[512], r3[512], r4[512];
    r1[d] = hn; r2[d] = hn * hn; r3[d] = cn; r4[d] = cn * cn;
    __syncthreads();
    for (int s = 256; s > 0; s >>= 1) {
        if (d < s) { r1[d]+=r1[d+s]; r2[d]+=r2[d+s]; r3[d]+=r3[d+s]; r4[d]+=r4[d+s]; }
        __syncthreads();
    }
    float mh = r1[0] * (1.f/512.f), vh = r2[0] * (1.f/512.f) - mh*mh;
    float mc = r3[0] * (1.f/512.f), vc = r4[0] * (1.f/512.f) - mc*mc;
    float hln = (hn - mh) * rsqrtf(vh + 1e-5f) * g_h[d] + be_h[d];
    float cln = (cn - mc) * rsqrtf(vc + 1e-5f) * g_c[d] + be_c[d];
    bf16 hv = (bf16)hln;
    xh[(long)b * 3072 + 2560 + d] = hv;
    hseq[((long)t * B_ + b) * 512 + d] = hv;
    cbuf[(long)b * 512 + d] = cln;
}

// -------- preds: packed A/B fragment loads; zero-fill merged (sign-encoded orow) --------
__global__ __launch_bounds__(256)
void k_preds(const bf16* __restrict__ Apk, const bf16* __restrict__ Bpk,
             const float* __restrict__ bias, const int* __restrict__ orow,
             const int* __restrict__ mact, float* __restrict__ out)
{
    int o = blockIdx.x; int xcd = o & 7;
    int base = xcd < 6 ? xcd * 969 : 5814 + (xcd - 6) * 968;
    int wg = base + (o >> 3);
    int nt = wg / 31, mt = wg - 31 * nt;
    __shared__ int os[64];
    __shared__ __align__(16) float ct[64][132];
    const int tid = threadIdx.x, lane = tid & 63, w = tid >> 6;
    const int r16 = lane & 15, kq = lane >> 4;
    if (tid < 64) os[tid] = orow[mt * 64 + tid];
    __syncthreads();
    const int r0 = tid >> 5, cc = (tid & 31) * 4;
    const int gcol = nt * 128 + cc;
    if (mt * 64 >= mact[0]) {          // pure-inactive tile: zero-fill only
        f32x4 zz = {0.f, 0.f, 0.f, 0.f};
#pragma unroll
        for (int it = 0; it < 8; ++it) {
            int r = it * 8 + r0;
            int row = -os[r] - 1;
            *(f32x4*)(out + OUT_PREDS + (long)row * V_ + gcol) = zz;
        }
        return;
    }
    const bf16* Ap[4];
#pragma unroll
    for (int mi = 0; mi < 4; ++mi)
        Ap[mi] = Apk + (long)mt * 32768 + mi * 8192 + kq * 128 + r16 * 8;
    const bf16* Bp[2];
#pragma unroll
    for (int ni = 0; ni < 2; ++ni)
        Bp[ni] = Bpk + (long)((nt * 128 + w * 32 + ni * 16) >> 4) * 8192 + kq * 128 + r16 * 8;

    f32x4 acc[4][2] = {};
    bf16x8 af[4], bfr[2];
#pragma unroll
    for (int mi = 0; mi < 4; ++mi) af[mi] = *(const bf16x8*)(Ap[mi]);
#pragma unroll
    for (int ni = 0; ni < 2; ++ni) bfr[ni] = *(const bf16x8*)(Bp[ni]);
    for (int kk = 32; kk < 512; kk += 32) {
        bf16x8 af2[4], bf2[2];
#pragma unroll
        for (int mi = 0; mi < 4; ++mi) af2[mi] = *(const bf16x8*)(Ap[mi] + kk * 16);
#pragma unroll
        for (int ni = 0; ni < 2; ++ni) bf2[ni] = *(const bf16x8*)(Bp[ni] + kk * 16);
#pragma unroll
        for (int mi = 0; mi < 4; ++mi)
#pragma unroll
            for (int ni = 0; ni < 2; ++ni)
                acc[mi][ni] = __builtin_amdgcn_mfma_f32_16x16x32_bf16(bfr[ni], af[mi], acc[mi][ni], 0, 0, 0);
#pragma unroll
        for (int mi = 0; mi < 4; ++mi) af[mi] = af2[mi];
#pragma unroll
        for (int ni = 0; ni < 2; ++ni) bfr[ni] = bf2[ni];
    }
#pragma unroll
    for (int mi = 0; mi < 4; ++mi)
#pragma unroll
        for (int ni = 0; ni < 2; ++ni)
            acc[mi][ni] = __builtin_amdgcn_mfma_f32_16x16x32_bf16(bfr[ni], af[mi], acc[mi][ni], 0, 0, 0);

#pragma unroll
    for (int mi = 0; mi < 4; ++mi)
#pragma unroll
        for (int ni = 0; ni < 2; ++ni)
            *(f32x4*)&ct[mi * 16 + r16][w * 32 + ni * 16 + kq * 4] = acc[mi][ni];
    __syncthreads();
    f32x4 bv = *(const f32x4*)(bias + gcol);
    f32x4 zz = {0.f, 0.f, 0.f, 0.f};
#pragma unroll
    for (int it = 0; it < 8; ++it) {
        int r = it * 8 + r0;
        int orv = os[r];
        if (orv >= 0) {
            f32x4 v = *(f32x4*)&ct[r][cc];
            f32x4 oo;
            oo[0] = v[0] + bv[0]; oo[1] = v[1] + bv[1];
            oo[2] = v[2] + bv[2]; oo[3] = v[3] + bv[3];
            *(f32x4*)(out + OUT_PREDS + (long)orv * V_ + gcol) = oo;
        } else {
            int row = -orv - 1;
            *(f32x4*)(out + OUT_PREDS + (long)row * V_ + gcol) = zz;
        }
    }
}

extern "C" void kernel_launch(void* const* d_in, const int* in_sizes, int n_in,
                              void* d_out, int out_size, void* d_ws, size_t ws_size,
                              hipStream_t stream)
{
    const float* enc       = (const float*)d_in[0];
    const int*   caps      = (const int*)  d_in[1];
    const int*   caplen    = (const int*)  d_in[2];
    const float* emb       = (const float*)d_in[3];
    const float* W_enc_att = (const float*)d_in[4];
    const float* b_enc_att = (const float*)d_in[5];
    const float* W_dec_att = (const float*)d_in[6];
    const float* b_dec_att = (const float*)d_in[7];
    const float* W_full    = (const float*)d_in[8];
    // d_in[9] = b_full (softmax-invariant, unused)
    const float* W_ih      = (const float*)d_in[10];
    const float* b_ih      = (const float*)d_in[11];
    const float* W_hh      = (const float*)d_in[12];
    const float* b_hh      = (const float*)d_in[13];
    const float* g_h       = (const float*)d_in[14];
    const float* be_h      = (const float*)d_in[15];
    const float* g_c       = (const float*)d_in[16];
    const float* be_c      = (const float*)d_in[17];
    const float* W_init_h  = (const float*)d_in[18];
    const float* b_init_h  = (const float*)d_in[19];
    const float* W_init_c  = (const float*)d_in[20];
    const float* b_init_c  = (const float*)d_in[21];
    const float* W_beta    = (const float*)d_in[22];
    const float* b_beta    = (const float*)d_in[23];
    const float* W_fc      = (const float*)d_in[24];
    const float* b_fc      = (const float*)d_in[25];
    float* out = (float*)d_out;

    char* w = (char*)d_ws;
    auto alloc = [&](size_t bytes) { char* p = w; w += (bytes + 255) & ~(size_t)255; return p; };
    int*   order_i  = (int*)  alloc(B_ * 4);
    int*   declen_i = (int*)  alloc(B_ * 4);
    int*   caps_i   = (int*)  alloc(B_ * L_ * 4);
    int*   rmap     = (int*)  alloc(2048 * 4);
    int*   orow     = (int*)  alloc(2048 * 4);
    int*   mact     = (int*)  alloc(256);
    bf16*  enc_s    = (bf16*) alloc((size_t)B_ * P_ * ENC_ * 2);
    bf16*  enc_pk   = (bf16*) alloc((size_t)B_ * P_ * ENC_ * 2);
    bf16*  mean_b   = (bf16*) alloc((size_t)B_ * ENC_ * 2);
    bf16*  att1_b   = (bf16*) alloc((size_t)B_ * P_ * 512 * 2);
    float* pi       = (float*)alloc((size_t)B_ * 1024 * 4);
    float* cbuf     = (float*)alloc((size_t)B_ * 512 * 4);
    bf16*  xh       = (bf16*) alloc((size_t)B_ * 3072 * 2);
    float* att2gate = (float*)alloc((size_t)4 * B_ * 2560 * 4);
    float* gp       = (float*)alloc((size_t)8 * B_ * 2048 * 4);
    bf16*  hseq     = (bf16*) alloc((size_t)T_ * B_ * 512 * 2);
    bf16*  Apk      = (bf16*) alloc((size_t)31 * 32768 * 2);
    bf16*  W_inh_b  = (bf16*) alloc((size_t)512 * 2048 * 2);
    bf16*  W_inc_b  = (bf16*) alloc((size_t)512 * 2048 * 2);
    bf16*  Wenc_pk  = (bf16*) alloc((size_t)512 * 2048 * 2);    // W_enc packed
    bf16*  Wab_pk   = (bf16*) alloc((size_t)2560 * 512 * 2);    // [W_dec|W_beta] packed
    bf16*  Wg_pk    = (bf16*) alloc((size_t)2048 * 3072 * 2);   // [W_ih;W_hh] packed
    bf16*  Wfc_pk   = (bf16*) alloc((size_t)32000 * 512 * 2);   // W_fc packed

    k_order<<<1, B_, 0, stream>>>(caplen, caps, order_i, declen_i, caps_i, out, rmap, orow, mact);
    k_cvt_enc<<<12544, 256, 0, stream>>>(enc, order_i, enc_s, enc_pk);
    k_meanb<<<dim3(B_, 8), 256, 0, stream>>>(enc_s, mean_b);

    // plain converts (init weights only)
    CvtSegs cs;
    const float* srcs[2] = {W_init_h, W_init_c};
    bf16* dsts[2] = {W_inh_b, W_inc_b};
    long ns[2] = {512L*2048, 512L*2048};
    long cum = 0;
    for (int i = 0; i < 2; ++i) { cs.s[i] = srcs[i]; cs.d[i] = dsts[i]; cs.cum[i] = cum; cum += ns[i]; }
    cs.cum[2] = cum;
    k_cvt_all<<<(int)((cum / 8 + 255) / 256), 256, 0, stream>>>(cs);

    // fragment-packed weights
    k_packB<0><<<32, 256, 0, stream>>>(W_enc_att, nullptr, Wenc_pk, 2048, 0, 0);
    k_packB<1><<<160, 256, 0, stream>>>(W_dec_att, W_beta, Wab_pk, 512, 512, 0);
    k_packB<2><<<128, 256, 0, stream>>>(W_ih, W_hh, Wg_pk, 3072, 0, 2560);
    k_packB<0><<<2000, 256, 0, stream>>>(W_fc, nullptr, Wfc_pk, 512, 0, 0);

    // init: [h|c] = mean_b @ [W_init_h|W_init_c]^T (N-split), then LN
    k_mgemm<4, 1, 0, 0, 0, 0><<<dim3(1, 8, 1), 256, 0, stream>>>(mean_b, 2048, W_inh_b, W_inc_b,
        nullptr, pi, nullptr, 1024, 2048, 1, 512, 64);
    k_initln<<<B_, 512, 0, stream>>>(pi, b_init_h, b_init_c, g_h, be_h, g_c, be_c, xh, cbuf);

    // att1 = enc_pk @ Wenc_pk^T + b -> bf16 [12544][512]; MI=4, 784 blocks XCD-chunked
    k_mgemm<4, 0, 1, 1, 1, 1><<<784, 256, 0, stream>>>(enc_pk, 0, Wenc_pk, nullptr,
        b_enc_att, nullptr, att1_b, 512, 2048, 1, 0, 12544);

    for (int t = 0; t < T_; ++t) {
        // [att2|gate_pre] = h @ packed[W_dec|W_beta]^T (split-K S=4 raw slots)
        k_mgemm<4, 0, 0, 0, 1, 0><<<dim3(1, 20, 4), 256, 0, stream>>>(xh + 2560, 3072, Wab_pk, nullptr,
            nullptr, att2gate, nullptr, 2560, 512, 4, 0, 64);
        k_attn<<<128, 512, 0, stream>>>(att2gate, b_dec_att, b_beta, W_full, att1_b, enc_s,
            caps_i, declen_i, emb, xh, out, t);
        // gates = xh @ packed[W_ih;W_hh]^T (split-K S=8)
        k_mgemm<4, 0, 0, 0, 1, 0><<<dim3(1, 16, 8), 256, 0, stream>>>(xh, 3072, Wg_pk, nullptr,
            nullptr, gp, nullptr, 2048, 3072, 8, 0, 64);
        k_lstm<<<B_, 512, 0, stream>>>(gp, b_ih, b_hh, g_h, be_h, g_c, be_c,
            xh, cbuf, hseq, declen_i, t);
    }

    // pack hseq (rmap gather) then preds with zero-fill merged
    k_packA<<<31, 256, 0, stream>>>(hseq, rmap, Apk);
    k_preds<<<7750, 256, 0, stream>>>(Apk, Wfc_pk, b_fc, orow, mact, out);
}